// Round 1
// baseline (6988.760 us; speedup 1.0000x reference)
//
#include <hip/hip_runtime.h>
#include <hip/hip_bf16.h>
#include <math.h>

#define DEV __device__ __forceinline__

static constexpr int A_ = 64, T_ = 50, K_ = 6, H_ = 128, NH_ = 8, F_ = 60, L_ = 512;
static constexpr int M_  = A_ * T_ * K_;   // 19200 mode nodes
static constexpr int AT_ = A_ * T_;        // 3200
static constexpr int FF_ = 4 * H_;         // 512
static constexpr int NL_ = 10;
static constexpr int P2F = 2 * F_;         // 120
static constexpr int AK_ = A_ * K_;        // 384

// ---- monotone float<->uint encoding for atomicMax on signed floats ----
DEV unsigned enc_f32(float f) {
    unsigned u = __float_as_uint(f);
    return (u & 0x80000000u) ? ~u : (u | 0x80000000u);
}
DEV float dec_f32(unsigned u) {
    unsigned b = (u & 0x80000000u) ? (u & 0x7fffffffu) : ~u;
    return __uint_as_float(b);
}

// ======================= LayerNorm: one wave per row =======================
__global__ __launch_bounds__(256) void ln_kernel(const float* __restrict__ x,
                                                 const float* __restrict__ g,
                                                 const float* __restrict__ b,
                                                 float* __restrict__ y, int n) {
    int row = blockIdx.x * 4 + (threadIdx.x >> 6);
    int lane = threadIdx.x & 63;
    if (row >= n) return;
    const float* xr = x + (size_t)row * H_;
    float v0 = xr[lane], v1 = xr[lane + 64];
    float s = v0 + v1;
    for (int m = 32; m >= 1; m >>= 1) s += __shfl_xor(s, m, 64);
    float mu = s * (1.f / 128.f);
    float d0 = v0 - mu, d1 = v1 - mu;
    float vs = d0 * d0 + d1 * d1;
    for (int m = 32; m >= 1; m >>= 1) vs += __shfl_xor(vs, m, 64);
    float rs = rsqrtf(vs * (1.f / 128.f) + 1e-5f);
    float* yr = y + (size_t)row * H_;
    yr[lane]      = d0 * rs * g[lane] + b[lane];
    yr[lane + 64] = d1 * rs * g[lane + 64] + b[lane + 64];
}

// ============ tiled GEMM: Y[n,C] = act(X[n,Kd]@W[Kd,C] + bias) (+res) ======
// requires n%64==0, Kd%64==0, C%64==0. 64x64 tile, 4x4 microtile, 256 thr.
template <int ACT, bool RES>
__global__ __launch_bounds__(256) void gemm64(const float* __restrict__ X,
                                              const float* __restrict__ W,
                                              const float* __restrict__ bias,
                                              const float* __restrict__ res,
                                              float* __restrict__ Y,
                                              int n, int Kd, int C) {
    __shared__ float Xs[64 * 68];   // [r][kk] stride 68: conflict-free writes
    __shared__ float Ws[64 * 64];   // [kk][c]
    int row0 = blockIdx.x * 64, col0 = blockIdx.y * 64;
    int tid = threadIdx.x;
    int tc = tid & 15, tr = tid >> 4;
    int c0 = tc * 4, r0 = tr * 4;
    float acc[4][4] = {};
    for (int k0 = 0; k0 < Kd; k0 += 64) {
#pragma unroll
        for (int i = 0; i < 16; i++) {
            int idx = tid + i * 256;
            int kk = idx & 63, r = idx >> 6;
            Xs[r * 68 + kk] = X[(size_t)(row0 + r) * Kd + (k0 + kk)];
            Ws[r * 64 + kk] = W[(size_t)(k0 + r) * C + (col0 + kk)];
        }
        __syncthreads();
        for (int kk = 0; kk < 64; kk++) {
            float4 wv = *(const float4*)(Ws + kk * 64 + c0);
            float x0 = Xs[(r0 + 0) * 68 + kk];
            float x1 = Xs[(r0 + 1) * 68 + kk];
            float x2 = Xs[(r0 + 2) * 68 + kk];
            float x3 = Xs[(r0 + 3) * 68 + kk];
            acc[0][0] = fmaf(x0, wv.x, acc[0][0]); acc[0][1] = fmaf(x0, wv.y, acc[0][1]);
            acc[0][2] = fmaf(x0, wv.z, acc[0][2]); acc[0][3] = fmaf(x0, wv.w, acc[0][3]);
            acc[1][0] = fmaf(x1, wv.x, acc[1][0]); acc[1][1] = fmaf(x1, wv.y, acc[1][1]);
            acc[1][2] = fmaf(x1, wv.z, acc[1][2]); acc[1][3] = fmaf(x1, wv.w, acc[1][3]);
            acc[2][0] = fmaf(x2, wv.x, acc[2][0]); acc[2][1] = fmaf(x2, wv.y, acc[2][1]);
            acc[2][2] = fmaf(x2, wv.z, acc[2][2]); acc[2][3] = fmaf(x2, wv.w, acc[2][3]);
            acc[3][0] = fmaf(x3, wv.x, acc[3][0]); acc[3][1] = fmaf(x3, wv.y, acc[3][1]);
            acc[3][2] = fmaf(x3, wv.z, acc[3][2]); acc[3][3] = fmaf(x3, wv.w, acc[3][3]);
        }
        __syncthreads();
    }
    float4 bv = bias ? *(const float4*)(bias + col0 + c0) : make_float4(0.f, 0.f, 0.f, 0.f);
#pragma unroll
    for (int i = 0; i < 4; i++) {
        size_t off = (size_t)(row0 + r0 + i) * C + col0 + c0;
        float4 o;
        o.x = acc[i][0] + bv.x; o.y = acc[i][1] + bv.y;
        o.z = acc[i][2] + bv.z; o.w = acc[i][3] + bv.w;
        if (ACT == 1) { o.x = fmaxf(o.x, 0.f); o.y = fmaxf(o.y, 0.f);
                        o.z = fmaxf(o.z, 0.f); o.w = fmaxf(o.w, 0.f); }
        if (RES) { float4 rv = *(const float4*)(res + off);
                   o.x += rv.x; o.y += rv.y; o.z += rv.z; o.w += rv.w; }
        *(float4*)(Y + off) = o;
    }
}

// ============== naive GEMM for small/ragged shapes (heads, embeds) =========
template <int ACT, bool RES>
__global__ void small_gemm(const float* __restrict__ X, const float* __restrict__ W,
                           const float* __restrict__ bias, const float* __restrict__ res,
                           float* __restrict__ Y, int n, int Kd, int C) {
    int idx = blockIdx.x * 256 + threadIdx.x;
    if (idx >= n * C) return;
    int row = idx / C, c = idx - row * C;
    float a = bias ? bias[c] : 0.f;
    const float* xr = X + (size_t)row * Kd;
    for (int k = 0; k < Kd; k++) a = fmaf(xr[k], W[(size_t)k * C + c], a);
    if (ACT == 1) a = fmaxf(a, 0.f);
    if (RES) a += res[idx];
    Y[idx] = a;
}

// ==== combined weights: Ck[l] = eW2[g] @ Wke[l], ckb[l] = eb2[g] @ Wke[l] ===
__global__ __launch_bounds__(256) void combine_all(const float* __restrict__ eW2,
                                                   const float* __restrict__ eb2,
                                                   const float* __restrict__ Wke,
                                                   const float* __restrict__ Wve,
                                                   float* __restrict__ Ck, float* __restrict__ Cv,
                                                   float* __restrict__ ckb, float* __restrict__ cvb) {
    int x = blockIdx.x;           // 0..15: (li 0..7) x (kv 0..1)
    int li = x & 7, kv = x >> 3;
    int l = li < 4 ? li : li + 1; // layers 0,1,2,3,5,6,7,8
    int g = (li & 3) + 1;         // emb idx 1..4
    const float* Wsrc = (kv ? Wve : Wke) + (size_t)l * H_ * H_;
    const float* E2 = eW2 + (size_t)g * H_ * H_;
    float* out = (kv ? Cv : Ck) + (size_t)l * H_ * H_;
    float* outb = (kv ? cvb : ckb) + (size_t)l * H_;
    int tid = threadIdx.x;
    int c = tid & 127, kh = tid >> 7;
    int kbase = blockIdx.y * 32 + kh * 16;
    for (int k = kbase; k < kbase + 16; k++) {
        float a = 0.f;
        const float* er = E2 + (size_t)k * H_;
        for (int j = 0; j < H_; j++) a = fmaf(er[j], Wsrc[(size_t)j * H_ + c], a);
        out[(size_t)k * H_ + c] = a;
    }
    if (blockIdx.y == 0 && tid < H_) {
        float a = 0.f;
        const float* ebg = eb2 + g * H_;
        for (int j = 0; j < H_; j++) a = fmaf(ebg[j], Wsrc[(size_t)j * H_ + tid], a);
        outb[tid] = a;
    }
}

// =================== per-layer scratch init ================================
__global__ void init_layer(unsigned* __restrict__ smax, float* __restrict__ den,
                           float* __restrict__ agg) {
    int idx = blockIdx.x * 256 + threadIdx.x;
    if (idx < M_ * NH_) { smax[idx] = 0x007FFFFFu; den[idx] = 0.f; }  // enc(-inf)
    if (idx < M_ * H_) agg[idx] = 0.f;
}

// ======== edge score: inline h=relu(pad(attr)@eW1+eb1), k=h@Ck+ckb+kx[src],
//          score = (q[dst]·k)/4 per head, store + atomicMax segment max =====
template <bool HASE>
__global__ __launch_bounds__(256) void edge_score(const int* __restrict__ src,
                                                  const int* __restrict__ dst,
                                                  const float* __restrict__ attr, int aw,
                                                  const float* __restrict__ eW1,
                                                  const float* __restrict__ eb1,
                                                  const float* __restrict__ Ck,
                                                  const float* __restrict__ ckb,
                                                  const float* __restrict__ kx,
                                                  const float* __restrict__ q,
                                                  float* __restrict__ scores,
                                                  unsigned* __restrict__ smax, int E) {
    __shared__ float hs[HASE ? 64 * 132 : 1];
    __shared__ int sS[64], sD[64];
    int e0 = blockIdx.x * 64;
    int tid = threadIdx.x;
    int rem = E - e0; if (rem > 64) rem = 64;
    if (tid < 64) { sS[tid] = (tid < rem) ? src[e0 + tid] : 0;
                    sD[tid] = (tid < rem) ? dst[e0 + tid] : 0; }
    int tc = tid & 31, tr = tid >> 5;
    int c0 = tc * 4, r0 = tr * 8;
    float acc[8][4] = {};
    if (HASE) {
        for (int i = 0; i < 32; i++) {
            int idx = tid + i * 256;
            int c = idx & 127, r = idx >> 7;
            float hv = 0.f;
            if (r < rem) {
                hv = eb1[c];
                const float* ar = attr + (size_t)(e0 + r) * aw;
                for (int j = 0; j < aw; j++) hv = fmaf(ar[j], eW1[j * H_ + c], hv);
                hv = fmaxf(hv, 0.f);
            }
            hs[r * 132 + c] = hv;
        }
    }
    __syncthreads();
    if (HASE) {
        for (int kk = 0; kk < H_; kk++) {
            float4 ck = *(const float4*)(Ck + (size_t)kk * H_ + c0);
#pragma unroll
            for (int i = 0; i < 8; i++) {
                float xv = hs[(r0 + i) * 132 + kk];
                acc[i][0] = fmaf(xv, ck.x, acc[i][0]);
                acc[i][1] = fmaf(xv, ck.y, acc[i][1]);
                acc[i][2] = fmaf(xv, ck.z, acc[i][2]);
                acc[i][3] = fmaf(xv, ck.w, acc[i][3]);
            }
        }
    }
    float4 cb = HASE ? *(const float4*)(ckb + c0) : make_float4(0.f, 0.f, 0.f, 0.f);
    int h = tc >> 2;
#pragma unroll
    for (int i = 0; i < 8; i++) {
        int r = r0 + i;
        int sR = sS[r], dR = sD[r];
        float4 kxv = *(const float4*)(kx + (size_t)sR * H_ + c0);
        float4 qv  = *(const float4*)(q  + (size_t)dR * H_ + c0);
        float p = qv.x * (acc[i][0] + cb.x + kxv.x)
                + qv.y * (acc[i][1] + cb.y + kxv.y)
                + qv.z * (acc[i][2] + cb.z + kxv.z)
                + qv.w * (acc[i][3] + cb.w + kxv.w);
        p += __shfl_xor(p, 1, 64);
        p += __shfl_xor(p, 2, 64);
        if (r < rem && (tc & 3) == 0) {
            float s = p * 0.25f;   // 1/sqrt(dh=16)
            scores[(size_t)(e0 + r) * NH_ + h] = s;
            atomicMax(smax + (size_t)dR * NH_ + h, enc_f32(s));
        }
    }
}

// ============ exp pass: ex = exp(s - smax[dst]); den += ex =================
__global__ void exp_pass(float* __restrict__ scores, const int* __restrict__ dst,
                         const unsigned* __restrict__ smax, float* __restrict__ den, int E) {
    int t = blockIdx.x * 256 + threadIdx.x;
    if (t >= E * NH_) return;
    int e = t >> 3, h = t & 7;
    int d = dst[e];
    float mx = dec_f32(smax[(size_t)d * NH_ + h]);
    float ex = expf(scores[t] - mx);
    scores[t] = ex;
    atomicAdd(den + (size_t)d * NH_ + h, ex);
}

// ======== edge agg: v = h@Cv+cvb+vx[src]; agg[dst] += attn*v ==============
template <bool HASE>
__global__ __launch_bounds__(256) void edge_agg(const int* __restrict__ src,
                                                const int* __restrict__ dst,
                                                const float* __restrict__ attr, int aw,
                                                const float* __restrict__ eW1,
                                                const float* __restrict__ eb1,
                                                const float* __restrict__ Cv,
                                                const float* __restrict__ cvb,
                                                const float* __restrict__ vx,
                                                const float* __restrict__ ex,
                                                const float* __restrict__ den,
                                                float* __restrict__ agg, int E) {
    __shared__ float hs[HASE ? 64 * 132 : 1];
    __shared__ int sS[64], sD[64];
    int e0 = blockIdx.x * 64;
    int tid = threadIdx.x;
    int rem = E - e0; if (rem > 64) rem = 64;
    if (tid < 64) { sS[tid] = (tid < rem) ? src[e0 + tid] : 0;
                    sD[tid] = (tid < rem) ? dst[e0 + tid] : 0; }
    int tc = tid & 31, tr = tid >> 5;
    int c0 = tc * 4, r0 = tr * 8;
    float acc[8][4] = {};
    if (HASE) {
        for (int i = 0; i < 32; i++) {
            int idx = tid + i * 256;
            int c = idx & 127, r = idx >> 7;
            float hv = 0.f;
            if (r < rem) {
                hv = eb1[c];
                const float* ar = attr + (size_t)(e0 + r) * aw;
                for (int j = 0; j < aw; j++) hv = fmaf(ar[j], eW1[j * H_ + c], hv);
                hv = fmaxf(hv, 0.f);
            }
            hs[r * 132 + c] = hv;
        }
    }
    __syncthreads();
    if (HASE) {
        for (int kk = 0; kk < H_; kk++) {
            float4 cv = *(const float4*)(Cv + (size_t)kk * H_ + c0);
#pragma unroll
            for (int i = 0; i < 8; i++) {
                float xv = hs[(r0 + i) * 132 + kk];
                acc[i][0] = fmaf(xv, cv.x, acc[i][0]);
                acc[i][1] = fmaf(xv, cv.y, acc[i][1]);
                acc[i][2] = fmaf(xv, cv.z, acc[i][2]);
                acc[i][3] = fmaf(xv, cv.w, acc[i][3]);
            }
        }
    }
    float4 cb = HASE ? *(const float4*)(cvb + c0) : make_float4(0.f, 0.f, 0.f, 0.f);
    int h = tc >> 2;
#pragma unroll
    for (int i = 0; i < 8; i++) {
        int r = r0 + i;
        if (r >= rem) break;
        int sR = sS[r], dR = sD[r];
        float4 vxv = *(const float4*)(vx + (size_t)sR * H_ + c0);
        float w = ex[(size_t)(e0 + r) * NH_ + h] / (den[(size_t)dR * NH_ + h] + 1e-9f);
        float* ap = agg + (size_t)dR * H_ + c0;
        atomicAdd(ap + 0, w * (acc[i][0] + cb.x + vxv.x));
        atomicAdd(ap + 1, w * (acc[i][1] + cb.y + vxv.y));
        atomicAdd(ap + 2, w * (acc[i][2] + cb.z + vxv.z));
        atomicAdd(ap + 3, w * (acc[i][3] + cb.w + vxv.w));
    }
}

// ======================= small glue kernels ================================
__global__ void mode_init(float* __restrict__ m, const float* __restrict__ mt) {
    int idx = blockIdx.x * 256 + threadIdx.x;
    if (idx >= M_ * H_) return;
    int node = idx >> 7, c = idx & 127;
    m[idx] = mt[(node % K_) * H_ + c];
}
__global__ void extract_last(const float* __restrict__ m, float* __restrict__ out) {
    int idx = blockIdx.x * 256 + threadIdx.x;
    if (idx >= AK_ * H_) return;
    int row = idx >> 7, c = idx & 127;
    int a = row / K_, k = row - a * K_;
    int node = (a * T_ + (T_ - 1)) * K_ + k;
    out[idx] = m[(size_t)node * H_ + c];
}
__global__ void add_anchor(float* __restrict__ m, const float* __restrict__ anchor) {
    int idx = blockIdx.x * 256 + threadIdx.x;
    if (idx >= M_ * H_) return;
    int node = idx >> 7, c = idx & 127;
    int a = node / (T_ * K_), k = node % K_;
    m[idx] += anchor[(size_t)(a * K_ + k) * H_ + c];
}

// ============================ host launch ==================================
extern "C" void kernel_launch(void* const* d_in, const int* in_sizes, int n_in,
                              void* d_out, int out_size, void* d_ws, size_t ws_size,
                              hipStream_t stream) {
    const float* a_input     = (const float*)d_in[0];
    const float* l_embs      = (const float*)d_in[1];
    const float* mode_tokens = (const float*)d_in[2];
    const float* emb_W1 = (const float*)d_in[3];
    const float* emb_b1 = (const float*)d_in[4];
    const float* emb_W2 = (const float*)d_in[5];
    const float* emb_b2 = (const float*)d_in[6];
    const float* ga_Wq  = (const float*)d_in[7];
    const float* ga_Wk  = (const float*)d_in[8];
    const float* ga_Wv  = (const float*)d_in[9];
    const float* ga_Wo  = (const float*)d_in[10];
    const float* ga_Wke = (const float*)d_in[11];
    const float* ga_Wve = (const float*)d_in[12];
    const float* ga_g1  = (const float*)d_in[13];
    const float* ga_b1  = (const float*)d_in[14];
    const float* ga_g2  = (const float*)d_in[15];
    const float* ga_b2  = (const float*)d_in[16];
    const float* ga_fW1 = (const float*)d_in[17];
    const float* ga_fb1 = (const float*)d_in[18];
    const float* ga_fW2 = (const float*)d_in[19];
    const float* ga_fb2 = (const float*)d_in[20];
    const float* tp_W1 = (const float*)d_in[21];
    const float* tp_b1 = (const float*)d_in[22];
    const float* tp_W2 = (const float*)d_in[23];
    const float* tp_b2 = (const float*)d_in[24];
    const float* pa_W1 = (const float*)d_in[25];
    const float* pa_b1 = (const float*)d_in[26];
    const float* pa_W2 = (const float*)d_in[27];
    const float* pa_b2 = (const float*)d_in[28];
    const float* tr_W1 = (const float*)d_in[29];
    const float* tr_b1 = (const float*)d_in[30];
    const float* tr_W2 = (const float*)d_in[31];
    const float* tr_b2 = (const float*)d_in[32];
    const float* attrs[4] = { (const float*)d_in[33], (const float*)d_in[34],
                              (const float*)d_in[35], (const float*)d_in[36] };
    const int* eis[5] = { (const int*)d_in[37], (const int*)d_in[38], (const int*)d_in[39],
                          (const int*)d_in[40], (const int*)d_in[41] };
    int Es[5];
    int Emax = 0;
    for (int i = 0; i < 5; i++) { Es[i] = in_sizes[37 + i] / 2; if (Es[i] > Emax) Emax = Es[i]; }

    // ---- workspace layout (all 256B aligned) ----
    size_t off = 0;
    auto alloc = [&](size_t nf) -> float* {
        float* p = (float*)((char*)d_ws + off);
        off += ((nf * sizeof(float) + 255) / 256) * 256;
        return p;
    };
    float* cCk    = alloc((size_t)NL_ * H_ * H_);
    float* cCv    = alloc((size_t)NL_ * H_ * H_);
    float* ckb    = alloc(NL_ * H_);
    float* cvb    = alloc(NL_ * H_);
    float* a_embs = alloc((size_t)AT_ * H_);
    float* m      = alloc((size_t)M_ * H_);
    float* xd_ln  = alloc((size_t)M_ * H_);
    float* xs_ln  = alloc((size_t)AT_ * H_);
    float* q      = alloc((size_t)M_ * H_);
    float* kx     = alloc((size_t)M_ * H_);
    float* vx     = alloc((size_t)M_ * H_);
    float* agg    = alloc((size_t)M_ * H_);
    float* hidden = alloc((size_t)M_ * FF_);
    float* scores = alloc((size_t)Emax * NH_);
    unsigned* smax = (unsigned*)alloc(M_ * NH_);
    float* den    = alloc(M_ * NH_);
    float* mlast  = alloc(AK_ * H_);
    float* hbuf   = alloc(AK_ * H_);
    float* anchor = alloc(AK_ * H_);
    (void)ws_size; (void)n_in;

    const size_t HH = (size_t)H_ * H_;
    float* outp = (float*)d_out;

    // ---- setup ----
    combine_all<<<dim3(16, 4), 256, 0, stream>>>(emb_W2, emb_b2, ga_Wke, ga_Wve, cCk, cCv, ckb, cvb);
    small_gemm<1, false><<<(AT_ * H_ + 255) / 256, 256, 0, stream>>>(a_input, emb_W1, emb_b1, nullptr, hidden, AT_, 5, H_);
    small_gemm<0, false><<<(AT_ * H_ + 255) / 256, 256, 0, stream>>>(hidden, emb_W2, emb_b2, nullptr, a_embs, AT_, H_, H_);
    mode_init<<<(M_ * H_ + 255) / 256, 256, 0, stream>>>(m, mode_tokens);

    struct Cfg { const float* srcX; int n_src; int gi; int ai; int aw; bool hasE; };
    // gi: edge-graph index 0..4 (t2m,l2m,m2m_h,m2m_a,m2m_s); ai: attr idx
    Cfg cfgs[10] = {
        { a_embs, AT_, 0, 0, 4, true }, { l_embs, L_, 1, 1, 3, true },
        { nullptr, M_, 2, 2, 4, true }, { nullptr, M_, 3, 3, 3, true },
        { nullptr, M_, 4, 0, 0, false },
        { a_embs, AT_, 0, 0, 4, true }, { l_embs, L_, 1, 1, 3, true },
        { nullptr, M_, 2, 2, 4, true }, { nullptr, M_, 3, 3, 3, true },
        { nullptr, M_, 4, 0, 0, false },
    };

    for (int l = 0; l < 10; l++) {
        const Cfg& cf = cfgs[l];
        int E = Es[cf.gi];
        const int* srcI = eis[cf.gi];
        const int* dstI = eis[cf.gi] + E;
        const float* g1 = ga_g1 + l * H_; const float* b1 = ga_b1 + l * H_;

        // LN + projections
        ln_kernel<<<M_ / 4, 256, 0, stream>>>(m, g1, b1, xd_ln, M_);
        gemm64<0, false><<<dim3(M_ / 64, 2), 256, 0, stream>>>(xd_ln, ga_Wq + l * HH, nullptr, nullptr, q, M_, H_, H_);
        const float* srcLN = xd_ln;
        if (cf.srcX) {
            ln_kernel<<<cf.n_src / 4, 256, 0, stream>>>(cf.srcX, g1, b1, xs_ln, cf.n_src);
            srcLN = xs_ln;
        }
        gemm64<0, false><<<dim3(cf.n_src / 64, 2), 256, 0, stream>>>(srcLN, ga_Wk + l * HH, nullptr, nullptr, kx, cf.n_src, H_, H_);
        gemm64<0, false><<<dim3(cf.n_src / 64, 2), 256, 0, stream>>>(srcLN, ga_Wv + l * HH, nullptr, nullptr, vx, cf.n_src, H_, H_);

        init_layer<<<(M_ * H_ + 255) / 256, 256, 0, stream>>>(smax, den, agg);

        int nb = (E + 63) / 64;
        int gg = (l < 5) ? l + 1 : l - 4;   // embed-MLP index for this graph
        const float* eW1g = emb_W1 + (size_t)gg * 5 * H_;
        const float* eb1g = emb_b1 + (size_t)gg * H_;
        if (cf.hasE) {
            edge_score<true><<<nb, 256, 0, stream>>>(srcI, dstI, attrs[cf.ai], cf.aw, eW1g, eb1g,
                cCk + l * HH, ckb + l * H_, kx, q, scores, smax, E);
        } else {
            edge_score<false><<<nb, 256, 0, stream>>>(srcI, dstI, nullptr, 0, nullptr, nullptr,
                nullptr, nullptr, kx, q, scores, smax, E);
        }
        exp_pass<<<(E * NH_ + 255) / 256, 256, 0, stream>>>(scores, dstI, smax, den, E);
        if (cf.hasE) {
            edge_agg<true><<<nb, 256, 0, stream>>>(srcI, dstI, attrs[cf.ai], cf.aw, eW1g, eb1g,
                cCv + l * HH, cvb + l * H_, vx, scores, den, agg, E);
        } else {
            edge_agg<false><<<nb, 256, 0, stream>>>(srcI, dstI, nullptr, 0, nullptr, nullptr,
                nullptr, nullptr, vx, scores, den, agg, E);
        }

        // x = x + agg @ Wo ; FFN with pre-LN
        gemm64<0, true><<<dim3(M_ / 64, 2), 256, 0, stream>>>(agg, ga_Wo + l * HH, nullptr, m, m, M_, H_, H_);
        ln_kernel<<<M_ / 4, 256, 0, stream>>>(m, ga_g2 + l * H_, ga_b2 + l * H_, xd_ln, M_);
        gemm64<1, false><<<dim3(M_ / 64, FF_ / 64), 256, 0, stream>>>(xd_ln, ga_fW1 + (size_t)l * H_ * FF_, ga_fb1 + l * FF_, nullptr, hidden, M_, H_, FF_);
        gemm64<0, true><<<dim3(M_ / 64, 2), 256, 0, stream>>>(hidden, ga_fW2 + (size_t)l * FF_ * H_, ga_fb2 + l * H_, m, m, M_, FF_, H_);

        if (l == 4) {
            // proposal head + anchor conditioning
            extract_last<<<(AK_ * H_ + 255) / 256, 256, 0, stream>>>(m, mlast);
            small_gemm<1, false><<<(AK_ * H_ + 255) / 256, 256, 0, stream>>>(mlast, tp_W1, tp_b1, nullptr, hbuf, AK_, H_, H_);
            small_gemm<0, false><<<(AK_ * P2F + 255) / 256, 256, 0, stream>>>(hbuf, tp_W2, tp_b2, nullptr, outp, AK_, H_, P2F);
            small_gemm<1, false><<<(AK_ * H_ + 255) / 256, 256, 0, stream>>>(outp, pa_W1, pa_b1, nullptr, hbuf, AK_, P2F, H_);
            small_gemm<0, false><<<(AK_ * H_ + 255) / 256, 256, 0, stream>>>(hbuf, pa_W2, pa_b2, nullptr, anchor, AK_, H_, H_);
            add_anchor<<<(M_ * H_ + 255) / 256, 256, 0, stream>>>(m, anchor);
        }
    }

    // refinement head: refine = proposal + MLP(n_last)
    extract_last<<<(AK_ * H_ + 255) / 256, 256, 0, stream>>>(m, mlast);
    small_gemm<1, false><<<(AK_ * H_ + 255) / 256, 256, 0, stream>>>(mlast, tr_W1, tr_b1, nullptr, hbuf, AK_, H_, H_);
    small_gemm<0, true><<<(AK_ * P2F + 255) / 256, 256, 0, stream>>>(hbuf, tr_W2, tr_b2, outp, outp + AK_ * P2F, AK_, H_, P2F);
}

// Round 2
// 4713.736 us; speedup vs baseline: 1.4826x; 1.4826x over previous
//
#include <hip/hip_runtime.h>
#include <hip/hip_bf16.h>
#include <math.h>

#define DEV __device__ __forceinline__

static constexpr int A_ = 64, T_ = 50, K_ = 6, H_ = 128, NH_ = 8, F_ = 60, L_ = 512;
static constexpr int M_  = A_ * T_ * K_;   // 19200 mode nodes
static constexpr int AT_ = A_ * T_;        // 3200
static constexpr int FF_ = 4 * H_;         // 512
static constexpr int NL_ = 10;
static constexpr int P2F = 2 * F_;         // 120
static constexpr int AK_ = A_ * K_;        // 384

// ======================= LayerNorm: one wave per row =======================
__global__ __launch_bounds__(256) void ln_kernel(const float* __restrict__ x,
                                                 const float* __restrict__ g,
                                                 const float* __restrict__ b,
                                                 float* __restrict__ y, int n) {
    int row = blockIdx.x * 4 + (threadIdx.x >> 6);
    int lane = threadIdx.x & 63;
    if (row >= n) return;
    const float* xr = x + (size_t)row * H_;
    float v0 = xr[lane], v1 = xr[lane + 64];
    float s = v0 + v1;
    for (int m = 32; m >= 1; m >>= 1) s += __shfl_xor(s, m, 64);
    float mu = s * (1.f / 128.f);
    float d0 = v0 - mu, d1 = v1 - mu;
    float vs = d0 * d0 + d1 * d1;
    for (int m = 32; m >= 1; m >>= 1) vs += __shfl_xor(vs, m, 64);
    float rs = rsqrtf(vs * (1.f / 128.f) + 1e-5f);
    float* yr = y + (size_t)row * H_;
    yr[lane]      = d0 * rs * g[lane] + b[lane];
    yr[lane + 64] = d1 * rs * g[lane + 64] + b[lane + 64];
}

// ====== 128x128-tile f32 GEMM, 8x8 microtile, BK=32, 256 threads ==========
// Y[n,C] = act(X[n,Kd] @ W[Kd,C] + bias) (+res). Kd%32==0, C%128==0.
// Rows guarded (n arbitrary). HGEN: X replaced by h=relu(pad(attr)@eW1+eb1).
template <int ACT, bool RES, bool HGEN>
__global__ __launch_bounds__(256) void gemm128(const float* __restrict__ X,
                                               const float* __restrict__ W,
                                               const float* __restrict__ bias,
                                               const float* __restrict__ res,
                                               float* __restrict__ Y,
                                               int n, int Kd, int C,
                                               const float* __restrict__ attr, int aw,
                                               const float* __restrict__ eW1,
                                               const float* __restrict__ eb1) {
    __shared__ float Xs[128 * 36];                    // [r][kk], stride 36
    __shared__ float Ws[32 * 128];                    // [kk][c]
    __shared__ float attrS[HGEN ? 128 * 4 : 1];
    __shared__ float eW1s[HGEN ? 4 * 128 : 1];
    __shared__ float eb1s[HGEN ? 128 : 1];
    int row0 = blockIdx.x * 128, col0 = blockIdx.y * 128;
    int tid = threadIdx.x;
    int tc = tid & 15, tr = tid >> 4;
    int cA = tc * 4;
    int rA = tr * 4;
    float acc[8][8] = {};

    if (HGEN) {
        for (int t = tid; t < 128 * aw; t += 256) {
            int r = t / aw, j = t - r * aw;
            attrS[r * 4 + j] = (row0 + r < n) ? attr[(size_t)(row0 + r) * aw + j] : 0.f;
        }
        for (int t = tid; t < aw * 128; t += 256) eW1s[t] = eW1[t];
        if (tid < 128) eb1s[tid] = eb1[tid];
        __syncthreads();
    }

    for (int k0 = 0; k0 < Kd; k0 += 32) {
        if (HGEN) {
#pragma unroll
            for (int i = 0; i < 16; i++) {
                int idx = tid + i * 256;
                int r = idx >> 5, kk = idx & 31;
                float hv = eb1s[k0 + kk];
                for (int j = 0; j < aw; j++)
                    hv = fmaf(attrS[r * 4 + j], eW1s[j * 128 + k0 + kk], hv);
                Xs[r * 36 + kk] = fmaxf(hv, 0.f);
            }
        } else {
#pragma unroll
            for (int i = 0; i < 4; i++) {
                int idx = tid + i * 256;
                int r = idx >> 3, kc = idx & 7;
                float4 v = make_float4(0.f, 0.f, 0.f, 0.f);
                if (row0 + r < n)
                    v = *(const float4*)(X + (size_t)(row0 + r) * Kd + k0 + kc * 4);
                *(float4*)(Xs + r * 36 + kc * 4) = v;
            }
        }
#pragma unroll
        for (int i = 0; i < 4; i++) {
            int idx = tid + i * 256;
            int cc = idx & 31, kk = idx >> 5;
            *(float4*)(Ws + kk * 128 + cc * 4) =
                *(const float4*)(W + (size_t)(k0 + kk) * C + col0 + cc * 4);
        }
        __syncthreads();
#pragma unroll 8
        for (int kk = 0; kk < 32; kk++) {
            float4 w0 = *(const float4*)(Ws + kk * 128 + cA);
            float4 w1 = *(const float4*)(Ws + kk * 128 + cA + 64);
            float xr[8];
#pragma unroll
            for (int i = 0; i < 4; i++) {
                xr[i]     = Xs[(rA + i) * 36 + kk];
                xr[4 + i] = Xs[(rA + i + 64) * 36 + kk];
            }
#pragma unroll
            for (int i = 0; i < 8; i++) {
                float x = xr[i];
                acc[i][0] = fmaf(x, w0.x, acc[i][0]);
                acc[i][1] = fmaf(x, w0.y, acc[i][1]);
                acc[i][2] = fmaf(x, w0.z, acc[i][2]);
                acc[i][3] = fmaf(x, w0.w, acc[i][3]);
                acc[i][4] = fmaf(x, w1.x, acc[i][4]);
                acc[i][5] = fmaf(x, w1.y, acc[i][5]);
                acc[i][6] = fmaf(x, w1.z, acc[i][6]);
                acc[i][7] = fmaf(x, w1.w, acc[i][7]);
            }
        }
        __syncthreads();
    }

    float4 bv0 = make_float4(0.f, 0.f, 0.f, 0.f), bv1 = bv0;
    if (bias) {
        bv0 = *(const float4*)(bias + col0 + cA);
        bv1 = *(const float4*)(bias + col0 + cA + 64);
    }
#pragma unroll
    for (int i = 0; i < 8; i++) {
        int r = row0 + ((i < 4) ? (rA + i) : (rA + i + 60));  // i>=4: +64+(i-4)
        if (r >= n) continue;
#pragma unroll
        for (int ch = 0; ch < 2; ch++) {
            int col = col0 + cA + ch * 64;
            size_t off = (size_t)r * C + col;
            float4 bvv = ch ? bv1 : bv0;
            float4 o;
            o.x = acc[i][ch * 4 + 0] + bvv.x;
            o.y = acc[i][ch * 4 + 1] + bvv.y;
            o.z = acc[i][ch * 4 + 2] + bvv.z;
            o.w = acc[i][ch * 4 + 3] + bvv.w;
            if (ACT == 1) { o.x = fmaxf(o.x, 0.f); o.y = fmaxf(o.y, 0.f);
                            o.z = fmaxf(o.z, 0.f); o.w = fmaxf(o.w, 0.f); }
            if (RES) { float4 rv = *(const float4*)(res + off);
                       o.x += rv.x; o.y += rv.y; o.z += rv.z; o.w += rv.w; }
            *(float4*)(Y + off) = o;
        }
    }
}

// ============== naive GEMM for small/ragged shapes (heads, embeds) =========
template <int ACT, bool RES>
__global__ void small_gemm(const float* __restrict__ X, const float* __restrict__ W,
                           const float* __restrict__ bias, const float* __restrict__ res,
                           float* __restrict__ Y, int n, int Kd, int C) {
    int idx = blockIdx.x * 256 + threadIdx.x;
    if (idx >= n * C) return;
    int row = idx / C, c = idx - row * C;
    float a = bias ? bias[c] : 0.f;
    const float* xr = X + (size_t)row * Kd;
    for (int k = 0; k < Kd; k++) a = fmaf(xr[k], W[(size_t)k * C + c], a);
    if (ACT == 1) a = fmaxf(a, 0.f);
    if (RES) a += res[idx];
    Y[idx] = a;
}

// ==== combined weights: cW[l][k][0:128]=eW2[g]@Wke[l], [128:256]=..@Wve[l] ==
__global__ __launch_bounds__(256) void combine_all(const float* __restrict__ eW2,
                                                   const float* __restrict__ eb2,
                                                   const float* __restrict__ Wke,
                                                   const float* __restrict__ Wve,
                                                   float* __restrict__ cW,
                                                   float* __restrict__ cb) {
    int li = blockIdx.x;              // 0..7
    int l = li < 4 ? li : li + 1;     // layers 0,1,2,3,5,6,7,8
    int g = (li & 3) + 1;             // emb idx 1..4
    int c = threadIdx.x;              // 0..255
    int isV = c >> 7, cc = c & 127;
    const size_t HH = (size_t)H_ * H_;
    const float* Wsrc = (isV ? Wve : Wke) + (size_t)l * HH;
    const float* E2 = eW2 + (size_t)g * HH;
    int k0 = blockIdx.y * 32;
    for (int k = k0; k < k0 + 32; k++) {
        float a = 0.f;
        for (int j = 0; j < 128; j++) a = fmaf(E2[k * 128 + j], Wsrc[(size_t)j * 128 + cc], a);
        cW[(size_t)l * 128 * 256 + (size_t)k * 256 + c] = a;
    }
    if (blockIdx.y == 0) {
        float a = 0.f;
        const float* eb = eb2 + g * 128;
        for (int j = 0; j < 128; j++) a = fmaf(eb[j], Wsrc[(size_t)j * 128 + cc], a);
        cb[l * 256 + c] = a;
    }
}

// ============================ CSR construction =============================
__global__ void zero_i32(int* __restrict__ p, int n) {
    int i = blockIdx.x * 256 + threadIdx.x;
    if (i < n) p[i] = 0;
}
__global__ void hist_kernel(const int* __restrict__ dst, int E, int* __restrict__ deg) {
    int e = blockIdx.x * 256 + threadIdx.x;
    if (e < E) atomicAdd(&deg[dst[e]], 1);
}
// single-block exclusive scan over n ints -> off[0..n], cursor copy
__global__ __launch_bounds__(256) void exscan_kernel(const int* __restrict__ deg,
                                                     int* __restrict__ off,
                                                     int* __restrict__ cursor, int n) {
    __shared__ int wsum[4];
    __shared__ int carry;
    int tid = threadIdx.x, lane = tid & 63, w = tid >> 6;
    if (tid == 0) carry = 0;
    __syncthreads();
    for (int base = 0; base < n; base += 256) {
        int v = (base + tid < n) ? deg[base + tid] : 0;
        int incl = v;
        for (int d = 1; d < 64; d <<= 1) {
            int t = __shfl_up(incl, d, 64);
            if (lane >= d) incl += t;
        }
        if (lane == 63) wsum[w] = incl;
        __syncthreads();
        int woff = 0;
        for (int i = 0; i < w; i++) woff += wsum[i];
        int total = wsum[0] + wsum[1] + wsum[2] + wsum[3];
        int excl = carry + woff + incl - v;
        if (base + tid < n) { off[base + tid] = excl; cursor[base + tid] = excl; }
        __syncthreads();
        if (tid == 0) carry += total;
        __syncthreads();
    }
    if (threadIdx.x == 0) off[n] = carry;
}
__global__ void scatter_kernel(const int* __restrict__ dst, int E,
                               int* __restrict__ cursor, int* __restrict__ eids) {
    int e = blockIdx.x * 256 + threadIdx.x;
    if (e < E) { int p = atomicAdd(&cursor[dst[e]], 1); eids[p] = e; }
}

// ========== fused attention: one wave per dst, online softmax ==============
template <bool HASE>
__global__ __launch_bounds__(256) void attn_fused(const int* __restrict__ off,
                                                  const int* __restrict__ eid_list,
                                                  const int* __restrict__ srcArr,
                                                  const float* __restrict__ kvadd,
                                                  const float* __restrict__ kx,
                                                  const float* __restrict__ vx,
                                                  const float* __restrict__ q,
                                                  float* __restrict__ agg) {
    int w = threadIdx.x >> 6, lane = threadIdx.x & 63;
    int d = blockIdx.x * 4 + w;
    int beg = off[d], end = off[d + 1];
    float q0 = q[(size_t)d * 128 + lane] * 0.25f;       // fold 1/sqrt(16)
    float q1 = q[(size_t)d * 128 + 64 + lane] * 0.25f;
    float m0 = -INFINITY, m1 = -INFINITY;
    float den0 = 0.f, den1 = 0.f, acc0 = 0.f, acc1 = 0.f;
    for (int pos = beg; pos < end; pos++) {
        int e = eid_list[pos];
        int s = srcArr[e];
        const float* kxr = kx + (size_t)s * 128;
        const float* vxr = vx + (size_t)s * 128;
        float k0 = kxr[lane], k1 = kxr[64 + lane];
        float v0 = vxr[lane], v1 = vxr[64 + lane];
        if (HASE) {
            const float* kv = kvadd + (size_t)e * 256;
            k0 += kv[lane];       k1 += kv[64 + lane];
            v0 += kv[128 + lane]; v1 += kv[192 + lane];
        }
        float p0 = q0 * k0, p1 = q1 * k1;
#pragma unroll
        for (int msk = 1; msk < 16; msk <<= 1) {
            p0 += __shfl_xor(p0, msk, 64);
            p1 += __shfl_xor(p1, msk, 64);
        }
        float nm0 = fmaxf(m0, p0), nm1 = fmaxf(m1, p1);
        float c0 = __expf(m0 - nm0), c1 = __expf(m1 - nm1);
        float e0 = __expf(p0 - nm0), e1 = __expf(p1 - nm1);
        acc0 = acc0 * c0 + e0 * v0; den0 = den0 * c0 + e0;
        acc1 = acc1 * c1 + e1 * v1; den1 = den1 * c1 + e1;
        m0 = nm0; m1 = nm1;
    }
    agg[(size_t)d * 128 + lane]      = acc0 / (den0 + 1e-9f);
    agg[(size_t)d * 128 + 64 + lane] = acc1 / (den1 + 1e-9f);
}

// ======================= small glue kernels ================================
__global__ void mode_init(float* __restrict__ m, const float* __restrict__ mt) {
    int idx = blockIdx.x * 256 + threadIdx.x;
    if (idx >= M_ * H_) return;
    int node = idx >> 7, c = idx & 127;
    m[idx] = mt[(node % K_) * H_ + c];
}
__global__ void extract_last(const float* __restrict__ m, float* __restrict__ out) {
    int idx = blockIdx.x * 256 + threadIdx.x;
    if (idx >= AK_ * H_) return;
    int row = idx >> 7, c = idx & 127;
    int a = row / K_, k = row - a * K_;
    int node = (a * T_ + (T_ - 1)) * K_ + k;
    out[idx] = m[(size_t)node * H_ + c];
}
__global__ void add_anchor(float* __restrict__ m, const float* __restrict__ anchor) {
    int idx = blockIdx.x * 256 + threadIdx.x;
    if (idx >= M_ * H_) return;
    int node = idx >> 7, c = idx & 127;
    int a = node / (T_ * K_), k = node % K_;
    m[idx] += anchor[(size_t)(a * K_ + k) * H_ + c];
}

// ============================ host launch ==================================
extern "C" void kernel_launch(void* const* d_in, const int* in_sizes, int n_in,
                              void* d_out, int out_size, void* d_ws, size_t ws_size,
                              hipStream_t stream) {
    const float* a_input     = (const float*)d_in[0];
    const float* l_embs      = (const float*)d_in[1];
    const float* mode_tokens = (const float*)d_in[2];
    const float* emb_W1 = (const float*)d_in[3];
    const float* emb_b1 = (const float*)d_in[4];
    const float* emb_W2 = (const float*)d_in[5];
    const float* emb_b2 = (const float*)d_in[6];
    const float* ga_Wq  = (const float*)d_in[7];
    const float* ga_Wk  = (const float*)d_in[8];
    const float* ga_Wv  = (const float*)d_in[9];
    const float* ga_Wo  = (const float*)d_in[10];
    const float* ga_Wke = (const float*)d_in[11];
    const float* ga_Wve = (const float*)d_in[12];
    const float* ga_g1  = (const float*)d_in[13];
    const float* ga_b1  = (const float*)d_in[14];
    const float* ga_g2  = (const float*)d_in[15];
    const float* ga_b2  = (const float*)d_in[16];
    const float* ga_fW1 = (const float*)d_in[17];
    const float* ga_fb1 = (const float*)d_in[18];
    const float* ga_fW2 = (const float*)d_in[19];
    const float* ga_fb2 = (const float*)d_in[20];
    const float* tp_W1 = (const float*)d_in[21];
    const float* tp_b1 = (const float*)d_in[22];
    const float* tp_W2 = (const float*)d_in[23];
    const float* tp_b2 = (const float*)d_in[24];
    const float* pa_W1 = (const float*)d_in[25];
    const float* pa_b1 = (const float*)d_in[26];
    const float* pa_W2 = (const float*)d_in[27];
    const float* pa_b2 = (const float*)d_in[28];
    const float* tr_W1 = (const float*)d_in[29];
    const float* tr_b1 = (const float*)d_in[30];
    const float* tr_W2 = (const float*)d_in[31];
    const float* tr_b2 = (const float*)d_in[32];
    const float* attrs[4] = { (const float*)d_in[33], (const float*)d_in[34],
                              (const float*)d_in[35], (const float*)d_in[36] };
    const int* eis[5] = { (const int*)d_in[37], (const int*)d_in[38], (const int*)d_in[39],
                          (const int*)d_in[40], (const int*)d_in[41] };
    int Es[5];
    int Emax = 0;
    for (int i = 0; i < 5; i++) { Es[i] = in_sizes[37 + i] / 2; if (Es[i] > Emax) Emax = Es[i]; }

    // ---- workspace layout (256B aligned) ----
    size_t off = 0;
    auto alloc = [&](size_t nbytes) -> char* {
        char* p = (char*)d_ws + off;
        off += ((nbytes + 255) / 256) * 256;
        return p;
    };
    float* cW     = (float*)alloc((size_t)NL_ * 128 * 256 * 4);
    float* cb     = (float*)alloc((size_t)NL_ * 256 * 4);
    float* a_embs = (float*)alloc((size_t)AT_ * H_ * 4);
    float* m      = (float*)alloc((size_t)M_ * H_ * 4);
    float* xd_ln  = (float*)alloc((size_t)M_ * H_ * 4);
    float* xs_ln  = (float*)alloc((size_t)AT_ * H_ * 4);
    float* q      = (float*)alloc((size_t)M_ * H_ * 4);
    float* kx     = (float*)alloc((size_t)M_ * H_ * 4);
    float* vx     = (float*)alloc((size_t)M_ * H_ * 4);
    float* agg    = (float*)alloc((size_t)M_ * H_ * 4);
    size_t bigN   = (size_t)Emax * 256;
    if ((size_t)M_ * FF_ > bigN) bigN = (size_t)M_ * FF_;
    float* big    = (float*)alloc(bigN * 4);          // kvadd / FFN hidden
    int* csr_off  = (int*)alloc((size_t)5 * (M_ + 1) * 4);
    int* csr_eid  = (int*)alloc((size_t)5 * Emax * 4);
    int* deg      = (int*)alloc((size_t)M_ * 4);
    int* cursor   = (int*)alloc((size_t)M_ * 4);
    float* mlast  = (float*)alloc((size_t)AK_ * H_ * 4);
    float* hbuf   = (float*)alloc((size_t)AK_ * H_ * 4);
    float* anchor = (float*)alloc((size_t)AK_ * H_ * 4);
    (void)ws_size; (void)n_in;

    const size_t HH = (size_t)H_ * H_;
    float* outp = (float*)d_out;

    // ---- CSR for 5 graphs ----
    for (int gI = 0; gI < 5; gI++) {
        int E = Es[gI];
        const int* dstI = eis[gI] + E;
        int* offg = csr_off + gI * (M_ + 1);
        int* eidg = csr_eid + (size_t)gI * Emax;
        zero_i32<<<(M_ + 255) / 256, 256, 0, stream>>>(deg, M_);
        hist_kernel<<<(E + 255) / 256, 256, 0, stream>>>(dstI, E, deg);
        exscan_kernel<<<1, 256, 0, stream>>>(deg, offg, cursor, M_);
        scatter_kernel<<<(E + 255) / 256, 256, 0, stream>>>(dstI, E, cursor, eidg);
    }

    // ---- setup ----
    combine_all<<<dim3(8, 4), 256, 0, stream>>>(emb_W2, emb_b2, ga_Wke, ga_Wve, cW, cb);
    small_gemm<1, false><<<(AT_ * H_ + 255) / 256, 256, 0, stream>>>(a_input, emb_W1, emb_b1, nullptr, big, AT_, 5, H_);
    small_gemm<0, false><<<(AT_ * H_ + 255) / 256, 256, 0, stream>>>(big, emb_W2, emb_b2, nullptr, a_embs, AT_, H_, H_);
    mode_init<<<(M_ * H_ + 255) / 256, 256, 0, stream>>>(m, mode_tokens);

    struct Cfg { const float* srcX; int n_src; int gi; int ai; int aw; bool hasE; };
    Cfg cfgs[10] = {
        { a_embs, AT_, 0, 0, 4, true }, { l_embs, L_, 1, 1, 3, true },
        { nullptr, M_, 2, 2, 4, true }, { nullptr, M_, 3, 3, 3, true },
        { nullptr, M_, 4, 0, 0, false },
        { a_embs, AT_, 0, 0, 4, true }, { l_embs, L_, 1, 1, 3, true },
        { nullptr, M_, 2, 2, 4, true }, { nullptr, M_, 3, 3, 3, true },
        { nullptr, M_, 4, 0, 0, false },
    };

    for (int l = 0; l < 10; l++) {
        const Cfg& cf = cfgs[l];
        int E = Es[cf.gi];
        const int* srcI = eis[cf.gi];
        const int* offg = csr_off + cf.gi * (M_ + 1);
        const int* eidg = csr_eid + (size_t)cf.gi * Emax;
        const float* g1 = ga_g1 + l * H_; const float* b1 = ga_b1 + l * H_;

        // LN + projections
        ln_kernel<<<M_ / 4, 256, 0, stream>>>(m, g1, b1, xd_ln, M_);
        gemm128<0, false, false><<<dim3(M_ / 128, 1), 256, 0, stream>>>(
            xd_ln, ga_Wq + l * HH, nullptr, nullptr, q, M_, H_, H_, nullptr, 0, nullptr, nullptr);
        const float* srcLN = xd_ln;
        if (cf.srcX) {
            ln_kernel<<<cf.n_src / 4, 256, 0, stream>>>(cf.srcX, g1, b1, xs_ln, cf.n_src);
            srcLN = xs_ln;
        }
        gemm128<0, false, false><<<dim3(cf.n_src / 128, 1), 256, 0, stream>>>(
            srcLN, ga_Wk + l * HH, nullptr, nullptr, kx, cf.n_src, H_, H_, nullptr, 0, nullptr, nullptr);
        gemm128<0, false, false><<<dim3(cf.n_src / 128, 1), 256, 0, stream>>>(
            srcLN, ga_Wv + l * HH, nullptr, nullptr, vx, cf.n_src, H_, H_, nullptr, 0, nullptr, nullptr);

        if (cf.hasE) {
            int gg = (l < 5) ? l + 1 : l - 4;
            const float* eW1g = emb_W1 + (size_t)gg * 5 * H_;
            const float* eb1g = emb_b1 + (size_t)gg * H_;
            // kvadd[E,256] = relu(pad(attr)@eW1+eb1) @ [Ck|Cv] + [ckb|cvb]
            gemm128<0, false, true><<<dim3((E + 127) / 128, 2), 256, 0, stream>>>(
                nullptr, cW + (size_t)l * 128 * 256, cb + l * 256, nullptr, big,
                E, H_, 256, attrs[cf.ai], cf.aw, eW1g, eb1g);
            attn_fused<true><<<M_ / 4, 256, 0, stream>>>(offg, eidg, srcI, big, kx, vx, q, agg);
        } else {
            attn_fused<false><<<M_ / 4, 256, 0, stream>>>(offg, eidg, srcI, nullptr, kx, vx, q, agg);
        }

        // x = x + agg @ Wo ; FFN with pre-LN
        gemm128<0, true, false><<<dim3(M_ / 128, 1), 256, 0, stream>>>(
            agg, ga_Wo + l * HH, nullptr, m, m, M_, H_, H_, nullptr, 0, nullptr, nullptr);
        ln_kernel<<<M_ / 4, 256, 0, stream>>>(m, ga_g2 + l * H_, ga_b2 + l * H_, xd_ln, M_);
        gemm128<1, false, false><<<dim3(M_ / 128, FF_ / 128), 256, 0, stream>>>(
            xd_ln, ga_fW1 + (size_t)l * H_ * FF_, ga_fb1 + l * FF_, nullptr, big, M_, H_, FF_, nullptr, 0, nullptr, nullptr);
        gemm128<0, true, false><<<dim3(M_ / 128, 1), 256, 0, stream>>>(
            big, ga_fW2 + (size_t)l * FF_ * H_, ga_fb2 + l * H_, m, m, M_, FF_, H_, nullptr, 0, nullptr, nullptr);

        if (l == 4) {
            extract_last<<<(AK_ * H_ + 255) / 256, 256, 0, stream>>>(m, mlast);
            small_gemm<1, false><<<(AK_ * H_ + 255) / 256, 256, 0, stream>>>(mlast, tp_W1, tp_b1, nullptr, hbuf, AK_, H_, H_);
            small_gemm<0, false><<<(AK_ * P2F + 255) / 256, 256, 0, stream>>>(hbuf, tp_W2, tp_b2, nullptr, outp, AK_, H_, P2F);
            small_gemm<1, false><<<(AK_ * H_ + 255) / 256, 256, 0, stream>>>(outp, pa_W1, pa_b1, nullptr, hbuf, AK_, P2F, H_);
            small_gemm<0, false><<<(AK_ * H_ + 255) / 256, 256, 0, stream>>>(hbuf, pa_W2, pa_b2, nullptr, anchor, AK_, H_, H_);
            add_anchor<<<(M_ * H_ + 255) / 256, 256, 0, stream>>>(m, anchor);
        }
    }

    // refinement head: refine = proposal + MLP(n_last)
    extract_last<<<(AK_ * H_ + 255) / 256, 256, 0, stream>>>(m, mlast);
    small_gemm<1, false><<<(AK_ * H_ + 255) / 256, 256, 0, stream>>>(mlast, tr_W1, tr_b1, nullptr, hbuf, AK_, H_, H_);
    small_gemm<0, true><<<(AK_ * P2F + 255) / 256, 256, 0, stream>>>(hbuf, tr_W2, tr_b2, outp, outp + AK_ * P2F, AK_, H_, P2F);
}

// Round 3
// 4172.944 us; speedup vs baseline: 1.6748x; 1.1296x over previous
//
#include <hip/hip_runtime.h>
#include <hip/hip_bf16.h>
#include <math.h>

#define DEV __device__ __forceinline__

static constexpr int A_ = 64, T_ = 50, K_ = 6, H_ = 128, NH_ = 8, F_ = 60, L_ = 512;
static constexpr int M_  = A_ * T_ * K_;   // 19200 mode nodes
static constexpr int AT_ = A_ * T_;        // 3200
static constexpr int FF_ = 4 * H_;         // 512
static constexpr int NL_ = 10;
static constexpr int P2F = 2 * F_;         // 120
static constexpr int AK_ = A_ * K_;        // 384

// ======================= LayerNorm: one wave per row =======================
__global__ __launch_bounds__(256) void ln_kernel(const float* __restrict__ x,
                                                 const float* __restrict__ g,
                                                 const float* __restrict__ b,
                                                 float* __restrict__ y, int n) {
    int row = blockIdx.x * 4 + (threadIdx.x >> 6);
    int lane = threadIdx.x & 63;
    if (row >= n) return;
    const float* xr = x + (size_t)row * H_;
    float v0 = xr[lane], v1 = xr[lane + 64];
    float s = v0 + v1;
    for (int m = 32; m >= 1; m >>= 1) s += __shfl_xor(s, m, 64);
    float mu = s * (1.f / 128.f);
    float d0 = v0 - mu, d1 = v1 - mu;
    float vs = d0 * d0 + d1 * d1;
    for (int m = 32; m >= 1; m >>= 1) vs += __shfl_xor(vs, m, 64);
    float rs = rsqrtf(vs * (1.f / 128.f) + 1e-5f);
    float* yr = y + (size_t)row * H_;
    yr[lane]      = d0 * rs * g[lane] + b[lane];
    yr[lane + 64] = d1 * rs * g[lane + 64] + b[lane + 64];
}

// ====== 128x128-tile f32 GEMM, 8x8 microtile, BK=32, 256 threads ==========
template <int ACT, bool RES>
__global__ __launch_bounds__(256) void gemm128(const float* __restrict__ X,
                                               const float* __restrict__ W,
                                               const float* __restrict__ bias,
                                               const float* __restrict__ res,
                                               float* __restrict__ Y,
                                               int n, int Kd, int C) {
    __shared__ float Xs[128 * 36];
    __shared__ float Ws[32 * 128];
    int row0 = blockIdx.x * 128, col0 = blockIdx.y * 128;
    int tid = threadIdx.x;
    int tc = tid & 15, tr = tid >> 4;
    int cA = tc * 4;
    int rA = tr * 4;
    float acc[8][8] = {};
    for (int k0 = 0; k0 < Kd; k0 += 32) {
#pragma unroll
        for (int i = 0; i < 4; i++) {
            int idx = tid + i * 256;
            int r = idx >> 3, kc = idx & 7;
            float4 v = make_float4(0.f, 0.f, 0.f, 0.f);
            if (row0 + r < n)
                v = *(const float4*)(X + (size_t)(row0 + r) * Kd + k0 + kc * 4);
            *(float4*)(Xs + r * 36 + kc * 4) = v;
        }
#pragma unroll
        for (int i = 0; i < 4; i++) {
            int idx = tid + i * 256;
            int cc = idx & 31, kk = idx >> 5;
            *(float4*)(Ws + kk * 128 + cc * 4) =
                *(const float4*)(W + (size_t)(k0 + kk) * C + col0 + cc * 4);
        }
        __syncthreads();
#pragma unroll 8
        for (int kk = 0; kk < 32; kk++) {
            float4 w0 = *(const float4*)(Ws + kk * 128 + cA);
            float4 w1 = *(const float4*)(Ws + kk * 128 + cA + 64);
            float xr[8];
#pragma unroll
            for (int i = 0; i < 4; i++) {
                xr[i]     = Xs[(rA + i) * 36 + kk];
                xr[4 + i] = Xs[(rA + i + 64) * 36 + kk];
            }
#pragma unroll
            for (int i = 0; i < 8; i++) {
                float x = xr[i];
                acc[i][0] = fmaf(x, w0.x, acc[i][0]);
                acc[i][1] = fmaf(x, w0.y, acc[i][1]);
                acc[i][2] = fmaf(x, w0.z, acc[i][2]);
                acc[i][3] = fmaf(x, w0.w, acc[i][3]);
                acc[i][4] = fmaf(x, w1.x, acc[i][4]);
                acc[i][5] = fmaf(x, w1.y, acc[i][5]);
                acc[i][6] = fmaf(x, w1.z, acc[i][6]);
                acc[i][7] = fmaf(x, w1.w, acc[i][7]);
            }
        }
        __syncthreads();
    }
    float4 bv0 = make_float4(0.f, 0.f, 0.f, 0.f), bv1 = bv0;
    if (bias) {
        bv0 = *(const float4*)(bias + col0 + cA);
        bv1 = *(const float4*)(bias + col0 + cA + 64);
    }
#pragma unroll
    for (int i = 0; i < 8; i++) {
        int r = row0 + ((i < 4) ? (rA + i) : (rA + i + 60));
        if (r >= n) continue;
#pragma unroll
        for (int ch = 0; ch < 2; ch++) {
            int col = col0 + cA + ch * 64;
            size_t off = (size_t)r * C + col;
            float4 bvv = ch ? bv1 : bv0;
            float4 o;
            o.x = acc[i][ch * 4 + 0] + bvv.x;
            o.y = acc[i][ch * 4 + 1] + bvv.y;
            o.z = acc[i][ch * 4 + 2] + bvv.z;
            o.w = acc[i][ch * 4 + 3] + bvv.w;
            if (ACT == 1) { o.x = fmaxf(o.x, 0.f); o.y = fmaxf(o.y, 0.f);
                            o.z = fmaxf(o.z, 0.f); o.w = fmaxf(o.w, 0.f); }
            if (RES) { float4 rv = *(const float4*)(res + off);
                       o.x += rv.x; o.y += rv.y; o.z += rv.z; o.w += rv.w; }
            *(float4*)(Y + off) = o;
        }
    }
}

// ============== naive GEMM for small/ragged shapes =========================
template <int ACT, bool RES>
__global__ void small_gemm(const float* __restrict__ X, const float* __restrict__ W,
                           const float* __restrict__ bias, const float* __restrict__ res,
                           float* __restrict__ Y, int n, int Kd, int C) {
    int idx = blockIdx.x * 256 + threadIdx.x;
    if (idx >= n * C) return;
    int row = idx / C, c = idx - row * C;
    float a = bias ? bias[c] : 0.f;
    const float* xr = X + (size_t)row * Kd;
    for (int k = 0; k < Kd; k++) a = fmaf(xr[k], W[(size_t)k * C + c], a);
    if (ACT == 1) a = fmaxf(a, 0.f);
    if (RES) a += res[idx];
    Y[idx] = a;
}

// ==== combined weights: cW[l][c'][0:128]=Ck=eW2@Wke, [128:256]=Cv=eW2@Wve ==
__global__ __launch_bounds__(256) void combine_all(const float* __restrict__ eW2,
                                                   const float* __restrict__ eb2,
                                                   const float* __restrict__ Wke,
                                                   const float* __restrict__ Wve,
                                                   float* __restrict__ cW,
                                                   float* __restrict__ cb) {
    int li = blockIdx.x;              // 0..7
    int l = li < 4 ? li : li + 1;     // layers 0,1,2,3,5,6,7,8
    int g = (li & 3) + 1;             // emb idx 1..4
    int c = threadIdx.x;              // 0..255
    int isV = c >> 7, cc = c & 127;
    const size_t HH = (size_t)H_ * H_;
    const float* Wsrc = (isV ? Wve : Wke) + (size_t)l * HH;
    const float* E2 = eW2 + (size_t)g * HH;
    int k0 = blockIdx.y * 32;
    for (int k = k0; k < k0 + 32; k++) {
        float a = 0.f;
        for (int j = 0; j < 128; j++) a = fmaf(E2[k * 128 + j], Wsrc[(size_t)j * 128 + cc], a);
        cW[(size_t)l * 128 * 256 + (size_t)k * 256 + c] = a;
    }
    if (blockIdx.y == 0) {
        float a = 0.f;
        const float* eb = eb2 + g * 128;
        for (int j = 0; j < 128; j++) a = fmaf(eb[j], Wsrc[(size_t)j * 128 + cc], a);
        cb[l * 256 + c] = a;
    }
}

// ============================ CSR construction =============================
__global__ void zero_i32(int* __restrict__ p, int n) {
    int i = blockIdx.x * 256 + threadIdx.x;
    if (i < n) p[i] = 0;
}
__global__ void hist_kernel(const int* __restrict__ dst, int E, int* __restrict__ deg) {
    int e = blockIdx.x * 256 + threadIdx.x;
    if (e < E) atomicAdd(&deg[dst[e]], 1);
}
__global__ __launch_bounds__(256) void exscan_kernel(const int* __restrict__ deg,
                                                     int* __restrict__ off,
                                                     int* __restrict__ cursor, int n) {
    __shared__ int wsum[4];
    __shared__ int carry;
    int tid = threadIdx.x, lane = tid & 63, w = tid >> 6;
    if (tid == 0) carry = 0;
    __syncthreads();
    for (int base = 0; base < n; base += 256) {
        int v = (base + tid < n) ? deg[base + tid] : 0;
        int incl = v;
        for (int d = 1; d < 64; d <<= 1) {
            int t = __shfl_up(incl, d, 64);
            if (lane >= d) incl += t;
        }
        if (lane == 63) wsum[w] = incl;
        __syncthreads();
        int woff = 0;
        for (int i = 0; i < w; i++) woff += wsum[i];
        int total = wsum[0] + wsum[1] + wsum[2] + wsum[3];
        int excl = carry + woff + incl - v;
        if (base + tid < n) { off[base + tid] = excl; cursor[base + tid] = excl; }
        __syncthreads();
        if (tid == 0) carry += total;
        __syncthreads();
    }
    if (threadIdx.x == 0) off[n] = carry;
}
__global__ void scatter_kernel(const int* __restrict__ dst, int E,
                               int* __restrict__ cursor, int* __restrict__ eids) {
    int e = blockIdx.x * 256 + threadIdx.x;
    if (e < E) { int p = atomicAdd(&cursor[dst[e]], 1); eids[p] = e; }
}
// gather src/attr into CSR order (padded float4 attr)
__global__ void sort_edges(const int* __restrict__ eid, const int* __restrict__ srcArr,
                           const float* __restrict__ attr, int aw, int E,
                           int* __restrict__ esrc, float4* __restrict__ eattr) {
    int pos = blockIdx.x * 256 + threadIdx.x;
    if (pos >= E) return;
    int e = eid[pos];
    esrc[pos] = srcArr[e];
    if (attr) {
        float4 v;
        v.x = attr[(size_t)e * aw + 0];
        v.y = attr[(size_t)e * aw + 1];
        v.z = (aw > 2) ? attr[(size_t)e * aw + 2] : 0.f;
        v.w = (aw > 3) ? attr[(size_t)e * aw + 3] : 0.f;
        eattr[pos] = v;
    }
}

// ====== prep_g: g[d, h*128+c'] = 0.25 * sum_t Ck[c'][16h+t] q[d][16h+t] ====
//        sb[d,h] = 0.25 * sum_t ckb[16h+t] q[d][16h+t]
__global__ __launch_bounds__(256) void prep_g(const float* __restrict__ q,
                                              const float* __restrict__ cWl,
                                              const float* __restrict__ cbl,
                                              float* __restrict__ g,
                                              float* __restrict__ sb) {
    __shared__ float Cks[128 * 132];
    __shared__ float qs[128];
    int tid = threadIdx.x;
    {
        int cp = tid >> 1, cb0 = (tid & 1) * 64;
#pragma unroll
        for (int kq = 0; kq < 16; kq++)
            *(float4*)(Cks + cp * 132 + cb0 + kq * 4) =
                *(const float4*)(cWl + (size_t)cp * 256 + cb0 + kq * 4);
    }
    int cp = tid & 127, hb = (tid >> 7) * 4;
    for (int d = blockIdx.x; d < M_; d += gridDim.x) {
        __syncthreads();
        if (tid < 32) *(float4*)(qs + tid * 4) = *(const float4*)(q + (size_t)d * 128 + tid * 4);
        __syncthreads();
#pragma unroll
        for (int h = hb; h < hb + 4; h++) {
            float a = 0.f;
#pragma unroll
            for (int jq = 0; jq < 4; jq++) {
                float4 ck = *(float4*)(Cks + cp * 132 + h * 16 + jq * 4);
                float4 qv = *(float4*)(qs + h * 16 + jq * 4);
                a = fmaf(ck.x, qv.x, a); a = fmaf(ck.y, qv.y, a);
                a = fmaf(ck.z, qv.z, a); a = fmaf(ck.w, qv.w, a);
            }
            g[(size_t)d * 1024 + h * 128 + cp] = a * 0.25f;
        }
        if (tid < 8) {
            float a = 0.f;
#pragma unroll
            for (int t16 = 0; t16 < 16; t16++)
                a = fmaf(cbl[tid * 16 + t16], qs[tid * 16 + t16], a);
            sb[d * 8 + tid] = a * 0.25f;
        }
    }
}

// ===== factorized fused attention (edge-emb layers): one wave per dst ======
// outputs: hsum[M,1024] (unnormalized attn-weighted h), vxacc[M,128], den[M,8]
__global__ __launch_bounds__(256) void attn_fact(const int* __restrict__ off,
                                                 const int* __restrict__ esrc,
                                                 const float4* __restrict__ eattr,
                                                 const float* __restrict__ g,
                                                 const float* __restrict__ sb,
                                                 const float* __restrict__ eW1,
                                                 const float* __restrict__ eb1,
                                                 const float* __restrict__ kx,
                                                 const float* __restrict__ vx,
                                                 const float* __restrict__ q,
                                                 float* __restrict__ hsum,
                                                 float* __restrict__ vxacc,
                                                 float* __restrict__ den) {
    __shared__ float lds[4 * 144];
    int w = threadIdx.x >> 6, l = threadIdx.x & 63;
    int i = l & 15, hlo = l >> 4;
    float* hw = lds + w * 144;            // [0..127] h_e, [128..143] w/c bcast
    int d = blockIdx.x * 4 + w;
    int beg = off[d], end = off[d + 1];
    float q0 = q[(size_t)d * 128 + l] * 0.25f;
    float q1 = q[(size_t)d * 128 + 64 + l] * 0.25f;
    float gA[8], gB[8];
#pragma unroll
    for (int j = 0; j < 8; j++) {
        gA[j] = g[(size_t)d * 1024 + hlo * 128 + j * 16 + i];
        gB[j] = g[(size_t)d * 1024 + (hlo + 4) * 128 + j * 16 + i];
    }
    float sbA = sb[d * 8 + hlo], sbB = sb[d * 8 + 4 + hlo];
    float w1a[4], w1b[4];
#pragma unroll
    for (int j = 0; j < 4; j++) { w1a[j] = eW1[j * 128 + l]; w1b[j] = eW1[j * 128 + 64 + l]; }
    float ebA = eb1[l], ebB = eb1[64 + l];
    float mA = -INFINITY, mB = -INFINITY, dnA = 0.f, dnB = 0.f;
    float accL[8] = {}, accH[8] = {};
    float va0 = 0.f, va1 = 0.f;
    int sN = 0; float4 aN = make_float4(0.f, 0.f, 0.f, 0.f);
    if (beg < end) { sN = esrc[beg]; aN = eattr[beg]; }
    for (int pos = beg; pos < end; pos++) {
        int s = sN; float4 at = aN;
        const float* kxr = kx + (size_t)s * 128;
        const float* vxr = vx + (size_t)s * 128;
        float k0 = kxr[l], k1 = kxr[64 + l];
        float v0 = vxr[l], v1 = vxr[64 + l];
        if (pos + 1 < end) { sN = esrc[pos + 1]; aN = eattr[pos + 1]; }
        float h0 = fmaxf(ebA + at.x * w1a[0] + at.y * w1a[1] + at.z * w1a[2] + at.w * w1a[3], 0.f);
        float h1 = fmaxf(ebB + at.x * w1b[0] + at.y * w1b[1] + at.z * w1b[2] + at.w * w1b[3], 0.f);
        hw[l] = h0; hw[64 + l] = h1;
        __builtin_amdgcn_wave_barrier();
        float pA = q0 * k0, pB = q1 * k1;
#pragma unroll
        for (int j = 0; j < 8; j++) {
            float hv = hw[j * 16 + i];
            pA = fmaf(hv, gA[j], pA);
            pB = fmaf(hv, gB[j], pB);
        }
#pragma unroll
        for (int msk = 1; msk < 16; msk <<= 1) {
            pA += __shfl_xor(pA, msk, 64);
            pB += __shfl_xor(pB, msk, 64);
        }
        pA += sbA; pB += sbB;
        float nmA = fmaxf(mA, pA), nmB = fmaxf(mB, pB);
        float cA = __expf(mA - nmA), cB = __expf(mB - nmB);
        float wA = __expf(pA - nmA), wB = __expf(pB - nmB);
        mA = nmA; mB = nmB;
        dnA = dnA * cA + wA; dnB = dnB * cB + wB;
        va0 = va0 * cA + wA * v0; va1 = va1 * cB + wB * v1;
        if (i == 0) {
            hw[128 + hlo] = wA; hw[132 + hlo] = wB;
            hw[136 + hlo] = cA; hw[140 + hlo] = cB;
        }
        __builtin_amdgcn_wave_barrier();
        float4 wv0 = *(float4*)(hw + 128), wv1 = *(float4*)(hw + 132);
        float4 cv0 = *(float4*)(hw + 136), cv1 = *(float4*)(hw + 140);
        accL[0] = fmaf(accL[0], cv0.x, wv0.x * h0); accH[0] = fmaf(accH[0], cv0.x, wv0.x * h1);
        accL[1] = fmaf(accL[1], cv0.y, wv0.y * h0); accH[1] = fmaf(accH[1], cv0.y, wv0.y * h1);
        accL[2] = fmaf(accL[2], cv0.z, wv0.z * h0); accH[2] = fmaf(accH[2], cv0.z, wv0.z * h1);
        accL[3] = fmaf(accL[3], cv0.w, wv0.w * h0); accH[3] = fmaf(accH[3], cv0.w, wv0.w * h1);
        accL[4] = fmaf(accL[4], cv1.x, wv1.x * h0); accH[4] = fmaf(accH[4], cv1.x, wv1.x * h1);
        accL[5] = fmaf(accL[5], cv1.y, wv1.y * h0); accH[5] = fmaf(accH[5], cv1.y, wv1.y * h1);
        accL[6] = fmaf(accL[6], cv1.z, wv1.z * h0); accH[6] = fmaf(accH[6], cv1.z, wv1.z * h1);
        accL[7] = fmaf(accL[7], cv1.w, wv1.w * h0); accH[7] = fmaf(accH[7], cv1.w, wv1.w * h1);
    }
#pragma unroll
    for (int h = 0; h < 8; h++) {
        hsum[(size_t)d * 1024 + h * 128 + l]      = accL[h];
        hsum[(size_t)d * 1024 + h * 128 + 64 + l] = accH[h];
    }
    vxacc[(size_t)d * 128 + l] = va0;
    vxacc[(size_t)d * 128 + 64 + l] = va1;
    if (i == 0) { den[d * 8 + hlo] = dnA; den[d * 8 + 4 + hlo] = dnB; }
}

// ========= plain fused attention (no edge emb): one wave per dst ===========
__global__ __launch_bounds__(256) void attn_plain(const int* __restrict__ off,
                                                  const int* __restrict__ esrc,
                                                  const float* __restrict__ kx,
                                                  const float* __restrict__ vx,
                                                  const float* __restrict__ q,
                                                  float* __restrict__ agg) {
    int w = threadIdx.x >> 6, lane = threadIdx.x & 63;
    int d = blockIdx.x * 4 + w;
    int beg = off[d], end = off[d + 1];
    float q0 = q[(size_t)d * 128 + lane] * 0.25f;
    float q1 = q[(size_t)d * 128 + 64 + lane] * 0.25f;
    float m0 = -INFINITY, m1 = -INFINITY;
    float den0 = 0.f, den1 = 0.f, acc0 = 0.f, acc1 = 0.f;
    int sN = (beg < end) ? esrc[beg] : 0;
    for (int pos = beg; pos < end; pos++) {
        int s = sN;
        const float* kxr = kx + (size_t)s * 128;
        const float* vxr = vx + (size_t)s * 128;
        float k0 = kxr[lane], k1 = kxr[64 + lane];
        float v0 = vxr[lane], v1 = vxr[64 + lane];
        if (pos + 1 < end) sN = esrc[pos + 1];
        float p0 = q0 * k0, p1 = q1 * k1;
#pragma unroll
        for (int msk = 1; msk < 16; msk <<= 1) {
            p0 += __shfl_xor(p0, msk, 64);
            p1 += __shfl_xor(p1, msk, 64);
        }
        float nm0 = fmaxf(m0, p0), nm1 = fmaxf(m1, p1);
        float c0 = __expf(m0 - nm0), c1 = __expf(m1 - nm1);
        float e0 = __expf(p0 - nm0), e1 = __expf(p1 - nm1);
        acc0 = acc0 * c0 + e0 * v0; den0 = den0 * c0 + e0;
        acc1 = acc1 * c1 + e1 * v1; den1 = den1 * c1 + e1;
        m0 = nm0; m1 = nm1;
    }
    agg[(size_t)d * 128 + lane]      = acc0 / (den0 + 1e-9f);
    agg[(size_t)d * 128 + 64 + lane] = acc1 / (den1 + 1e-9f);
}

// ====== epilogue: agg = (vxacc + hsum @ blockdiag(Cv)) * inv + cvb * cf ====
static constexpr int HST_ = 1092;   // pad: 1092%32=4 -> 2-way max with h-stride 136
__global__ __launch_bounds__(256) void agg_fin(const float* __restrict__ hsum,
                                               const float* __restrict__ vxacc,
                                               const float* __restrict__ den,
                                               const float* __restrict__ cWl,
                                               const float* __restrict__ cbl,
                                               float* __restrict__ agg) {
    __shared__ float Cvs[128 * 128];
    __shared__ float hstage[8 * HST_];
    __shared__ float dens[64];
    int tid = threadIdx.x;
    {
        int cp = tid >> 1, cb0 = (tid & 1) * 64;
#pragma unroll
        for (int kq = 0; kq < 16; kq++)
            *(float4*)(Cvs + cp * 128 + cb0 + kq * 4) =
                *(const float4*)(cWl + (size_t)cp * 256 + 128 + cb0 + kq * 4);
    }
    int j = tid & 31, dsel = tid >> 5;
    int c4 = j * 4, h = j >> 2;
    float4 cvb = *(const float4*)(cbl + 128 + c4);
    for (int d0 = blockIdx.x * 8; d0 < M_; d0 += gridDim.x * 8) {
        __syncthreads();
        int r = tid * 4;
#pragma unroll
        for (int k = 0; k < 8; k++) {
            *(float4*)(hstage + k * HST_ + (r >> 7) * 136 + (r & 127)) =
                *(const float4*)(hsum + (size_t)(d0 + k) * 1024 + r);
        }
        if (tid < 64) dens[tid] = den[d0 * 8 + tid];
        __syncthreads();
        int d = d0 + dsel;
        float dn = dens[dsel * 8 + h];
        float inv = 1.f / (dn + 1e-9f);
        float cf = dn * inv;
        float a0 = 0.f, a1 = 0.f, a2 = 0.f, a3 = 0.f;
        const float* hrow = hstage + dsel * HST_ + h * 136;
#pragma unroll 4
        for (int cpp = 0; cpp < 128; cpp++) {
            float hs = hrow[cpp];
            float4 cv = *(float4*)(Cvs + cpp * 128 + c4);
            a0 = fmaf(hs, cv.x, a0); a1 = fmaf(hs, cv.y, a1);
            a2 = fmaf(hs, cv.z, a2); a3 = fmaf(hs, cv.w, a3);
        }
        float4 vv = *(const float4*)(vxacc + (size_t)d * 128 + c4);
        float4 o;
        o.x = (vv.x + a0) * inv + cvb.x * cf;
        o.y = (vv.y + a1) * inv + cvb.y * cf;
        o.z = (vv.z + a2) * inv + cvb.z * cf;
        o.w = (vv.w + a3) * inv + cvb.w * cf;
        *(float4*)(agg + (size_t)d * 128 + c4) = o;
    }
}

// ======================= small glue kernels ================================
__global__ void mode_init(float* __restrict__ m, const float* __restrict__ mt) {
    int idx = blockIdx.x * 256 + threadIdx.x;
    if (idx >= M_ * H_) return;
    int node = idx >> 7, c = idx & 127;
    m[idx] = mt[(node % K_) * H_ + c];
}
__global__ void extract_last(const float* __restrict__ m, float* __restrict__ out) {
    int idx = blockIdx.x * 256 + threadIdx.x;
    if (idx >= AK_ * H_) return;
    int row = idx >> 7, c = idx & 127;
    int a = row / K_, k = row - a * K_;
    int node = (a * T_ + (T_ - 1)) * K_ + k;
    out[idx] = m[(size_t)node * H_ + c];
}
__global__ void add_anchor(float* __restrict__ m, const float* __restrict__ anchor) {
    int idx = blockIdx.x * 256 + threadIdx.x;
    if (idx >= M_ * H_) return;
    int node = idx >> 7, c = idx & 127;
    int a = node / (T_ * K_), k = node % K_;
    m[idx] += anchor[(size_t)(a * K_ + k) * H_ + c];
}

// ============================ host launch ==================================
extern "C" void kernel_launch(void* const* d_in, const int* in_sizes, int n_in,
                              void* d_out, int out_size, void* d_ws, size_t ws_size,
                              hipStream_t stream) {
    const float* a_input     = (const float*)d_in[0];
    const float* l_embs      = (const float*)d_in[1];
    const float* mode_tokens = (const float*)d_in[2];
    const float* emb_W1 = (const float*)d_in[3];
    const float* emb_b1 = (const float*)d_in[4];
    const float* emb_W2 = (const float*)d_in[5];
    const float* emb_b2 = (const float*)d_in[6];
    const float* ga_Wq  = (const float*)d_in[7];
    const float* ga_Wk  = (const float*)d_in[8];
    const float* ga_Wv  = (const float*)d_in[9];
    const float* ga_Wo  = (const float*)d_in[10];
    const float* ga_Wke = (const float*)d_in[11];
    const float* ga_Wve = (const float*)d_in[12];
    const float* ga_g1  = (const float*)d_in[13];
    const float* ga_b1  = (const float*)d_in[14];
    const float* ga_g2  = (const float*)d_in[15];
    const float* ga_b2  = (const float*)d_in[16];
    const float* ga_fW1 = (const float*)d_in[17];
    const float* ga_fb1 = (const float*)d_in[18];
    const float* ga_fW2 = (const float*)d_in[19];
    const float* ga_fb2 = (const float*)d_in[20];
    const float* tp_W1 = (const float*)d_in[21];
    const float* tp_b1 = (const float*)d_in[22];
    const float* tp_W2 = (const float*)d_in[23];
    const float* tp_b2 = (const float*)d_in[24];
    const float* pa_W1 = (const float*)d_in[25];
    const float* pa_b1 = (const float*)d_in[26];
    const float* pa_W2 = (const float*)d_in[27];
    const float* pa_b2 = (const float*)d_in[28];
    const float* tr_W1 = (const float*)d_in[29];
    const float* tr_b1 = (const float*)d_in[30];
    const float* tr_W2 = (const float*)d_in[31];
    const float* tr_b2 = (const float*)d_in[32];
    const float* attrs[4] = { (const float*)d_in[33], (const float*)d_in[34],
                              (const float*)d_in[35], (const float*)d_in[36] };
    const int* eis[5] = { (const int*)d_in[37], (const int*)d_in[38], (const int*)d_in[39],
                          (const int*)d_in[40], (const int*)d_in[41] };
    int Es[5];
    int Emax = 0;
    for (int i = 0; i < 5; i++) { Es[i] = in_sizes[37 + i] / 2; if (Es[i] > Emax) Emax = Es[i]; }

    size_t off = 0;
    auto alloc = [&](size_t nbytes) -> char* {
        char* p = (char*)d_ws + off;
        off += ((nbytes + 255) / 256) * 256;
        return p;
    };
    float* cW     = (float*)alloc((size_t)NL_ * 128 * 256 * 4);
    float* cb     = (float*)alloc((size_t)NL_ * 256 * 4);
    float* a_embs = (float*)alloc((size_t)AT_ * H_ * 4);
    float* m      = (float*)alloc((size_t)M_ * H_ * 4);
    float* xd_ln  = (float*)alloc((size_t)M_ * H_ * 4);
    float* xs_ln  = (float*)alloc((size_t)AT_ * H_ * 4);
    float* q      = (float*)alloc((size_t)M_ * H_ * 4);
    float* kx     = (float*)alloc((size_t)M_ * H_ * 4);
    float* vx     = (float*)alloc((size_t)M_ * H_ * 4);
    float* agg    = (float*)alloc((size_t)M_ * H_ * 4);
    float* big    = (float*)alloc((size_t)M_ * 1024 * 4);   // g / FFN hidden
    float* hsum   = (float*)alloc((size_t)M_ * 1024 * 4);
    float* vxacc  = (float*)alloc((size_t)M_ * H_ * 4);
    float* den    = (float*)alloc((size_t)M_ * 8 * 4);
    float* sb     = (float*)alloc((size_t)M_ * 8 * 4);
    int* csr_off  = (int*)alloc((size_t)5 * (M_ + 1) * 4);
    int* csr_eid  = (int*)alloc((size_t)5 * Emax * 4);
    int* esrc     = (int*)alloc((size_t)5 * Emax * 4);
    float4* eattr = (float4*)alloc((size_t)4 * Emax * 16);
    int* deg      = (int*)alloc((size_t)M_ * 4);
    int* cursor   = (int*)alloc((size_t)M_ * 4);
    float* mlast  = (float*)alloc((size_t)AK_ * H_ * 4);
    float* hbuf   = (float*)alloc((size_t)AK_ * H_ * 4);
    float* anchor = (float*)alloc((size_t)AK_ * H_ * 4);
    (void)ws_size; (void)n_in;

    const size_t HH = (size_t)H_ * H_;
    float* outp = (float*)d_out;

    // ---- CSR + sorted src/attr for 5 graphs ----
    for (int gI = 0; gI < 5; gI++) {
        int E = Es[gI];
        const int* srcI = eis[gI];
        const int* dstI = eis[gI] + E;
        int* offg = csr_off + gI * (M_ + 1);
        int* eidg = csr_eid + (size_t)gI * Emax;
        zero_i32<<<(M_ + 255) / 256, 256, 0, stream>>>(deg, M_);
        hist_kernel<<<(E + 255) / 256, 256, 0, stream>>>(dstI, E, deg);
        exscan_kernel<<<1, 256, 0, stream>>>(deg, offg, cursor, M_);
        scatter_kernel<<<(E + 255) / 256, 256, 0, stream>>>(dstI, E, cursor, eidg);
        int aw = (gI == 0 || gI == 2) ? 4 : (gI == 4 ? 0 : 3);
        sort_edges<<<(E + 255) / 256, 256, 0, stream>>>(
            eidg, srcI, (gI < 4) ? attrs[gI] : nullptr, aw, E,
            esrc + (size_t)gI * Emax, eattr + (size_t)gI * Emax);
    }

    // ---- setup ----
    combine_all<<<dim3(8, 4), 256, 0, stream>>>(emb_W2, emb_b2, ga_Wke, ga_Wve, cW, cb);
    small_gemm<1, false><<<(AT_ * H_ + 255) / 256, 256, 0, stream>>>(a_input, emb_W1, emb_b1, nullptr, big, AT_, 5, H_);
    small_gemm<0, false><<<(AT_ * H_ + 255) / 256, 256, 0, stream>>>(big, emb_W2, emb_b2, nullptr, a_embs, AT_, H_, H_);
    mode_init<<<(M_ * H_ + 255) / 256, 256, 0, stream>>>(m, mode_tokens);

    struct Cfg { const float* srcX; int n_src; int gi; bool hasE; };
    Cfg cfgs[10] = {
        { a_embs, AT_, 0, true }, { l_embs, L_, 1, true },
        { nullptr, M_, 2, true }, { nullptr, M_, 3, true },
        { nullptr, M_, 4, false },
        { a_embs, AT_, 0, true }, { l_embs, L_, 1, true },
        { nullptr, M_, 2, true }, { nullptr, M_, 3, true },
        { nullptr, M_, 4, false },
    };

    for (int l = 0; l < 10; l++) {
        const Cfg& cf = cfgs[l];
        const int* offg = csr_off + cf.gi * (M_ + 1);
        const int* esrcg = esrc + (size_t)cf.gi * Emax;
        const float4* eattrg = eattr + (size_t)cf.gi * Emax;
        const float* g1 = ga_g1 + l * H_; const float* b1 = ga_b1 + l * H_;

        ln_kernel<<<M_ / 4, 256, 0, stream>>>(m, g1, b1, xd_ln, M_);
        gemm128<0, false><<<dim3(M_ / 128, 1), 256, 0, stream>>>(
            xd_ln, ga_Wq + l * HH, nullptr, nullptr, q, M_, H_, H_);
        const float* srcLN = xd_ln;
        if (cf.srcX) {
            ln_kernel<<<cf.n_src / 4, 256, 0, stream>>>(cf.srcX, g1, b1, xs_ln, cf.n_src);
            srcLN = xs_ln;
        }
        gemm128<0, false><<<dim3(cf.n_src / 128, 1), 256, 0, stream>>>(
            srcLN, ga_Wk + l * HH, nullptr, nullptr, kx, cf.n_src, H_, H_);
        gemm128<0, false><<<dim3(cf.n_src / 128, 1), 256, 0, stream>>>(
            srcLN, ga_Wv + l * HH, nullptr, nullptr, vx, cf.n_src, H_, H_);

        if (cf.hasE) {
            int gg = (l < 5) ? l + 1 : l - 4;
            const float* eW1g = emb_W1 + (size_t)gg * 5 * H_;
            const float* eb1g = emb_b1 + (size_t)gg * H_;
            prep_g<<<512, 256, 0, stream>>>(q, cW + (size_t)l * 128 * 256, cb + l * 256, big, sb);
            attn_fact<<<M_ / 4, 256, 0, stream>>>(offg, esrcg, eattrg, big, sb, eW1g, eb1g,
                                                  kx, vx, q, hsum, vxacc, den);
            agg_fin<<<256, 256, 0, stream>>>(hsum, vxacc, den,
                                             cW + (size_t)l * 128 * 256, cb + l * 256, agg);
        } else {
            attn_plain<<<M_ / 4, 256, 0, stream>>>(offg, esrcg, kx, vx, q, agg);
        }

        gemm128<0, true><<<dim3(M_ / 128, 1), 256, 0, stream>>>(
            agg, ga_Wo + l * HH, nullptr, m, m, M_, H_, H_);
        ln_kernel<<<M_ / 4, 256, 0, stream>>>(m, ga_g2 + l * H_, ga_b2 + l * H_, xd_ln, M_);
        gemm128<1, false><<<dim3(M_ / 128, FF_ / 128), 256, 0, stream>>>(
            xd_ln, ga_fW1 + (size_t)l * H_ * FF_, ga_fb1 + l * FF_, nullptr, big, M_, H_, FF_);
        gemm128<0, true><<<dim3(M_ / 128, 1), 256, 0, stream>>>(
            big, ga_fW2 + (size_t)l * FF_ * H_, ga_fb2 + l * H_, m, m, M_, FF_, H_);

        if (l == 4) {
            extract_last<<<(AK_ * H_ + 255) / 256, 256, 0, stream>>>(m, mlast);
            small_gemm<1, false><<<(AK_ * H_ + 255) / 256, 256, 0, stream>>>(mlast, tp_W1, tp_b1, nullptr, hbuf, AK_, H_, H_);
            small_gemm<0, false><<<(AK_ * P2F + 255) / 256, 256, 0, stream>>>(hbuf, tp_W2, tp_b2, nullptr, outp, AK_, H_, P2F);
            small_gemm<1, false><<<(AK_ * H_ + 255) / 256, 256, 0, stream>>>(outp, pa_W1, pa_b1, nullptr, hbuf, AK_, P2F, H_);
            small_gemm<0, false><<<(AK_ * H_ + 255) / 256, 256, 0, stream>>>(hbuf, pa_W2, pa_b2, nullptr, anchor, AK_, H_, H_);
            add_anchor<<<(M_ * H_ + 255) / 256, 256, 0, stream>>>(m, anchor);
        }
    }

    extract_last<<<(AK_ * H_ + 255) / 256, 256, 0, stream>>>(m, mlast);
    small_gemm<1, false><<<(AK_ * H_ + 255) / 256, 256, 0, stream>>>(mlast, tr_W1, tr_b1, nullptr, hbuf, AK_, H_, H_);
    small_gemm<0, true><<<(AK_ * P2F + 255) / 256, 256, 0, stream>>>(hbuf, tr_W2, tr_b2, outp, outp + AK_ * P2F, AK_, H_, P2F);
}

// Round 4
// 2968.562 us; speedup vs baseline: 2.3543x; 1.4057x over previous
//
#include <hip/hip_runtime.h>
#include <hip/hip_bf16.h>
#include <math.h>

#define DEV __device__ __forceinline__

typedef __attribute__((ext_vector_type(4))) float floatx4;
typedef __attribute__((ext_vector_type(8))) __bf16 bf16x8;

static constexpr int A_ = 64, T_ = 50, K_ = 6, H_ = 128, NH_ = 8, F_ = 60, L_ = 512;
static constexpr int M_  = A_ * T_ * K_;   // 19200 mode nodes
static constexpr int AT_ = A_ * T_;        // 3200
static constexpr int FF_ = 4 * H_;         // 512
static constexpr int NL_ = 10;
static constexpr int P2F = 2 * F_;         // 120
static constexpr int AK_ = A_ * K_;        // 384
static constexpr size_t WLAY = 196608;     // per-layer transposed-weight elems

// ---- bf16 split helpers ----
DEV ushort f2bh(float f) {                 // RNE float->bf16 bits
    unsigned u = __float_as_uint(f);
    unsigned r = u + 0x7FFFu + ((u >> 16) & 1u);
    return (ushort)(r >> 16);
}
DEV float bh2f(ushort h) { return __uint_as_float(((unsigned)h) << 16); }

// ======================= LayerNorm: one wave per row =======================
__global__ __launch_bounds__(256) void ln_kernel(const float* __restrict__ x,
                                                 const float* __restrict__ g,
                                                 const float* __restrict__ b,
                                                 float* __restrict__ y, int n) {
    int row = blockIdx.x * 4 + (threadIdx.x >> 6);
    int lane = threadIdx.x & 63;
    if (row >= n) return;
    const float* xr = x + (size_t)row * H_;
    float v0 = xr[lane], v1 = xr[lane + 64];
    float s = v0 + v1;
    for (int m = 32; m >= 1; m >>= 1) s += __shfl_xor(s, m, 64);
    float mu = s * (1.f / 128.f);
    float d0 = v0 - mu, d1 = v1 - mu;
    float vs = d0 * d0 + d1 * d1;
    for (int m = 32; m >= 1; m >>= 1) vs += __shfl_xor(vs, m, 64);
    float rs = rsqrtf(vs * (1.f / 128.f) + 1e-5f);
    float* yr = y + (size_t)row * H_;
    yr[lane]      = d0 * rs * g[lane] + b[lane];
    yr[lane + 64] = d1 * rs * g[lane + 64] + b[lane + 64];
}

// ====== split-bf16 MFMA GEMM: Y = act(X @ W + bias) (+res) ================
// X f32 [n][Kd]; W pre-transposed bf16 hi/lo [C][Kd]. n%128==0, Kd%64==0,
// C%128==0. 128x128 tile, 4 waves, 16x16x32 MFMA, 3-term split precision.
template <int ACT, bool RES>
__global__ __launch_bounds__(256) void mgemm(const float* __restrict__ X,
                                             const ushort* __restrict__ Wh,
                                             const ushort* __restrict__ Wl,
                                             const float* __restrict__ bias,
                                             const float* __restrict__ res,
                                             float* __restrict__ Y,
                                             int n, int Kd, int C) {
    __shared__ ushort lds[4 * 8192];           // Xh,Xl,Wsh,Wsl: [128][64] each
    ushort* Xh  = lds;
    ushort* Xl  = lds + 8192;
    ushort* Wsh = lds + 16384;
    ushort* Wsl = lds + 24576;
    int row0 = blockIdx.x * 128, col0 = blockIdx.y * 128;
    int tid = threadIdx.x;
    int lane = tid & 63, wid = tid >> 6;
    int rbase = (wid >> 1) * 64, cbase = (wid & 1) * 64;
    int lrow = lane & 15, lk = lane >> 4;
    floatx4 acc[4][4];
#pragma unroll
    for (int a = 0; a < 4; a++)
#pragma unroll
        for (int b2 = 0; b2 < 4; b2++) acc[a][b2] = floatx4{0.f, 0.f, 0.f, 0.f};

    for (int k0 = 0; k0 < Kd; k0 += 64) {
        // stage X (f32 -> hi/lo bf16), chunk-swizzled
#pragma unroll
        for (int i = 0; i < 8; i++) {
            int idx = tid + i * 256;
            int r = idx >> 4, kc = idx & 15;
            float4 v = *(const float4*)(X + (size_t)(row0 + r) * Kd + k0 + kc * 4);
            ushort h0 = f2bh(v.x), h1 = f2bh(v.y), h2 = f2bh(v.z), h3 = f2bh(v.w);
            ushort l0 = f2bh(v.x - bh2f(h0)), l1 = f2bh(v.y - bh2f(h1)),
                   l2 = f2bh(v.z - bh2f(h2)), l3 = f2bh(v.w - bh2f(h3));
            int base = (r << 6) + (((kc >> 1) ^ (r & 7)) << 3) + ((kc & 1) << 2);
            *(ushort4*)(Xh + base) = make_ushort4(h0, h1, h2, h3);
            *(ushort4*)(Xl + base) = make_ushort4(l0, l1, l2, l3);
        }
        // stage W hi/lo (already bf16 [C][Kd])
#pragma unroll
        for (int i = 0; i < 4; i++) {
            int idx = tid + i * 256;
            int c = idx >> 3, ch = idx & 7;
            int base = (c << 6) + ((ch ^ (c & 7)) << 3);
            size_t go = (size_t)(col0 + c) * Kd + k0 + ch * 8;
            *(float4*)(Wsh + base) = *(const float4*)(Wh + go);
            *(float4*)(Wsl + base) = *(const float4*)(Wl + go);
        }
        __syncthreads();
#pragma unroll
        for (int kk = 0; kk < 2; kk++) {
            int ch = kk * 4 + lk;
            bf16x8 xh[4], xl[4], wh[4], wl[4];
#pragma unroll
            for (int s = 0; s < 4; s++) {
                int r = rbase + s * 16 + lrow;
                int xoff = (r << 6) + ((ch ^ (r & 7)) << 3);
                xh[s] = *(const bf16x8*)(Xh + xoff);
                xl[s] = *(const bf16x8*)(Xl + xoff);
                int c = cbase + s * 16 + lrow;
                int woff = (c << 6) + ((ch ^ (c & 7)) << 3);
                wh[s] = *(const bf16x8*)(Wsh + woff);
                wl[s] = *(const bf16x8*)(Wsl + woff);
            }
#pragma unroll
            for (int sr = 0; sr < 4; sr++)
#pragma unroll
                for (int sc = 0; sc < 4; sc++) {
                    acc[sr][sc] = __builtin_amdgcn_mfma_f32_16x16x32_bf16(wh[sc], xh[sr], acc[sr][sc], 0, 0, 0);
                    acc[sr][sc] = __builtin_amdgcn_mfma_f32_16x16x32_bf16(wl[sc], xh[sr], acc[sr][sc], 0, 0, 0);
                    acc[sr][sc] = __builtin_amdgcn_mfma_f32_16x16x32_bf16(wh[sc], xl[sr], acc[sr][sc], 0, 0, 0);
                }
        }
        __syncthreads();
    }
    // epilogue: lane holds 4 consecutive cols per (sr,sc) -> float4 stores
#pragma unroll
    for (int sr = 0; sr < 4; sr++) {
        int row = row0 + rbase + sr * 16 + lrow;
#pragma unroll
        for (int sc = 0; sc < 4; sc++) {
            int col = col0 + cbase + sc * 16 + lk * 4;
            size_t o = (size_t)row * C + col;
            float4 v = make_float4(acc[sr][sc][0], acc[sr][sc][1],
                                   acc[sr][sc][2], acc[sr][sc][3]);
            if (bias) { float4 bv = *(const float4*)(bias + col);
                        v.x += bv.x; v.y += bv.y; v.z += bv.z; v.w += bv.w; }
            if (ACT == 1) { v.x = fmaxf(v.x, 0.f); v.y = fmaxf(v.y, 0.f);
                            v.z = fmaxf(v.z, 0.f); v.w = fmaxf(v.w, 0.f); }
            if (RES) { float4 rv = *(const float4*)(res + o);
                       v.x += rv.x; v.y += rv.y; v.z += rv.z; v.w += rv.w; }
            *(float4*)(Y + o) = v;
        }
    }
}

// ==== prep_w: transpose+split all per-layer GEMM weights to bf16 [C][K] ====
// per layer: Wq(0) Wk(16384) Wv(32768) Wo(49152) fW1(65536,[512][128])
//            fW2(131072,[128][512])
__global__ __launch_bounds__(256) void prep_w(const float* __restrict__ Wq,
                                              const float* __restrict__ Wk,
                                              const float* __restrict__ Wv,
                                              const float* __restrict__ Wo,
                                              const float* __restrict__ fW1,
                                              const float* __restrict__ fW2,
                                              ushort* __restrict__ oh,
                                              ushort* __restrict__ ol) {
    int l = blockIdx.y, t = blockIdx.x;
    const float* src; int K, C, tiles_c; size_t obase;
    if (t < 64) {
        int mi = t >> 4; t &= 15;
        src = (mi == 0 ? Wq : mi == 1 ? Wk : mi == 2 ? Wv : Wo) + (size_t)l * 16384;
        K = 128; C = 128; tiles_c = 4; obase = (size_t)l * WLAY + (size_t)mi * 16384;
    } else if (t < 128) {
        t -= 64; src = fW1 + (size_t)l * 65536;
        K = 128; C = 512; tiles_c = 16; obase = (size_t)l * WLAY + 65536;
    } else {
        t -= 128; src = fW2 + (size_t)l * 65536;
        K = 512; C = 128; tiles_c = 4; obase = (size_t)l * WLAY + 131072;
    }
    int tc = t % tiles_c, tk = t / tiles_c;
    __shared__ float tile[32][33];
    int tx = threadIdx.x & 31, ty = threadIdx.x >> 5;
#pragma unroll
    for (int i = 0; i < 4; i++) {
        int k = tk * 32 + ty + i * 8;
        tile[ty + i * 8][tx] = src[(size_t)k * C + tc * 32 + tx];
    }
    __syncthreads();
#pragma unroll
    for (int i = 0; i < 4; i++) {
        int c = tc * 32 + ty + i * 8;
        float v = tile[tx][ty + i * 8];
        ushort h = f2bh(v);
        ushort lo = f2bh(v - bh2f(h));
        size_t o = obase + (size_t)c * K + tk * 32 + tx;
        oh[o] = h; ol[o] = lo;
    }
}

// ============== naive GEMM for small/ragged shapes =========================
template <int ACT, bool RES>
__global__ void small_gemm(const float* __restrict__ X, const float* __restrict__ W,
                           const float* __restrict__ bias, const float* __restrict__ res,
                           float* __restrict__ Y, int n, int Kd, int C) {
    int idx = blockIdx.x * 256 + threadIdx.x;
    if (idx >= n * C) return;
    int row = idx / C, c = idx - row * C;
    float a = bias ? bias[c] : 0.f;
    const float* xr = X + (size_t)row * Kd;
    for (int k = 0; k < Kd; k++) a = fmaf(xr[k], W[(size_t)k * C + c], a);
    if (ACT == 1) a = fmaxf(a, 0.f);
    if (RES) a += res[idx];
    Y[idx] = a;
}

// ==== combined weights cW[l][k][c256]: tiled f32 GEMM, 16 blocks ===========
__global__ __launch_bounds__(256) void combine_fast(const float* __restrict__ eW2,
                                                    const float* __restrict__ Wke,
                                                    const float* __restrict__ Wve,
                                                    float* __restrict__ cW) {
    __shared__ float Xs[128 * 36];
    __shared__ float Ws[32 * 128];
    int x = blockIdx.x;
    int li = x & 7, kv = x >> 3;
    int l = li < 4 ? li : li + 1;
    int g = (li & 3) + 1;
    const float* E2 = eW2 + (size_t)g * 16384;            // [k][j]
    const float* Wp = (kv ? Wve : Wke) + (size_t)l * 16384; // [j][c]
    float* out = cW + (size_t)l * 32768 + kv * 128;
    int tid = threadIdx.x;
    int tc = tid & 15, tr = tid >> 4;
    int cA = tc * 4, rA = tr * 4;
    float acc[8][8] = {};
    for (int j0 = 0; j0 < 128; j0 += 32) {
#pragma unroll
        for (int i = 0; i < 4; i++) {
            int idx = tid + i * 256;
            int r = idx >> 3, jc = idx & 7;
            *(float4*)(Xs + r * 36 + jc * 4) =
                *(const float4*)(E2 + (size_t)r * 128 + j0 + jc * 4);
        }
#pragma unroll
        for (int i = 0; i < 4; i++) {
            int idx = tid + i * 256;
            int cc = idx & 31, jj = idx >> 5;
            *(float4*)(Ws + jj * 128 + cc * 4) =
                *(const float4*)(Wp + (size_t)(j0 + jj) * 128 + cc * 4);
        }
        __syncthreads();
#pragma unroll 8
        for (int jj = 0; jj < 32; jj++) {
            float4 w0 = *(const float4*)(Ws + jj * 128 + cA);
            float4 w1 = *(const float4*)(Ws + jj * 128 + cA + 64);
            float xr[8];
#pragma unroll
            for (int i2 = 0; i2 < 4; i2++) {
                xr[i2]     = Xs[(rA + i2) * 36 + jj];
                xr[4 + i2] = Xs[(rA + i2 + 64) * 36 + jj];
            }
#pragma unroll
            for (int i2 = 0; i2 < 8; i2++) {
                float xv = xr[i2];
                acc[i2][0] = fmaf(xv, w0.x, acc[i2][0]);
                acc[i2][1] = fmaf(xv, w0.y, acc[i2][1]);
                acc[i2][2] = fmaf(xv, w0.z, acc[i2][2]);
                acc[i2][3] = fmaf(xv, w0.w, acc[i2][3]);
                acc[i2][4] = fmaf(xv, w1.x, acc[i2][4]);
                acc[i2][5] = fmaf(xv, w1.y, acc[i2][5]);
                acc[i2][6] = fmaf(xv, w1.z, acc[i2][6]);
                acc[i2][7] = fmaf(xv, w1.w, acc[i2][7]);
            }
        }
        __syncthreads();
    }
#pragma unroll
    for (int i = 0; i < 8; i++) {
        int r = (i < 4) ? (rA + i) : (rA + i + 60);
#pragma unroll
        for (int chh = 0; chh < 2; chh++) {
            int c = cA + chh * 64;
            *(float4*)(out + (size_t)r * 256 + c) =
                make_float4(acc[i][chh * 4 + 0], acc[i][chh * 4 + 1],
                            acc[i][chh * 4 + 2], acc[i][chh * 4 + 3]);
        }
    }
}
__global__ void combine_bias(const float* __restrict__ eb2,
                             const float* __restrict__ Wke,
                             const float* __restrict__ Wve,
                             float* __restrict__ cb) {
    int x = blockIdx.x;
    int li = x & 7, kv = x >> 3;
    int l = li < 4 ? li : li + 1;
    int g = (li & 3) + 1;
    const float* Wp = (kv ? Wve : Wke) + (size_t)l * 16384;
    const float* eb = eb2 + g * 128;
    int cc = threadIdx.x;
    float a = 0.f;
    for (int j = 0; j < 128; j++) a = fmaf(eb[j], Wp[(size_t)j * 128 + cc], a);
    cb[l * 256 + kv * 128 + cc] = a;
}

// ============================ CSR construction =============================
__global__ void zero_i32(int* __restrict__ p, int n) {
    int i = blockIdx.x * 256 + threadIdx.x;
    if (i < n) p[i] = 0;
}
__global__ void hist_kernel(const int* __restrict__ dst, int E, int* __restrict__ deg) {
    int e = blockIdx.x * 256 + threadIdx.x;
    if (e < E) atomicAdd(&deg[dst[e]], 1);
}
__global__ __launch_bounds__(256) void exscan5(const int* __restrict__ deg0,
                                               int* __restrict__ off0,
                                               int* __restrict__ cursor0, int n) {
    int g = blockIdx.x;
    const int* deg = deg0 + (size_t)g * n;
    int* off = off0 + (size_t)g * (n + 1);
    int* cursor = cursor0 + (size_t)g * n;
    __shared__ int wsum[4];
    __shared__ int carry;
    int tid = threadIdx.x, lane = tid & 63, w = tid >> 6;
    if (tid == 0) carry = 0;
    __syncthreads();
    for (int base = 0; base < n; base += 256) {
        int v = (base + tid < n) ? deg[base + tid] : 0;
        int incl = v;
        for (int d = 1; d < 64; d <<= 1) {
            int t = __shfl_up(incl, d, 64);
            if (lane >= d) incl += t;
        }
        if (lane == 63) wsum[w] = incl;
        __syncthreads();
        int woff = 0;
        for (int i = 0; i < w; i++) woff += wsum[i];
        int total = wsum[0] + wsum[1] + wsum[2] + wsum[3];
        int excl = carry + woff + incl - v;
        if (base + tid < n) { off[base + tid] = excl; cursor[base + tid] = excl; }
        __syncthreads();
        if (tid == 0) carry += total;
        __syncthreads();
    }
    if (threadIdx.x == 0) off[n] = carry;
}
__global__ void scatter_kernel(const int* __restrict__ dst, int E,
                               int* __restrict__ cursor, int* __restrict__ eids) {
    int e = blockIdx.x * 256 + threadIdx.x;
    if (e < E) { int p = atomicAdd(&cursor[dst[e]], 1); eids[p] = e; }
}
__global__ void sort_edges(const int* __restrict__ eid, const int* __restrict__ srcArr,
                           const float* __restrict__ attr, int aw, int E,
                           int* __restrict__ esrc, float4* __restrict__ eattr) {
    int pos = blockIdx.x * 256 + threadIdx.x;
    if (pos >= E) return;
    int e = eid[pos];
    esrc[pos] = srcArr[e];
    if (attr) {
        float4 v;
        v.x = attr[(size_t)e * aw + 0];
        v.y = attr[(size_t)e * aw + 1];
        v.z = (aw > 2) ? attr[(size_t)e * aw + 2] : 0.f;
        v.w = (aw > 3) ? attr[(size_t)e * aw + 3] : 0.f;
        eattr[pos] = v;
    }
}

// ====== prep_g: g[d, h*128+c'] = 0.25 * sum_t Ck[c'][16h+t] q[d][16h+t] ====
__global__ __launch_bounds__(256) void prep_g(const float* __restrict__ q,
                                              const float* __restrict__ cWl,
                                              const float* __restrict__ cbl,
                                              float* __restrict__ g,
                                              float* __restrict__ sb) {
    __shared__ float Cks[128 * 132];
    __shared__ float qs[128];
    int tid = threadIdx.x;
    {
        int cp = tid >> 1, cb0 = (tid & 1) * 64;
#pragma unroll
        for (int kq = 0; kq < 16; kq++)
            *(float4*)(Cks + cp * 132 + cb0 + kq * 4) =
                *(const float4*)(cWl + (size_t)cp * 256 + cb0 + kq * 4);
    }
    int cp = tid & 127, hb = (tid >> 7) * 4;
    for (int d = blockIdx.x; d < M_; d += gridDim.x) {
        __syncthreads();
        if (tid < 32) *(float4*)(qs + tid * 4) = *(const float4*)(q + (size_t)d * 128 + tid * 4);
        __syncthreads();
#pragma unroll
        for (int h = hb; h < hb + 4; h++) {
            float a = 0.f;
#pragma unroll
            for (int jq = 0; jq < 4; jq++) {
                float4 ck = *(float4*)(Cks + cp * 132 + h * 16 + jq * 4);
                float4 qv = *(float4*)(qs + h * 16 + jq * 4);
                a = fmaf(ck.x, qv.x, a); a = fmaf(ck.y, qv.y, a);
                a = fmaf(ck.z, qv.z, a); a = fmaf(ck.w, qv.w, a);
            }
            g[(size_t)d * 1024 + h * 128 + cp] = a * 0.25f;
        }
        if (tid < 8) {
            float a = 0.f;
#pragma unroll
            for (int t16 = 0; t16 < 16; t16++)
                a = fmaf(cbl[tid * 16 + t16], qs[tid * 16 + t16], a);
            sb[d * 8 + tid] = a * 0.25f;
        }
    }
}

// ===== factorized fused attention (edge-emb layers): one wave per dst ======
__global__ __launch_bounds__(256) void attn_fact(const int* __restrict__ off,
                                                 const int* __restrict__ esrc,
                                                 const float4* __restrict__ eattr,
                                                 const float* __restrict__ g,
                                                 const float* __restrict__ sb,
                                                 const float* __restrict__ eW1,
                                                 const float* __restrict__ eb1,
                                                 const float* __restrict__ kx,
                                                 const float* __restrict__ vx,
                                                 const float* __restrict__ q,
                                                 float* __restrict__ hsum,
                                                 float* __restrict__ vxacc,
                                                 float* __restrict__ den) {
    __shared__ float lds[4 * 144];
    int w = threadIdx.x >> 6, l = threadIdx.x & 63;
    int i = l & 15, hlo = l >> 4;
    float* hw = lds + w * 144;
    int d = blockIdx.x * 4 + w;
    int beg = off[d], end = off[d + 1];
    float q0 = q[(size_t)d * 128 + l] * 0.25f;
    float q1 = q[(size_t)d * 128 + 64 + l] * 0.25f;
    float gA[8], gB[8];
#pragma unroll
    for (int j = 0; j < 8; j++) {
        gA[j] = g[(size_t)d * 1024 + hlo * 128 + j * 16 + i];
        gB[j] = g[(size_t)d * 1024 + (hlo + 4) * 128 + j * 16 + i];
    }
    float sbA = sb[d * 8 + hlo], sbB = sb[d * 8 + 4 + hlo];
    float w1a[4], w1b[4];
#pragma unroll
    for (int j = 0; j < 4; j++) { w1a[j] = eW1[j * 128 + l]; w1b[j] = eW1[j * 128 + 64 + l]; }
    float ebA = eb1[l], ebB = eb1[64 + l];
    float mA = -INFINITY, mB = -INFINITY, dnA = 0.f, dnB = 0.f;
    float accL[8] = {}, accH[8] = {};
    float va0 = 0.f, va1 = 0.f;
    int sN = 0; float4 aN = make_float4(0.f, 0.f, 0.f, 0.f);
    if (beg < end) { sN = esrc[beg]; aN = eattr[beg]; }
    for (int pos = beg; pos < end; pos++) {
        int s = sN; float4 at = aN;
        const float* kxr = kx + (size_t)s * 128;
        const float* vxr = vx + (size_t)s * 128;
        float k0 = kxr[l], k1 = kxr[64 + l];
        float v0 = vxr[l], v1 = vxr[64 + l];
        if (pos + 1 < end) { sN = esrc[pos + 1]; aN = eattr[pos + 1]; }
        float h0 = fmaxf(ebA + at.x * w1a[0] + at.y * w1a[1] + at.z * w1a[2] + at.w * w1a[3], 0.f);
        float h1 = fmaxf(ebB + at.x * w1b[0] + at.y * w1b[1] + at.z * w1b[2] + at.w * w1b[3], 0.f);
        hw[l] = h0; hw[64 + l] = h1;
        __builtin_amdgcn_wave_barrier();
        float pA = q0 * k0, pB = q1 * k1;
#pragma unroll
        for (int j = 0; j < 8; j++) {
            float hv = hw[j * 16 + i];
            pA = fmaf(hv, gA[j], pA);
            pB = fmaf(hv, gB[j], pB);
        }
#pragma unroll
        for (int msk = 1; msk < 16; msk <<= 1) {
            pA += __shfl_xor(pA, msk, 64);
            pB += __shfl_xor(pB, msk, 64);
        }
        pA += sbA; pB += sbB;
        float nmA = fmaxf(mA, pA), nmB = fmaxf(mB, pB);
        float cA = __expf(mA - nmA), cB = __expf(mB - nmB);
        float wA = __expf(pA - nmA), wB = __expf(pB - nmB);
        mA = nmA; mB = nmB;
        dnA = dnA * cA + wA; dnB = dnB * cB + wB;
        va0 = va0 * cA + wA * v0; va1 = va1 * cB + wB * v1;
        if (i == 0) {
            hw[128 + hlo] = wA; hw[132 + hlo] = wB;
            hw[136 + hlo] = cA; hw[140 + hlo] = cB;
        }
        __builtin_amdgcn_wave_barrier();
        float4 wv0 = *(float4*)(hw + 128), wv1 = *(float4*)(hw + 132);
        float4 cv0 = *(float4*)(hw + 136), cv1 = *(float4*)(hw + 140);
        accL[0] = fmaf(accL[0], cv0.x, wv0.x * h0); accH[0] = fmaf(accH[0], cv0.x, wv0.x * h1);
        accL[1] = fmaf(accL[1], cv0.y, wv0.y * h0); accH[1] = fmaf(accH[1], cv0.y, wv0.y * h1);
        accL[2] = fmaf(accL[2], cv0.z, wv0.z * h0); accH[2] = fmaf(accH[2], cv0.z, wv0.z * h1);
        accL[3] = fmaf(accL[3], cv0.w, wv0.w * h0); accH[3] = fmaf(accH[3], cv0.w, wv0.w * h1);
        accL[4] = fmaf(accL[4], cv1.x, wv1.x * h0); accH[4] = fmaf(accH[4], cv1.x, wv1.x * h1);
        accL[5] = fmaf(accL[5], cv1.y, wv1.y * h0); accH[5] = fmaf(accH[5], cv1.y, wv1.y * h1);
        accL[6] = fmaf(accL[6], cv1.z, wv1.z * h0); accH[6] = fmaf(accH[6], cv1.z, wv1.z * h1);
        accL[7] = fmaf(accL[7], cv1.w, wv1.w * h0); accH[7] = fmaf(accH[7], cv1.w, wv1.w * h1);
    }
#pragma unroll
    for (int h = 0; h < 8; h++) {
        hsum[(size_t)d * 1024 + h * 128 + l]      = accL[h];
        hsum[(size_t)d * 1024 + h * 128 + 64 + l] = accH[h];
    }
    vxacc[(size_t)d * 128 + l] = va0;
    vxacc[(size_t)d * 128 + 64 + l] = va1;
    if (i == 0) { den[d * 8 + hlo] = dnA; den[d * 8 + 4 + hlo] = dnB; }
}

// ========= plain fused attention (no edge emb): one wave per dst ===========
__global__ __launch_bounds__(256) void attn_plain(const int* __restrict__ off,
                                                  const int* __restrict__ esrc,
                                                  const float* __restrict__ kx,
                                                  const float* __restrict__ vx,
                                                  const float* __restrict__ q,
                                                  float* __restrict__ agg) {
    int w = threadIdx.x >> 6, lane = threadIdx.x & 63;
    int d = blockIdx.x * 4 + w;
    int beg = off[d], end = off[d + 1];
    float q0 = q[(size_t)d * 128 + lane] * 0.25f;
    float q1 = q[(size_t)d * 128 + 64 + lane] * 0.25f;
    float m0 = -INFINITY, m1 = -INFINITY;
    float den0 = 0.f, den1 = 0.f, acc0 = 0.f, acc1 = 0.f;
    int sN = (beg < end) ? esrc[beg] : 0;
    for (int pos = beg; pos < end; pos++) {
        int s = sN;
        const float* kxr = kx + (size_t)s * 128;
        const float* vxr = vx + (size_t)s * 128;
        float k0 = kxr[lane], k1 = kxr[64 + lane];
        float v0 = vxr[lane], v1 = vxr[64 + lane];
        if (pos + 1 < end) sN = esrc[pos + 1];
        float p0 = q0 * k0, p1 = q1 * k1;
#pragma unroll
        for (int msk = 1; msk < 16; msk <<= 1) {
            p0 += __shfl_xor(p0, msk, 64);
            p1 += __shfl_xor(p1, msk, 64);
        }
        float nm0 = fmaxf(m0, p0), nm1 = fmaxf(m1, p1);
        float c0 = __expf(m0 - nm0), c1 = __expf(m1 - nm1);
        float e0 = __expf(p0 - nm0), e1 = __expf(p1 - nm1);
        acc0 = acc0 * c0 + e0 * v0; den0 = den0 * c0 + e0;
        acc1 = acc1 * c1 + e1 * v1; den1 = den1 * c1 + e1;
        m0 = nm0; m1 = nm1;
    }
    agg[(size_t)d * 128 + lane]      = acc0 / (den0 + 1e-9f);
    agg[(size_t)d * 128 + 64 + lane] = acc1 / (den1 + 1e-9f);
}

// ====== epilogue: agg = (vxacc + hsum @ blockdiag(Cv)) * inv + cvb * cf ====
static constexpr int HST_ = 1092;
__global__ __launch_bounds__(256) void agg_fin(const float* __restrict__ hsum,
                                               const float* __restrict__ vxacc,
                                               const float* __restrict__ den,
                                               const float* __restrict__ cWl,
                                               const float* __restrict__ cbl,
                                               float* __restrict__ agg) {
    __shared__ float Cvs[128 * 128];
    __shared__ float hstage[8 * HST_];
    __shared__ float dens[64];
    int tid = threadIdx.x;
    {
        int cp = tid >> 1, cb0 = (tid & 1) * 64;
#pragma unroll
        for (int kq = 0; kq < 16; kq++)
            *(float4*)(Cvs + cp * 128 + cb0 + kq * 4) =
                *(const float4*)(cWl + (size_t)cp * 256 + 128 + cb0 + kq * 4);
    }
    int j = tid & 31, dsel = tid >> 5;
    int c4 = j * 4, h = j >> 2;
    float4 cvb = *(const float4*)(cbl + 128 + c4);
    for (int d0 = blockIdx.x * 8; d0 < M_; d0 += gridDim.x * 8) {
        __syncthreads();
        int r = tid * 4;
#pragma unroll
        for (int k = 0; k < 8; k++) {
            *(float4*)(hstage + k * HST_ + (r >> 7) * 136 + (r & 127)) =
                *(const float4*)(hsum + (size_t)(d0 + k) * 1024 + r);
        }
        if (tid < 64) dens[tid] = den[d0 * 8 + tid];
        __syncthreads();
        int d = d0 + dsel;
        float dn = dens[dsel * 8 + h];
        float inv = 1.f / (dn + 1e-9f);
        float cf = dn * inv;
        float a0 = 0.f, a1 = 0.f, a2 = 0.f, a3 = 0.f;
        const float* hrow = hstage + dsel * HST_ + h * 136;
#pragma unroll 4
        for (int cpp = 0; cpp < 128; cpp++) {
            float hs = hrow[cpp];
            float4 cv = *(float4*)(Cvs + cpp * 128 + c4);
            a0 = fmaf(hs, cv.x, a0); a1 = fmaf(hs, cv.y, a1);
            a2 = fmaf(hs, cv.z, a2); a3 = fmaf(hs, cv.w, a3);
        }
        float4 vv = *(const float4*)(vxacc + (size_t)d * 128 + c4);
        float4 o;
        o.x = (vv.x + a0) * inv + cvb.x * cf;
        o.y = (vv.y + a1) * inv + cvb.y * cf;
        o.z = (vv.z + a2) * inv + cvb.z * cf;
        o.w = (vv.w + a3) * inv + cvb.w * cf;
        *(float4*)(agg + (size_t)d * 128 + c4) = o;
    }
}

// ======================= small glue kernels ================================
__global__ void mode_init(float* __restrict__ m, const float* __restrict__ mt) {
    int idx = blockIdx.x * 256 + threadIdx.x;
    if (idx >= M_ * H_) return;
    int node = idx >> 7, c = idx & 127;
    m[idx] = mt[(node % K_) * H_ + c];
}
__global__ void extract_last(const float* __restrict__ m, float* __restrict__ out) {
    int idx = blockIdx.x * 256 + threadIdx.x;
    if (idx >= AK_ * H_) return;
    int row = idx >> 7, c = idx & 127;
    int a = row / K_, k = row - a * K_;
    int node = (a * T_ + (T_ - 1)) * K_ + k;
    out[idx] = m[(size_t)node * H_ + c];
}
__global__ void add_anchor(float* __restrict__ m, const float* __restrict__ anchor) {
    int idx = blockIdx.x * 256 + threadIdx.x;
    if (idx >= M_ * H_) return;
    int node = idx >> 7, c = idx & 127;
    int a = node / (T_ * K_), k = node % K_;
    m[idx] += anchor[(size_t)(a * K_ + k) * H_ + c];
}

// ============================ host launch ==================================
extern "C" void kernel_launch(void* const* d_in, const int* in_sizes, int n_in,
                              void* d_out, int out_size, void* d_ws, size_t ws_size,
                              hipStream_t stream) {
    const float* a_input     = (const float*)d_in[0];
    const float* l_embs      = (const float*)d_in[1];
    const float* mode_tokens = (const float*)d_in[2];
    const float* emb_W1 = (const float*)d_in[3];
    const float* emb_b1 = (const float*)d_in[4];
    const float* emb_W2 = (const float*)d_in[5];
    const float* emb_b2 = (const float*)d_in[6];
    const float* ga_Wq  = (const float*)d_in[7];
    const float* ga_Wk  = (const float*)d_in[8];
    const float* ga_Wv  = (const float*)d_in[9];
    const float* ga_Wo  = (const float*)d_in[10];
    const float* ga_Wke = (const float*)d_in[11];
    const float* ga_Wve = (const float*)d_in[12];
    const float* ga_g1  = (const float*)d_in[13];
    const float* ga_b1  = (const float*)d_in[14];
    const float* ga_g2  = (const float*)d_in[15];
    const float* ga_b2  = (const float*)d_in[16];
    const float* ga_fW1 = (const float*)d_in[17];
    const float* ga_fb1 = (const float*)d_in[18];
    const float* ga_fW2 = (const float*)d_in[19];
    const float* ga_fb2 = (const float*)d_in[20];
    const float* tp_W1 = (const float*)d_in[21];
    const float* tp_b1 = (const float*)d_in[22];
    const float* tp_W2 = (const float*)d_in[23];
    const float* tp_b2 = (const float*)d_in[24];
    const float* pa_W1 = (const float*)d_in[25];
    const float* pa_b1 = (const float*)d_in[26];
    const float* pa_W2 = (const float*)d_in[27];
    const float* pa_b2 = (const float*)d_in[28];
    const float* tr_W1 = (const float*)d_in[29];
    const float* tr_b1 = (const float*)d_in[30];
    const float* tr_W2 = (const float*)d_in[31];
    const float* tr_b2 = (const float*)d_in[32];
    const float* attrs[4] = { (const float*)d_in[33], (const float*)d_in[34],
                              (const float*)d_in[35], (const float*)d_in[36] };
    const int* eis[5] = { (const int*)d_in[37], (const int*)d_in[38], (const int*)d_in[39],
                          (const int*)d_in[40], (const int*)d_in[41] };
    int Es[5];
    int Emax = 0;
    for (int i = 0; i < 5; i++) { Es[i] = in_sizes[37 + i] / 2; if (Es[i] > Emax) Emax = Es[i]; }

    size_t off = 0;
    auto alloc = [&](size_t nbytes) -> char* {
        char* p = (char*)d_ws + off;
        off += ((nbytes + 255) / 256) * 256;
        return p;
    };
    float* cW     = (float*)alloc((size_t)NL_ * 128 * 256 * 4);
    float* cb     = (float*)alloc((size_t)NL_ * 256 * 4);
    ushort* wbh   = (ushort*)alloc((size_t)NL_ * WLAY * 2);
    ushort* wbl   = (ushort*)alloc((size_t)NL_ * WLAY * 2);
    float* a_embs = (float*)alloc((size_t)AT_ * H_ * 4);
    float* m      = (float*)alloc((size_t)M_ * H_ * 4);
    float* xd_ln  = (float*)alloc((size_t)M_ * H_ * 4);
    float* xs_ln  = (float*)alloc((size_t)AT_ * H_ * 4);
    float* q      = (float*)alloc((size_t)M_ * H_ * 4);
    float* kx     = (float*)alloc((size_t)M_ * H_ * 4);
    float* vx     = (float*)alloc((size_t)M_ * H_ * 4);
    float* agg    = (float*)alloc((size_t)M_ * H_ * 4);
    float* big    = (float*)alloc((size_t)M_ * 1024 * 4);   // g / FFN hidden
    float* hsum   = (float*)alloc((size_t)M_ * 1024 * 4);
    float* vxacc  = (float*)alloc((size_t)M_ * H_ * 4);
    float* den    = (float*)alloc((size_t)M_ * 8 * 4);
    float* sb     = (float*)alloc((size_t)M_ * 8 * 4);
    int* csr_off  = (int*)alloc((size_t)5 * (M_ + 1) * 4);
    int* csr_eid  = (int*)alloc((size_t)5 * Emax * 4);
    int* esrc     = (int*)alloc((size_t)5 * Emax * 4);
    float4* eattr = (float4*)alloc((size_t)4 * Emax * 16);
    int* deg5     = (int*)alloc((size_t)5 * M_ * 4);
    int* cursor5  = (int*)alloc((size_t)5 * M_ * 4);
    float* mlast  = (float*)alloc((size_t)AK_ * H_ * 4);
    float* hbuf   = (float*)alloc((size_t)AK_ * H_ * 4);
    float* anchor = (float*)alloc((size_t)AK_ * H_ * 4);
    (void)ws_size; (void)n_in;

    const size_t HH = (size_t)H_ * H_;
    float* outp = (float*)d_out;

    // ---- CSR + sorted src/attr for 5 graphs ----
    zero_i32<<<(5 * M_ + 255) / 256, 256, 0, stream>>>(deg5, 5 * M_);
    for (int gI = 0; gI < 5; gI++)
        hist_kernel<<<(Es[gI] + 255) / 256, 256, 0, stream>>>(eis[gI] + Es[gI], Es[gI], deg5 + (size_t)gI * M_);
    exscan5<<<5, 256, 0, stream>>>(deg5, csr_off, cursor5, M_);
    for (int gI = 0; gI < 5; gI++)
        scatter_kernel<<<(Es[gI] + 255) / 256, 256, 0, stream>>>(eis[gI] + Es[gI], Es[gI],
            cursor5 + (size_t)gI * M_, csr_eid + (size_t)gI * Emax);
    for (int gI = 0; gI < 5; gI++) {
        int aw = (gI == 0 || gI == 2) ? 4 : (gI == 4 ? 0 : 3);
        sort_edges<<<(Es[gI] + 255) / 256, 256, 0, stream>>>(
            csr_eid + (size_t)gI * Emax, eis[gI], (gI < 4) ? attrs[gI] : nullptr, aw, Es[gI],
            esrc + (size_t)gI * Emax, eattr + (size_t)gI * Emax);
    }

    // ---- weight prep ----
    prep_w<<<dim3(192, 10), 256, 0, stream>>>(ga_Wq, ga_Wk, ga_Wv, ga_Wo, ga_fW1, ga_fW2, wbh, wbl);
    combine_fast<<<16, 256, 0, stream>>>(emb_W2, ga_Wke, ga_Wve, cW);
    combine_bias<<<16, 128, 0, stream>>>(emb_b2, ga_Wke, ga_Wve, cb);

    // ---- embeddings / init ----
    small_gemm<1, false><<<(AT_ * H_ + 255) / 256, 256, 0, stream>>>(a_input, emb_W1, emb_b1, nullptr, big, AT_, 5, H_);
    small_gemm<0, false><<<(AT_ * H_ + 255) / 256, 256, 0, stream>>>(big, emb_W2, emb_b2, nullptr, a_embs, AT_, H_, H_);
    mode_init<<<(M_ * H_ + 255) / 256, 256, 0, stream>>>(m, mode_tokens);

    struct Cfg { const float* srcX; int n_src; int gi; bool hasE; };
    Cfg cfgs[10] = {
        { a_embs, AT_, 0, true }, { l_embs, L_, 1, true },
        { nullptr, M_, 2, true }, { nullptr, M_, 3, true },
        { nullptr, M_, 4, false },
        { a_embs, AT_, 0, true }, { l_embs, L_, 1, true },
        { nullptr, M_, 2, true }, { nullptr, M_, 3, true },
        { nullptr, M_, 4, false },
    };

    for (int l = 0; l < 10; l++) {
        const Cfg& cf = cfgs[l];
        const int* offg = csr_off + cf.gi * (M_ + 1);
        const int* esrcg = esrc + (size_t)cf.gi * Emax;
        const float4* eattrg = eattr + (size_t)cf.gi * Emax;
        const float* g1 = ga_g1 + l * H_; const float* b1 = ga_b1 + l * H_;
        size_t wb = (size_t)l * WLAY;

        ln_kernel<<<M_ / 4, 256, 0, stream>>>(m, g1, b1, xd_ln, M_);
        mgemm<0, false><<<dim3(M_ / 128, 1), 256, 0, stream>>>(
            xd_ln, wbh + wb, wbl + wb, nullptr, nullptr, q, M_, 128, 128);
        const float* srcLN = xd_ln;
        if (cf.srcX) {
            ln_kernel<<<cf.n_src / 4, 256, 0, stream>>>(cf.srcX, g1, b1, xs_ln, cf.n_src);
            srcLN = xs_ln;
        }
        mgemm<0, false><<<dim3(cf.n_src / 128, 1), 256, 0, stream>>>(
            srcLN, wbh + wb + 16384, wbl + wb + 16384, nullptr, nullptr, kx, cf.n_src, 128, 128);
        mgemm<0, false><<<dim3(cf.n_src / 128, 1), 256, 0, stream>>>(
            srcLN, wbh + wb + 32768, wbl + wb + 32768, nullptr, nullptr, vx, cf.n_src, 128, 128);

        if (cf.hasE) {
            int gg = (l < 5) ? l + 1 : l - 4;
            const float* eW1g = emb_W1 + (size_t)gg * 5 * H_;
            const float* eb1g = emb_b1 + (size_t)gg * H_;
            prep_g<<<2400, 256, 0, stream>>>(q, cW + (size_t)l * 128 * 256, cb + l * 256, big, sb);
            attn_fact<<<M_ / 4, 256, 0, stream>>>(offg, esrcg, eattrg, big, sb, eW1g, eb1g,
                                                  kx, vx, q, hsum, vxacc, den);
            agg_fin<<<256, 256, 0, stream>>>(hsum, vxacc, den,
                                             cW + (size_t)l * 128 * 256, cb + l * 256, agg);
        } else {
            attn_plain<<<M_ / 4, 256, 0, stream>>>(offg, esrcg, kx, vx, q, agg);
        }

        mgemm<0, true><<<dim3(M_ / 128, 1), 256, 0, stream>>>(
            agg, wbh + wb + 49152, wbl + wb + 49152, nullptr, m, m, M_, 128, 128);
        ln_kernel<<<M_ / 4, 256, 0, stream>>>(m, ga_g2 + l * H_, ga_b2 + l * H_, xd_ln, M_);
        mgemm<1, false><<<dim3(M_ / 128, 4), 256, 0, stream>>>(
            xd_ln, wbh + wb + 65536, wbl + wb + 65536, ga_fb1 + l * FF_, nullptr, big, M_, 128, 512);
        mgemm<0, true><<<dim3(M_ / 128, 1), 256, 0, stream>>>(
            big, wbh + wb + 131072, wbl + wb + 131072, ga_fb2 + l * H_, m, m, M_, 512, 128);

        if (l == 4) {
            extract_last<<<(AK_ * H_ + 255) / 256, 256, 0, stream>>>(m, mlast);
            small_gemm<1, false><<<(AK_ * H_ + 255) / 256, 256, 0, stream>>>(mlast, tp_W1, tp_b1, nullptr, hbuf, AK_, H_, H_);
            small_gemm<0, false><<<(AK_ * P2F + 255) / 256, 256, 0, stream>>>(hbuf, tp_W2, tp_b2, nullptr, outp, AK_, H_, P2F);
            small_gemm<1, false><<<(AK_ * H_ + 255) / 256, 256, 0, stream>>>(outp, pa_W1, pa_b1, nullptr, hbuf, AK_, P2F, H_);
            small_gemm<0, false><<<(AK_ * H_ + 255) / 256, 256, 0, stream>>>(hbuf, pa_W2, pa_b2, nullptr, anchor, AK_, H_, H_);
            add_anchor<<<(M_ * H_ + 255) / 256, 256, 0, stream>>>(m, anchor);
        }
    }

    extract_last<<<(AK_ * H_ + 255) / 256, 256, 0, stream>>>(m, mlast);
    small_gemm<1, false><<<(AK_ * H_ + 255) / 256, 256, 0, stream>>>(mlast, tr_W1, tr_b1, nullptr, hbuf, AK_, H_, H_);
    small_gemm<0, true><<<(AK_ * P2F + 255) / 256, 256, 0, stream>>>(hbuf, tr_W2, tr_b2, outp, outp + AK_ * P2F, AK_, H_, P2F);
}

// Round 5
// 2829.311 us; speedup vs baseline: 2.4701x; 1.0492x over previous
//
#include <hip/hip_runtime.h>
#include <hip/hip_bf16.h>
#include <math.h>

#define DEV __device__ __forceinline__

typedef __attribute__((ext_vector_type(4))) float floatx4;
typedef __attribute__((ext_vector_type(8))) __bf16 bf16x8;

static constexpr int A_ = 64, T_ = 50, K_ = 6, H_ = 128, NH_ = 8, F_ = 60, L_ = 512;
static constexpr int M_  = A_ * T_ * K_;   // 19200 mode nodes
static constexpr int AT_ = A_ * T_;        // 3200
static constexpr int FF_ = 4 * H_;         // 512
static constexpr int NL_ = 10;
static constexpr int P2F = 2 * F_;         // 120
static constexpr int AK_ = A_ * K_;        // 384
static constexpr size_t WLAY = 196608;     // per-layer transposed-weight elems

// ---- bf16 split helpers ----
DEV ushort f2bh(float f) {                 // RNE float->bf16 bits
    unsigned u = __float_as_uint(f);
    unsigned r = u + 0x7FFFu + ((u >> 16) & 1u);
    return (ushort)(r >> 16);
}
DEV float bh2f(ushort h) { return __uint_as_float(((unsigned)h) << 16); }

// ======================= LayerNorm: one wave per row =======================
__global__ __launch_bounds__(256) void ln_kernel(const float* __restrict__ x,
                                                 const float* __restrict__ g,
                                                 const float* __restrict__ b,
                                                 float* __restrict__ y, int n) {
    int row = blockIdx.x * 4 + (threadIdx.x >> 6);
    int lane = threadIdx.x & 63;
    if (row >= n) return;
    const float* xr = x + (size_t)row * H_;
    float v0 = xr[lane], v1 = xr[lane + 64];
    float s = v0 + v1;
    for (int m = 32; m >= 1; m >>= 1) s += __shfl_xor(s, m, 64);
    float mu = s * (1.f / 128.f);
    float d0 = v0 - mu, d1 = v1 - mu;
    float vs = d0 * d0 + d1 * d1;
    for (int m = 32; m >= 1; m >>= 1) vs += __shfl_xor(vs, m, 64);
    float rs = rsqrtf(vs * (1.f / 128.f) + 1e-5f);
    float* yr = y + (size_t)row * H_;
    yr[lane]      = d0 * rs * g[lane] + b[lane];
    yr[lane + 64] = d1 * rs * g[lane + 64] + b[lane + 64];
}

// ====== split-bf16 MFMA GEMM: Y = act(X @ W + bias) (+res) ================
template <int ACT, bool RES>
__global__ __launch_bounds__(256) void mgemm(const float* __restrict__ X,
                                             const ushort* __restrict__ Wh,
                                             const ushort* __restrict__ Wl,
                                             const float* __restrict__ bias,
                                             const float* __restrict__ res,
                                             float* __restrict__ Y,
                                             int n, int Kd, int C) {
    __shared__ ushort lds[4 * 8192];           // Xh,Xl,Wsh,Wsl: [128][64] each
    ushort* Xh  = lds;
    ushort* Xl  = lds + 8192;
    ushort* Wsh = lds + 16384;
    ushort* Wsl = lds + 24576;
    int row0 = blockIdx.x * 128, col0 = blockIdx.y * 128;
    int tid = threadIdx.x;
    int lane = tid & 63, wid = tid >> 6;
    int rbase = (wid >> 1) * 64, cbase = (wid & 1) * 64;
    int lrow = lane & 15, lk = lane >> 4;
    floatx4 acc[4][4];
#pragma unroll
    for (int a = 0; a < 4; a++)
#pragma unroll
        for (int b2 = 0; b2 < 4; b2++) acc[a][b2] = floatx4{0.f, 0.f, 0.f, 0.f};

    for (int k0 = 0; k0 < Kd; k0 += 64) {
#pragma unroll
        for (int i = 0; i < 8; i++) {
            int idx = tid + i * 256;
            int r = idx >> 4, kc = idx & 15;
            float4 v = *(const float4*)(X + (size_t)(row0 + r) * Kd + k0 + kc * 4);
            ushort h0 = f2bh(v.x), h1 = f2bh(v.y), h2 = f2bh(v.z), h3 = f2bh(v.w);
            ushort l0 = f2bh(v.x - bh2f(h0)), l1 = f2bh(v.y - bh2f(h1)),
                   l2 = f2bh(v.z - bh2f(h2)), l3 = f2bh(v.w - bh2f(h3));
            int base = (r << 6) + (((kc >> 1) ^ (r & 7)) << 3) + ((kc & 1) << 2);
            *(ushort4*)(Xh + base) = make_ushort4(h0, h1, h2, h3);
            *(ushort4*)(Xl + base) = make_ushort4(l0, l1, l2, l3);
        }
#pragma unroll
        for (int i = 0; i < 4; i++) {
            int idx = tid + i * 256;
            int c = idx >> 3, ch = idx & 7;
            int base = (c << 6) + ((ch ^ (c & 7)) << 3);
            size_t go = (size_t)(col0 + c) * Kd + k0 + ch * 8;
            *(float4*)(Wsh + base) = *(const float4*)(Wh + go);
            *(float4*)(Wsl + base) = *(const float4*)(Wl + go);
        }
        __syncthreads();
#pragma unroll
        for (int kk = 0; kk < 2; kk++) {
            int ch = kk * 4 + lk;
            bf16x8 xh[4], xl[4], wh[4], wl[4];
#pragma unroll
            for (int s = 0; s < 4; s++) {
                int r = rbase + s * 16 + lrow;
                int xoff = (r << 6) + ((ch ^ (r & 7)) << 3);
                xh[s] = *(const bf16x8*)(Xh + xoff);
                xl[s] = *(const bf16x8*)(Xl + xoff);
                int c = cbase + s * 16 + lrow;
                int woff = (c << 6) + ((ch ^ (c & 7)) << 3);
                wh[s] = *(const bf16x8*)(Wsh + woff);
                wl[s] = *(const bf16x8*)(Wsl + woff);
            }
#pragma unroll
            for (int sr = 0; sr < 4; sr++)
#pragma unroll
                for (int sc = 0; sc < 4; sc++) {
                    acc[sr][sc] = __builtin_amdgcn_mfma_f32_16x16x32_bf16(wh[sc], xh[sr], acc[sr][sc], 0, 0, 0);
                    acc[sr][sc] = __builtin_amdgcn_mfma_f32_16x16x32_bf16(wl[sc], xh[sr], acc[sr][sc], 0, 0, 0);
                    acc[sr][sc] = __builtin_amdgcn_mfma_f32_16x16x32_bf16(wh[sc], xl[sr], acc[sr][sc], 0, 0, 0);
                }
        }
        __syncthreads();
    }
#pragma unroll
    for (int sr = 0; sr < 4; sr++) {
        int row = row0 + rbase + sr * 16 + lrow;
#pragma unroll
        for (int sc = 0; sc < 4; sc++) {
            int col = col0 + cbase + sc * 16 + lk * 4;
            size_t o = (size_t)row * C + col;
            float4 v = make_float4(acc[sr][sc][0], acc[sr][sc][1],
                                   acc[sr][sc][2], acc[sr][sc][3]);
            if (bias) { float4 bv = *(const float4*)(bias + col);
                        v.x += bv.x; v.y += bv.y; v.z += bv.z; v.w += bv.w; }
            if (ACT == 1) { v.x = fmaxf(v.x, 0.f); v.y = fmaxf(v.y, 0.f);
                            v.z = fmaxf(v.z, 0.f); v.w = fmaxf(v.w, 0.f); }
            if (RES) { float4 rv = *(const float4*)(res + o);
                       v.x += rv.x; v.y += rv.y; v.z += rv.z; v.w += rv.w; }
            *(float4*)(Y + o) = v;
        }
    }
}

// ==== prep_w: transpose+split all per-layer GEMM weights to bf16 [C][K] ====
__global__ __launch_bounds__(256) void prep_w(const float* __restrict__ Wq,
                                              const float* __restrict__ Wk,
                                              const float* __restrict__ Wv,
                                              const float* __restrict__ Wo,
                                              const float* __restrict__ fW1,
                                              const float* __restrict__ fW2,
                                              ushort* __restrict__ oh,
                                              ushort* __restrict__ ol) {
    int l = blockIdx.y, t = blockIdx.x;
    const float* src; int K, C, tiles_c; size_t obase;
    if (t < 64) {
        int mi = t >> 4; t &= 15;
        src = (mi == 0 ? Wq : mi == 1 ? Wk : mi == 2 ? Wv : Wo) + (size_t)l * 16384;
        K = 128; C = 128; tiles_c = 4; obase = (size_t)l * WLAY + (size_t)mi * 16384;
    } else if (t < 128) {
        t -= 64; src = fW1 + (size_t)l * 65536;
        K = 128; C = 512; tiles_c = 16; obase = (size_t)l * WLAY + 65536;
    } else {
        t -= 128; src = fW2 + (size_t)l * 65536;
        K = 512; C = 128; tiles_c = 4; obase = (size_t)l * WLAY + 131072;
    }
    int tc = t % tiles_c, tk = t / tiles_c;
    __shared__ float tile[32][33];
    int tx = threadIdx.x & 31, ty = threadIdx.x >> 5;
#pragma unroll
    for (int i = 0; i < 4; i++) {
        int k = tk * 32 + ty + i * 8;
        tile[ty + i * 8][tx] = src[(size_t)k * C + tc * 32 + tx];
    }
    __syncthreads();
#pragma unroll
    for (int i = 0; i < 4; i++) {
        int c = tc * 32 + ty + i * 8;
        float v = tile[tx][ty + i * 8];
        ushort h = f2bh(v);
        ushort lo = f2bh(v - bh2f(h));
        size_t o = obase + (size_t)c * K + tk * 32 + tx;
        oh[o] = h; ol[o] = lo;
    }
}

// ============== naive GEMM for small/ragged shapes =========================
template <int ACT, bool RES>
__global__ void small_gemm(const float* __restrict__ X, const float* __restrict__ W,
                           const float* __restrict__ bias, const float* __restrict__ res,
                           float* __restrict__ Y, int n, int Kd, int C) {
    int idx = blockIdx.x * 256 + threadIdx.x;
    if (idx >= n * C) return;
    int row = idx / C, c = idx - row * C;
    float a = bias ? bias[c] : 0.f;
    const float* xr = X + (size_t)row * Kd;
    for (int k = 0; k < Kd; k++) a = fmaf(xr[k], W[(size_t)k * C + c], a);
    if (ACT == 1) a = fmaxf(a, 0.f);
    if (RES) a += res[idx];
    Y[idx] = a;
}

// ==== combined weights cW[l][k][c256]: tiled f32 GEMM, 16 blocks ===========
__global__ __launch_bounds__(256) void combine_fast(const float* __restrict__ eW2,
                                                    const float* __restrict__ Wke,
                                                    const float* __restrict__ Wve,
                                                    float* __restrict__ cW) {
    __shared__ float Xs[128 * 36];
    __shared__ float Ws[32 * 128];
    int x = blockIdx.x;
    int li = x & 7, kv = x >> 3;
    int l = li < 4 ? li : li + 1;
    int g = (li & 3) + 1;
    const float* E2 = eW2 + (size_t)g * 16384;
    const float* Wp = (kv ? Wve : Wke) + (size_t)l * 16384;
    float* out = cW + (size_t)l * 32768 + kv * 128;
    int tid = threadIdx.x;
    int tc = tid & 15, tr = tid >> 4;
    int cA = tc * 4, rA = tr * 4;
    float acc[8][8] = {};
    for (int j0 = 0; j0 < 128; j0 += 32) {
#pragma unroll
        for (int i = 0; i < 4; i++) {
            int idx = tid + i * 256;
            int r = idx >> 3, jc = idx & 7;
            *(float4*)(Xs + r * 36 + jc * 4) =
                *(const float4*)(E2 + (size_t)r * 128 + j0 + jc * 4);
        }
#pragma unroll
        for (int i = 0; i < 4; i++) {
            int idx = tid + i * 256;
            int cc = idx & 31, jj = idx >> 5;
            *(float4*)(Ws + jj * 128 + cc * 4) =
                *(const float4*)(Wp + (size_t)(j0 + jj) * 128 + cc * 4);
        }
        __syncthreads();
#pragma unroll 8
        for (int jj = 0; jj < 32; jj++) {
            float4 w0 = *(const float4*)(Ws + jj * 128 + cA);
            float4 w1 = *(const float4*)(Ws + jj * 128 + cA + 64);
            float xr[8];
#pragma unroll
            for (int i2 = 0; i2 < 4; i2++) {
                xr[i2]     = Xs[(rA + i2) * 36 + jj];
                xr[4 + i2] = Xs[(rA + i2 + 64) * 36 + jj];
            }
#pragma unroll
            for (int i2 = 0; i2 < 8; i2++) {
                float xv = xr[i2];
                acc[i2][0] = fmaf(xv, w0.x, acc[i2][0]);
                acc[i2][1] = fmaf(xv, w0.y, acc[i2][1]);
                acc[i2][2] = fmaf(xv, w0.z, acc[i2][2]);
                acc[i2][3] = fmaf(xv, w0.w, acc[i2][3]);
                acc[i2][4] = fmaf(xv, w1.x, acc[i2][4]);
                acc[i2][5] = fmaf(xv, w1.y, acc[i2][5]);
                acc[i2][6] = fmaf(xv, w1.z, acc[i2][6]);
                acc[i2][7] = fmaf(xv, w1.w, acc[i2][7]);
            }
        }
        __syncthreads();
    }
#pragma unroll
    for (int i = 0; i < 8; i++) {
        int r = (i < 4) ? (rA + i) : (rA + i + 60);
#pragma unroll
        for (int chh = 0; chh < 2; chh++) {
            int c = cA + chh * 64;
            *(float4*)(out + (size_t)r * 256 + c) =
                make_float4(acc[i][chh * 4 + 0], acc[i][chh * 4 + 1],
                            acc[i][chh * 4 + 2], acc[i][chh * 4 + 3]);
        }
    }
}
__global__ void combine_bias(const float* __restrict__ eb2,
                             const float* __restrict__ Wke,
                             const float* __restrict__ Wve,
                             float* __restrict__ cb) {
    int x = blockIdx.x;
    int li = x & 7, kv = x >> 3;
    int l = li < 4 ? li : li + 1;
    int g = (li & 3) + 1;
    const float* Wp = (kv ? Wve : Wke) + (size_t)l * 16384;
    const float* eb = eb2 + g * 128;
    int cc = threadIdx.x;
    float a = 0.f;
    for (int j = 0; j < 128; j++) a = fmaf(eb[j], Wp[(size_t)j * 128 + cc], a);
    cb[l * 256 + kv * 128 + cc] = a;
}

// ============================ CSR construction =============================
__global__ void zero_i32(int* __restrict__ p, int n) {
    int i = blockIdx.x * 256 + threadIdx.x;
    if (i < n) p[i] = 0;
}
__global__ void hist_kernel(const int* __restrict__ dst, int E, int* __restrict__ deg) {
    int e = blockIdx.x * 256 + threadIdx.x;
    if (e < E) atomicAdd(&deg[dst[e]], 1);
}
__global__ __launch_bounds__(256) void exscan5(const int* __restrict__ deg0,
                                               int* __restrict__ off0,
                                               int* __restrict__ cursor0, int n) {
    int g = blockIdx.x;
    const int* deg = deg0 + (size_t)g * n;
    int* off = off0 + (size_t)g * (n + 1);
    int* cursor = cursor0 + (size_t)g * n;
    __shared__ int wsum[4];
    __shared__ int carry;
    int tid = threadIdx.x, lane = tid & 63, w = tid >> 6;
    if (tid == 0) carry = 0;
    __syncthreads();
    for (int base = 0; base < n; base += 256) {
        int v = (base + tid < n) ? deg[base + tid] : 0;
        int incl = v;
        for (int d = 1; d < 64; d <<= 1) {
            int t = __shfl_up(incl, d, 64);
            if (lane >= d) incl += t;
        }
        if (lane == 63) wsum[w] = incl;
        __syncthreads();
        int woff = 0;
        for (int i = 0; i < w; i++) woff += wsum[i];
        int total = wsum[0] + wsum[1] + wsum[2] + wsum[3];
        int excl = carry + woff + incl - v;
        if (base + tid < n) { off[base + tid] = excl; cursor[base + tid] = excl; }
        __syncthreads();
        if (tid == 0) carry += total;
        __syncthreads();
    }
    if (threadIdx.x == 0) off[n] = carry;
}
__global__ void scatter_kernel(const int* __restrict__ dst, int E,
                               int* __restrict__ cursor, int* __restrict__ eids) {
    int e = blockIdx.x * 256 + threadIdx.x;
    if (e < E) { int p = atomicAdd(&cursor[dst[e]], 1); eids[p] = e; }
}
__global__ void sort_edges(const int* __restrict__ eid, const int* __restrict__ srcArr,
                           const float* __restrict__ attr, int aw, int E,
                           int* __restrict__ esrc, float4* __restrict__ eattr) {
    int pos = blockIdx.x * 256 + threadIdx.x;
    if (pos >= E) return;
    int e = eid[pos];
    esrc[pos] = srcArr[e];
    if (attr) {
        float4 v;
        v.x = attr[(size_t)e * aw + 0];
        v.y = attr[(size_t)e * aw + 1];
        v.z = (aw > 2) ? attr[(size_t)e * aw + 2] : 0.f;
        v.w = (aw > 3) ? attr[(size_t)e * aw + 3] : 0.f;
        eattr[pos] = v;
    }
}

// ====== prep_g: g[d, h*128+c'] = 0.25*sum_t Ck[c'][16h+t] q[d][16h+t], bf16 =
__global__ __launch_bounds__(256) void prep_g(const float* __restrict__ q,
                                              const float* __restrict__ cWl,
                                              const float* __restrict__ cbl,
                                              ushort* __restrict__ g,
                                              float* __restrict__ sb) {
    __shared__ float Cks[128 * 132];
    __shared__ float qs[128];
    int tid = threadIdx.x;
    {
        int cp = tid >> 1, cb0 = (tid & 1) * 64;
#pragma unroll
        for (int kq = 0; kq < 16; kq++)
            *(float4*)(Cks + cp * 132 + cb0 + kq * 4) =
                *(const float4*)(cWl + (size_t)cp * 256 + cb0 + kq * 4);
    }
    int cp = tid & 127, hb = (tid >> 7) * 4;
    for (int d = blockIdx.x; d < M_; d += gridDim.x) {
        __syncthreads();
        if (tid < 32) *(float4*)(qs + tid * 4) = *(const float4*)(q + (size_t)d * 128 + tid * 4);
        __syncthreads();
#pragma unroll
        for (int h = hb; h < hb + 4; h++) {
            float a = 0.f;
#pragma unroll
            for (int jq = 0; jq < 4; jq++) {
                float4 ck = *(float4*)(Cks + cp * 132 + h * 16 + jq * 4);
                float4 qv = *(float4*)(qs + h * 16 + jq * 4);
                a = fmaf(ck.x, qv.x, a); a = fmaf(ck.y, qv.y, a);
                a = fmaf(ck.z, qv.z, a); a = fmaf(ck.w, qv.w, a);
            }
            g[(size_t)d * 1024 + h * 128 + cp] = f2bh(a * 0.25f);
        }
        if (tid < 8) {
            float a = 0.f;
#pragma unroll
            for (int t16 = 0; t16 < 16; t16++)
                a = fmaf(cbl[tid * 16 + t16], qs[tid * 16 + t16], a);
            sb[d * 8 + tid] = a * 0.25f;
        }
    }
}

// ===== factorized fused attention (edge-emb layers): one wave per dst ======
__global__ __launch_bounds__(256) void attn_fact(const int* __restrict__ off,
                                                 const int* __restrict__ esrc,
                                                 const float4* __restrict__ eattr,
                                                 const ushort* __restrict__ g,
                                                 const float* __restrict__ sb,
                                                 const float* __restrict__ eW1,
                                                 const float* __restrict__ eb1,
                                                 const float* __restrict__ kx,
                                                 const float* __restrict__ vx,
                                                 const float* __restrict__ q,
                                                 ushort* __restrict__ hsum,
                                                 float* __restrict__ vxacc,
                                                 float* __restrict__ den) {
    __shared__ float lds[4 * 144];
    int w = threadIdx.x >> 6, l = threadIdx.x & 63;
    int i = l & 15, hlo = l >> 4;
    float* hw = lds + w * 144;
    int d = blockIdx.x * 4 + w;
    int beg = off[d], end = off[d + 1];
    float q0 = q[(size_t)d * 128 + l] * 0.25f;
    float q1 = q[(size_t)d * 128 + 64 + l] * 0.25f;
    float gA[8], gB[8];
#pragma unroll
    for (int j = 0; j < 8; j++) {
        gA[j] = bh2f(g[(size_t)d * 1024 + hlo * 128 + j * 16 + i]);
        gB[j] = bh2f(g[(size_t)d * 1024 + (hlo + 4) * 128 + j * 16 + i]);
    }
    float sbA = sb[d * 8 + hlo], sbB = sb[d * 8 + 4 + hlo];
    float w1a[4], w1b[4];
#pragma unroll
    for (int j = 0; j < 4; j++) { w1a[j] = eW1[j * 128 + l]; w1b[j] = eW1[j * 128 + 64 + l]; }
    float ebA = eb1[l], ebB = eb1[64 + l];
    float mA = -INFINITY, mB = -INFINITY, dnA = 0.f, dnB = 0.f;
    float accL[8] = {}, accH[8] = {};
    float va0 = 0.f, va1 = 0.f;
    // prefetched current-edge state
    float4 aC = make_float4(0.f, 0.f, 0.f, 0.f);
    float k0C = 0.f, k1C = 0.f, v0C = 0.f, v1C = 0.f;
    if (beg < end) {
        int s0 = esrc[beg]; aC = eattr[beg];
        const float* kxr = kx + (size_t)s0 * 128;
        const float* vxr = vx + (size_t)s0 * 128;
        k0C = kxr[l]; k1C = kxr[64 + l];
        v0C = vxr[l]; v1C = vxr[64 + l];
    }
    for (int pos = beg; pos < end; pos++) {
        float4 at = aC;
        float k0 = k0C, k1 = k1C, v0 = v0C, v1 = v1C;
        if (pos + 1 < end) {          // prefetch next edge's gathers
            int sN = esrc[pos + 1]; aC = eattr[pos + 1];
            const float* kxr = kx + (size_t)sN * 128;
            const float* vxr = vx + (size_t)sN * 128;
            k0C = kxr[l]; k1C = kxr[64 + l];
            v0C = vxr[l]; v1C = vxr[64 + l];
        }
        float h0 = fmaxf(ebA + at.x * w1a[0] + at.y * w1a[1] + at.z * w1a[2] + at.w * w1a[3], 0.f);
        float h1 = fmaxf(ebB + at.x * w1b[0] + at.y * w1b[1] + at.z * w1b[2] + at.w * w1b[3], 0.f);
        hw[l] = h0; hw[64 + l] = h1;
        __builtin_amdgcn_wave_barrier();
        float pA = q0 * k0, pB = q1 * k1;
#pragma unroll
        for (int j = 0; j < 8; j++) {
            float hv = hw[j * 16 + i];
            pA = fmaf(hv, gA[j], pA);
            pB = fmaf(hv, gB[j], pB);
        }
#pragma unroll
        for (int msk = 1; msk < 16; msk <<= 1) {
            pA += __shfl_xor(pA, msk, 64);
            pB += __shfl_xor(pB, msk, 64);
        }
        pA += sbA; pB += sbB;
        float nmA = fmaxf(mA, pA), nmB = fmaxf(mB, pB);
        float cA = __expf(mA - nmA), cB = __expf(mB - nmB);
        float wA = __expf(pA - nmA), wB = __expf(pB - nmB);
        mA = nmA; mB = nmB;
        dnA = dnA * cA + wA; dnB = dnB * cB + wB;
        va0 = va0 * cA + wA * v0; va1 = va1 * cB + wB * v1;
        if (i == 0) {
            hw[128 + hlo] = wA; hw[132 + hlo] = wB;
            hw[136 + hlo] = cA; hw[140 + hlo] = cB;
        }
        __builtin_amdgcn_wave_barrier();
        float4 wv0 = *(float4*)(hw + 128), wv1 = *(float4*)(hw + 132);
        float4 cv0 = *(float4*)(hw + 136), cv1 = *(float4*)(hw + 140);
        accL[0] = fmaf(accL[0], cv0.x, wv0.x * h0); accH[0] = fmaf(accH[0], cv0.x, wv0.x * h1);
        accL[1] = fmaf(accL[1], cv0.y, wv0.y * h0); accH[1] = fmaf(accH[1], cv0.y, wv0.y * h1);
        accL[2] = fmaf(accL[2], cv0.z, wv0.z * h0); accH[2] = fmaf(accH[2], cv0.z, wv0.z * h1);
        accL[3] = fmaf(accL[3], cv0.w, wv0.w * h0); accH[3] = fmaf(accH[3], cv0.w, wv0.w * h1);
        accL[4] = fmaf(accL[4], cv1.x, wv1.x * h0); accH[4] = fmaf(accH[4], cv1.x, wv1.x * h1);
        accL[5] = fmaf(accL[5], cv1.y, wv1.y * h0); accH[5] = fmaf(accH[5], cv1.y, wv1.y * h1);
        accL[6] = fmaf(accL[6], cv1.z, wv1.z * h0); accH[6] = fmaf(accH[6], cv1.z, wv1.z * h1);
        accL[7] = fmaf(accL[7], cv1.w, wv1.w * h0); accH[7] = fmaf(accH[7], cv1.w, wv1.w * h1);
    }
#pragma unroll
    for (int h = 0; h < 8; h++) {
        hsum[(size_t)d * 1024 + h * 128 + l]      = f2bh(accL[h]);
        hsum[(size_t)d * 1024 + h * 128 + 64 + l] = f2bh(accH[h]);
    }
    vxacc[(size_t)d * 128 + l] = va0;
    vxacc[(size_t)d * 128 + 64 + l] = va1;
    if (i == 0) { den[d * 8 + hlo] = dnA; den[d * 8 + 4 + hlo] = dnB; }
}

// ========= plain fused attention (no edge emb): one wave per dst ===========
__global__ __launch_bounds__(256) void attn_plain(const int* __restrict__ off,
                                                  const int* __restrict__ esrc,
                                                  const float* __restrict__ kx,
                                                  const float* __restrict__ vx,
                                                  const float* __restrict__ q,
                                                  float* __restrict__ agg) {
    int w = threadIdx.x >> 6, lane = threadIdx.x & 63;
    int d = blockIdx.x * 4 + w;
    int beg = off[d], end = off[d + 1];
    float q0 = q[(size_t)d * 128 + lane] * 0.25f;
    float q1 = q[(size_t)d * 128 + 64 + lane] * 0.25f;
    float m0 = -INFINITY, m1 = -INFINITY;
    float den0 = 0.f, den1 = 0.f, acc0 = 0.f, acc1 = 0.f;
    float k0C = 0.f, k1C = 0.f, v0C = 0.f, v1C = 0.f;
    if (beg < end) {
        int s0 = esrc[beg];
        const float* kxr = kx + (size_t)s0 * 128;
        const float* vxr = vx + (size_t)s0 * 128;
        k0C = kxr[lane]; k1C = kxr[64 + lane];
        v0C = vxr[lane]; v1C = vxr[64 + lane];
    }
    for (int pos = beg; pos < end; pos++) {
        float k0 = k0C, k1 = k1C, v0 = v0C, v1 = v1C;
        if (pos + 1 < end) {
            int sN = esrc[pos + 1];
            const float* kxr = kx + (size_t)sN * 128;
            const float* vxr = vx + (size_t)sN * 128;
            k0C = kxr[lane]; k1C = kxr[64 + lane];
            v0C = vxr[lane]; v1C = vxr[64 + lane];
        }
        float p0 = q0 * k0, p1 = q1 * k1;
#pragma unroll
        for (int msk = 1; msk < 16; msk <<= 1) {
            p0 += __shfl_xor(p0, msk, 64);
            p1 += __shfl_xor(p1, msk, 64);
        }
        float nm0 = fmaxf(m0, p0), nm1 = fmaxf(m1, p1);
        float c0 = __expf(m0 - nm0), c1 = __expf(m1 - nm1);
        float e0 = __expf(p0 - nm0), e1 = __expf(p1 - nm1);
        acc0 = acc0 * c0 + e0 * v0; den0 = den0 * c0 + e0;
        acc1 = acc1 * c1 + e1 * v1; den1 = den1 * c1 + e1;
        m0 = nm0; m1 = nm1;
    }
    agg[(size_t)d * 128 + lane]      = acc0 / (den0 + 1e-9f);
    agg[(size_t)d * 128 + 64 + lane] = acc1 / (den1 + 1e-9f);
}

// ====== epilogue: agg = (vxacc + hsum @ blockdiag(Cv)) * inv + cvb * cf ====
static constexpr int HST_ = 1092;
__global__ __launch_bounds__(256) void agg_fin(const ushort* __restrict__ hsum,
                                               const float* __restrict__ vxacc,
                                               const float* __restrict__ den,
                                               const float* __restrict__ cWl,
                                               const float* __restrict__ cbl,
                                               float* __restrict__ agg) {
    __shared__ float Cvs[128 * 128];
    __shared__ float hstage[8 * HST_];
    __shared__ float dens[64];
    int tid = threadIdx.x;
    {
        int cp = tid >> 1, cb0 = (tid & 1) * 64;
#pragma unroll
        for (int kq = 0; kq < 16; kq++)
            *(float4*)(Cvs + cp * 128 + cb0 + kq * 4) =
                *(const float4*)(cWl + (size_t)cp * 256 + 128 + cb0 + kq * 4);
    }
    int j = tid & 31, dsel = tid >> 5;
    int c4 = j * 4, h = j >> 2;
    float4 cvb = *(const float4*)(cbl + 128 + c4);
    for (int d0 = blockIdx.x * 8; d0 < M_; d0 += gridDim.x * 8) {
        __syncthreads();
        int r = tid * 4;
#pragma unroll
        for (int k = 0; k < 8; k++) {
            ushort4 u = *(const ushort4*)(hsum + (size_t)(d0 + k) * 1024 + r);
            *(float4*)(hstage + k * HST_ + (r >> 7) * 136 + (r & 127)) =
                make_float4(bh2f(u.x), bh2f(u.y), bh2f(u.z), bh2f(u.w));
        }
        if (tid < 64) dens[tid] = den[d0 * 8 + tid];
        __syncthreads();
        int d = d0 + dsel;
        float dn = dens[dsel * 8 + h];
        float inv = 1.f / (dn + 1e-9f);
        float cf = dn * inv;
        float a0 = 0.f, a1 = 0.f, a2 = 0.f, a3 = 0.f;
        const float* hrow = hstage + dsel * HST_ + h * 136;
#pragma unroll 4
        for (int cpp = 0; cpp < 128; cpp++) {
            float hs = hrow[cpp];
            float4 cv = *(float4*)(Cvs + cpp * 128 + c4);
            a0 = fmaf(hs, cv.x, a0); a1 = fmaf(hs, cv.y, a1);
            a2 = fmaf(hs, cv.z, a2); a3 = fmaf(hs, cv.w, a3);
        }
        float4 vv = *(const float4*)(vxacc + (size_t)d * 128 + c4);
        float4 o;
        o.x = (vv.x + a0) * inv + cvb.x * cf;
        o.y = (vv.y + a1) * inv + cvb.y * cf;
        o.z = (vv.z + a2) * inv + cvb.z * cf;
        o.w = (vv.w + a3) * inv + cvb.w * cf;
        *(float4*)(agg + (size_t)d * 128 + c4) = o;
    }
}

// ======================= small glue kernels ================================
__global__ void mode_init(float* __restrict__ m, const float* __restrict__ mt) {
    int idx = blockIdx.x * 256 + threadIdx.x;
    if (idx >= M_ * H_) return;
    int node = idx >> 7, c = idx & 127;
    m[idx] = mt[(node % K_) * H_ + c];
}
__global__ void extract_last(const float* __restrict__ m, float* __restrict__ out) {
    int idx = blockIdx.x * 256 + threadIdx.x;
    if (idx >= AK_ * H_) return;
    int row = idx >> 7, c = idx & 127;
    int a = row / K_, k = row - a * K_;
    int node = (a * T_ + (T_ - 1)) * K_ + k;
    out[idx] = m[(size_t)node * H_ + c];
}
__global__ void add_anchor(float* __restrict__ m, const float* __restrict__ anchor) {
    int idx = blockIdx.x * 256 + threadIdx.x;
    if (idx >= M_ * H_) return;
    int node = idx >> 7, c = idx & 127;
    int a = node / (T_ * K_), k = node % K_;
    m[idx] += anchor[(size_t)(a * K_ + k) * H_ + c];
}

// ============================ host launch ==================================
extern "C" void kernel_launch(void* const* d_in, const int* in_sizes, int n_in,
                              void* d_out, int out_size, void* d_ws, size_t ws_size,
                              hipStream_t stream) {
    const float* a_input     = (const float*)d_in[0];
    const float* l_embs      = (const float*)d_in[1];
    const float* mode_tokens = (const float*)d_in[2];
    const float* emb_W1 = (const float*)d_in[3];
    const float* emb_b1 = (const float*)d_in[4];
    const float* emb_W2 = (const float*)d_in[5];
    const float* emb_b2 = (const float*)d_in[6];
    const float* ga_Wq  = (const float*)d_in[7];
    const float* ga_Wk  = (const float*)d_in[8];
    const float* ga_Wv  = (const float*)d_in[9];
    const float* ga_Wo  = (const float*)d_in[10];
    const float* ga_Wke = (const float*)d_in[11];
    const float* ga_Wve = (const float*)d_in[12];
    const float* ga_g1  = (const float*)d_in[13];
    const float* ga_b1  = (const float*)d_in[14];
    const float* ga_g2  = (const float*)d_in[15];
    const float* ga_b2  = (const float*)d_in[16];
    const float* ga_fW1 = (const float*)d_in[17];
    const float* ga_fb1 = (const float*)d_in[18];
    const float* ga_fW2 = (const float*)d_in[19];
    const float* ga_fb2 = (const float*)d_in[20];
    const float* tp_W1 = (const float*)d_in[21];
    const float* tp_b1 = (const float*)d_in[22];
    const float* tp_W2 = (const float*)d_in[23];
    const float* tp_b2 = (const float*)d_in[24];
    const float* pa_W1 = (const float*)d_in[25];
    const float* pa_b1 = (const float*)d_in[26];
    const float* pa_W2 = (const float*)d_in[27];
    const float* pa_b2 = (const float*)d_in[28];
    const float* tr_W1 = (const float*)d_in[29];
    const float* tr_b1 = (const float*)d_in[30];
    const float* tr_W2 = (const float*)d_in[31];
    const float* tr_b2 = (const float*)d_in[32];
    const float* attrs[4] = { (const float*)d_in[33], (const float*)d_in[34],
                              (const float*)d_in[35], (const float*)d_in[36] };
    const int* eis[5] = { (const int*)d_in[37], (const int*)d_in[38], (const int*)d_in[39],
                          (const int*)d_in[40], (const int*)d_in[41] };
    int Es[5];
    int Emax = 0;
    for (int i = 0; i < 5; i++) { Es[i] = in_sizes[37 + i] / 2; if (Es[i] > Emax) Emax = Es[i]; }

    size_t off = 0;
    auto alloc = [&](size_t nbytes) -> char* {
        char* p = (char*)d_ws + off;
        off += ((nbytes + 255) / 256) * 256;
        return p;
    };
    float* cW     = (float*)alloc((size_t)NL_ * 128 * 256 * 4);
    float* cb     = (float*)alloc((size_t)NL_ * 256 * 4);
    ushort* wbh   = (ushort*)alloc((size_t)NL_ * WLAY * 2);
    ushort* wbl   = (ushort*)alloc((size_t)NL_ * WLAY * 2);
    float* a_embs = (float*)alloc((size_t)AT_ * H_ * 4);
    float* m      = (float*)alloc((size_t)M_ * H_ * 4);
    float* xd_ln  = (float*)alloc((size_t)M_ * H_ * 4);
    float* xs_ln  = (float*)alloc((size_t)AT_ * H_ * 4);
    float* q      = (float*)alloc((size_t)M_ * H_ * 4);
    float* kx     = (float*)alloc((size_t)M_ * H_ * 4);
    float* vx     = (float*)alloc((size_t)M_ * H_ * 4);
    float* agg    = (float*)alloc((size_t)M_ * H_ * 4);
    float* big    = (float*)alloc((size_t)M_ * FF_ * 4);     // FFN hidden
    ushort* gbuf  = (ushort*)alloc((size_t)M_ * 1024 * 2);   // bf16 g
    ushort* hsumb = (ushort*)alloc((size_t)M_ * 1024 * 2);   // bf16 hsum
    float* vxacc  = (float*)alloc((size_t)M_ * H_ * 4);
    float* den    = (float*)alloc((size_t)M_ * 8 * 4);
    float* sb     = (float*)alloc((size_t)M_ * 8 * 4);
    int* csr_off  = (int*)alloc((size_t)5 * (M_ + 1) * 4);
    int* csr_eid  = (int*)alloc((size_t)5 * Emax * 4);
    int* esrc     = (int*)alloc((size_t)5 * Emax * 4);
    float4* eattr = (float4*)alloc((size_t)4 * Emax * 16);
    int* deg5     = (int*)alloc((size_t)5 * M_ * 4);
    int* cursor5  = (int*)alloc((size_t)5 * M_ * 4);
    float* mlast  = (float*)alloc((size_t)AK_ * H_ * 4);
    float* hbuf   = (float*)alloc((size_t)AK_ * H_ * 4);
    float* anchor = (float*)alloc((size_t)AK_ * H_ * 4);
    (void)ws_size; (void)n_in;

    float* outp = (float*)d_out;

    // ---- CSR + sorted src/attr for 5 graphs ----
    zero_i32<<<(5 * M_ + 255) / 256, 256, 0, stream>>>(deg5, 5 * M_);
    for (int gI = 0; gI < 5; gI++)
        hist_kernel<<<(Es[gI] + 255) / 256, 256, 0, stream>>>(eis[gI] + Es[gI], Es[gI], deg5 + (size_t)gI * M_);
    exscan5<<<5, 256, 0, stream>>>(deg5, csr_off, cursor5, M_);
    for (int gI = 0; gI < 5; gI++)
        scatter_kernel<<<(Es[gI] + 255) / 256, 256, 0, stream>>>(eis[gI] + Es[gI], Es[gI],
            cursor5 + (size_t)gI * M_, csr_eid + (size_t)gI * Emax);
    for (int gI = 0; gI < 5; gI++) {
        int aw = (gI == 0 || gI == 2) ? 4 : (gI == 4 ? 0 : 3);
        sort_edges<<<(Es[gI] + 255) / 256, 256, 0, stream>>>(
            csr_eid + (size_t)gI * Emax, eis[gI], (gI < 4) ? attrs[gI] : nullptr, aw, Es[gI],
            esrc + (size_t)gI * Emax, eattr + (size_t)gI * Emax);
    }

    // ---- weight prep ----
    prep_w<<<dim3(192, 10), 256, 0, stream>>>(ga_Wq, ga_Wk, ga_Wv, ga_Wo, ga_fW1, ga_fW2, wbh, wbl);
    combine_fast<<<16, 256, 0, stream>>>(emb_W2, ga_Wke, ga_Wve, cW);
    combine_bias<<<16, 128, 0, stream>>>(emb_b2, ga_Wke, ga_Wve, cb);

    // ---- embeddings / init ----
    small_gemm<1, false><<<(AT_ * H_ + 255) / 256, 256, 0, stream>>>(a_input, emb_W1, emb_b1, nullptr, big, AT_, 5, H_);
    small_gemm<0, false><<<(AT_ * H_ + 255) / 256, 256, 0, stream>>>(big, emb_W2, emb_b2, nullptr, a_embs, AT_, H_, H_);
    mode_init<<<(M_ * H_ + 255) / 256, 256, 0, stream>>>(m, mode_tokens);

    struct Cfg { const float* srcX; int n_src; int gi; bool hasE; };
    Cfg cfgs[10] = {
        { a_embs, AT_, 0, true }, { l_embs, L_, 1, true },
        { nullptr, M_, 2, true }, { nullptr, M_, 3, true },
        { nullptr, M_, 4, false },
        { a_embs, AT_, 0, true }, { l_embs, L_, 1, true },
        { nullptr, M_, 2, true }, { nullptr, M_, 3, true },
        { nullptr, M_, 4, false },
    };

    for (int l = 0; l < 10; l++) {
        const Cfg& cf = cfgs[l];
        const int* offg = csr_off + cf.gi * (M_ + 1);
        const int* esrcg = esrc + (size_t)cf.gi * Emax;
        const float4* eattrg = eattr + (size_t)cf.gi * Emax;
        const float* g1 = ga_g1 + l * H_; const float* b1 = ga_b1 + l * H_;
        size_t wb = (size_t)l * WLAY;

        ln_kernel<<<M_ / 4, 256, 0, stream>>>(m, g1, b1, xd_ln, M_);
        mgemm<0, false><<<dim3(M_ / 128, 1), 256, 0, stream>>>(
            xd_ln, wbh + wb, wbl + wb, nullptr, nullptr, q, M_, 128, 128);
        const float* srcLN = xd_ln;
        if (cf.srcX) {
            ln_kernel<<<cf.n_src / 4, 256, 0, stream>>>(cf.srcX, g1, b1, xs_ln, cf.n_src);
            srcLN = xs_ln;
        }
        mgemm<0, false><<<dim3(cf.n_src / 128, 1), 256, 0, stream>>>(
            srcLN, wbh + wb + 16384, wbl + wb + 16384, nullptr, nullptr, kx, cf.n_src, 128, 128);
        mgemm<0, false><<<dim3(cf.n_src / 128, 1), 256, 0, stream>>>(
            srcLN, wbh + wb + 32768, wbl + wb + 32768, nullptr, nullptr, vx, cf.n_src, 128, 128);

        if (cf.hasE) {
            int gg = (l < 5) ? l + 1 : l - 4;
            const float* eW1g = emb_W1 + (size_t)gg * 5 * H_;
            const float* eb1g = emb_b1 + (size_t)gg * H_;
            prep_g<<<2400, 256, 0, stream>>>(q, cW + (size_t)l * 128 * 256, cb + l * 256, gbuf, sb);
            attn_fact<<<M_ / 4, 256, 0, stream>>>(offg, esrcg, eattrg, gbuf, sb, eW1g, eb1g,
                                                  kx, vx, q, hsumb, vxacc, den);
            agg_fin<<<256, 256, 0, stream>>>(hsumb, vxacc, den,
                                             cW + (size_t)l * 128 * 256, cb + l * 256, agg);
        } else {
            attn_plain<<<M_ / 4, 256, 0, stream>>>(offg, esrcg, kx, vx, q, agg);
        }

        mgemm<0, true><<<dim3(M_ / 128, 1), 256, 0, stream>>>(
            agg, wbh + wb + 49152, wbl + wb + 49152, nullptr, m, m, M_, 128, 128);
        ln_kernel<<<M_ / 4, 256, 0, stream>>>(m, ga_g2 + l * H_, ga_b2 + l * H_, xd_ln, M_);
        mgemm<1, false><<<dim3(M_ / 128, 4), 256, 0, stream>>>(
            xd_ln, wbh + wb + 65536, wbl + wb + 65536, ga_fb1 + l * FF_, nullptr, big, M_, 128, 512);
        mgemm<0, true><<<dim3(M_ / 128, 1), 256, 0, stream>>>(
            big, wbh + wb + 131072, wbl + wb + 131072, ga_fb2 + l * H_, m, m, M_, 512, 128);

        if (l == 4) {
            extract_last<<<(AK_ * H_ + 255) / 256, 256, 0, stream>>>(m, mlast);
            small_gemm<1, false><<<(AK_ * H_ + 255) / 256, 256, 0, stream>>>(mlast, tp_W1, tp_b1, nullptr, hbuf, AK_, H_, H_);
            small_gemm<0, false><<<(AK_ * P2F + 255) / 256, 256, 0, stream>>>(hbuf, tp_W2, tp_b2, nullptr, outp, AK_, H_, P2F);
            small_gemm<1, false><<<(AK_ * H_ + 255) / 256, 256, 0, stream>>>(outp, pa_W1, pa_b1, nullptr, hbuf, AK_, P2F, H_);
            small_gemm<0, false><<<(AK_ * H_ + 255) / 256, 256, 0, stream>>>(hbuf, pa_W2, pa_b2, nullptr, anchor, AK_, H_, H_);
            add_anchor<<<(M_ * H_ + 255) / 256, 256, 0, stream>>>(m, anchor);
        }
    }

    extract_last<<<(AK_ * H_ + 255) / 256, 256, 0, stream>>>(m, mlast);
    small_gemm<1, false><<<(AK_ * H_ + 255) / 256, 256, 0, stream>>>(mlast, tr_W1, tr_b1, nullptr, hbuf, AK_, H_, H_);
    small_gemm<0, true><<<(AK_ * P2F + 255) / 256, 256, 0, stream>>>(hbuf, tr_W2, tr_b2, outp, outp + AK_ * P2F, AK_, H_, P2F);
}

// Round 6
// 2694.184 us; speedup vs baseline: 2.5940x; 1.0502x over previous
//
#include <hip/hip_runtime.h>
#include <hip/hip_bf16.h>
#include <math.h>

#define DEV __device__ __forceinline__

typedef __attribute__((ext_vector_type(4))) float floatx4;
typedef __attribute__((ext_vector_type(8))) __bf16 bf16x8;

static constexpr int A_ = 64, T_ = 50, K_ = 6, H_ = 128, NH_ = 8, F_ = 60, L_ = 512;
static constexpr int M_  = A_ * T_ * K_;   // 19200 mode nodes
static constexpr int AT_ = A_ * T_;        // 3200
static constexpr int FF_ = 4 * H_;         // 512
static constexpr int NL_ = 10;
static constexpr int P2F = 2 * F_;         // 120
static constexpr int AK_ = A_ * K_;        // 384
static constexpr size_t WLAY = 196608;     // per-layer transposed-weight elems

// ---- bf16 split helpers ----
DEV ushort f2bh(float f) {                 // RNE float->bf16 bits
    unsigned u = __float_as_uint(f);
    unsigned r = u + 0x7FFFu + ((u >> 16) & 1u);
    return (ushort)(r >> 16);
}
DEV float bh2f(ushort h) { return __uint_as_float(((unsigned)h) << 16); }

// ======================= LayerNorm: one wave per row =======================
__global__ __launch_bounds__(256) void ln_kernel(const float* __restrict__ x,
                                                 const float* __restrict__ g,
                                                 const float* __restrict__ b,
                                                 float* __restrict__ y, int n) {
    int row = blockIdx.x * 4 + (threadIdx.x >> 6);
    int lane = threadIdx.x & 63;
    if (row >= n) return;
    const float* xr = x + (size_t)row * H_;
    float v0 = xr[lane], v1 = xr[lane + 64];
    float s = v0 + v1;
    for (int m = 32; m >= 1; m >>= 1) s += __shfl_xor(s, m, 64);
    float mu = s * (1.f / 128.f);
    float d0 = v0 - mu, d1 = v1 - mu;
    float vs = d0 * d0 + d1 * d1;
    for (int m = 32; m >= 1; m >>= 1) vs += __shfl_xor(vs, m, 64);
    float rs = rsqrtf(vs * (1.f / 128.f) + 1e-5f);
    float* yr = y + (size_t)row * H_;
    yr[lane]      = d0 * rs * g[lane] + b[lane];
    yr[lane + 64] = d1 * rs * g[lane + 64] + b[lane + 64];
}

// ====== split-bf16 MFMA GEMM: Y = act(X @ W + bias) (+res) ================
template <int ACT, bool RES>
__global__ __launch_bounds__(256) void mgemm(const float* __restrict__ X,
                                             const ushort* __restrict__ Wh,
                                             const ushort* __restrict__ Wl,
                                             const float* __restrict__ bias,
                                             const float* __restrict__ res,
                                             float* __restrict__ Y,
                                             int n, int Kd, int C) {
    __shared__ ushort lds[4 * 8192];           // Xh,Xl,Wsh,Wsl: [128][64] each
    ushort* Xh  = lds;
    ushort* Xl  = lds + 8192;
    ushort* Wsh = lds + 16384;
    ushort* Wsl = lds + 24576;
    int row0 = blockIdx.x * 128, col0 = blockIdx.y * 128;
    int tid = threadIdx.x;
    int lane = tid & 63, wid = tid >> 6;
    int rbase = (wid >> 1) * 64, cbase = (wid & 1) * 64;
    int lrow = lane & 15, lk = lane >> 4;
    floatx4 acc[4][4];
#pragma unroll
    for (int a = 0; a < 4; a++)
#pragma unroll
        for (int b2 = 0; b2 < 4; b2++) acc[a][b2] = floatx4{0.f, 0.f, 0.f, 0.f};

    for (int k0 = 0; k0 < Kd; k0 += 64) {
#pragma unroll
        for (int i = 0; i < 8; i++) {
            int idx = tid + i * 256;
            int r = idx >> 4, kc = idx & 15;
            float4 v = *(const float4*)(X + (size_t)(row0 + r) * Kd + k0 + kc * 4);
            ushort h0 = f2bh(v.x), h1 = f2bh(v.y), h2 = f2bh(v.z), h3 = f2bh(v.w);
            ushort l0 = f2bh(v.x - bh2f(h0)), l1 = f2bh(v.y - bh2f(h1)),
                   l2 = f2bh(v.z - bh2f(h2)), l3 = f2bh(v.w - bh2f(h3));
            int base = (r << 6) + (((kc >> 1) ^ (r & 7)) << 3) + ((kc & 1) << 2);
            *(ushort4*)(Xh + base) = make_ushort4(h0, h1, h2, h3);
            *(ushort4*)(Xl + base) = make_ushort4(l0, l1, l2, l3);
        }
#pragma unroll
        for (int i = 0; i < 4; i++) {
            int idx = tid + i * 256;
            int c = idx >> 3, ch = idx & 7;
            int base = (c << 6) + ((ch ^ (c & 7)) << 3);
            size_t go = (size_t)(col0 + c) * Kd + k0 + ch * 8;
            *(float4*)(Wsh + base) = *(const float4*)(Wh + go);
            *(float4*)(Wsl + base) = *(const float4*)(Wl + go);
        }
        __syncthreads();
#pragma unroll
        for (int kk = 0; kk < 2; kk++) {
            int ch = kk * 4 + lk;
            bf16x8 xh[4], xl[4], wh[4], wl[4];
#pragma unroll
            for (int s = 0; s < 4; s++) {
                int r = rbase + s * 16 + lrow;
                int xoff = (r << 6) + ((ch ^ (r & 7)) << 3);
                xh[s] = *(const bf16x8*)(Xh + xoff);
                xl[s] = *(const bf16x8*)(Xl + xoff);
                int c = cbase + s * 16 + lrow;
                int woff = (c << 6) + ((ch ^ (c & 7)) << 3);
                wh[s] = *(const bf16x8*)(Wsh + woff);
                wl[s] = *(const bf16x8*)(Wsl + woff);
            }
#pragma unroll
            for (int sr = 0; sr < 4; sr++)
#pragma unroll
                for (int sc = 0; sc < 4; sc++) {
                    acc[sr][sc] = __builtin_amdgcn_mfma_f32_16x16x32_bf16(wh[sc], xh[sr], acc[sr][sc], 0, 0, 0);
                    acc[sr][sc] = __builtin_amdgcn_mfma_f32_16x16x32_bf16(wl[sc], xh[sr], acc[sr][sc], 0, 0, 0);
                    acc[sr][sc] = __builtin_amdgcn_mfma_f32_16x16x32_bf16(wh[sc], xl[sr], acc[sr][sc], 0, 0, 0);
                }
        }
        __syncthreads();
    }
#pragma unroll
    for (int sr = 0; sr < 4; sr++) {
        int row = row0 + rbase + sr * 16 + lrow;
#pragma unroll
        for (int sc = 0; sc < 4; sc++) {
            int col = col0 + cbase + sc * 16 + lk * 4;
            size_t o = (size_t)row * C + col;
            float4 v = make_float4(acc[sr][sc][0], acc[sr][sc][1],
                                   acc[sr][sc][2], acc[sr][sc][3]);
            if (bias) { float4 bv = *(const float4*)(bias + col);
                        v.x += bv.x; v.y += bv.y; v.z += bv.z; v.w += bv.w; }
            if (ACT == 1) { v.x = fmaxf(v.x, 0.f); v.y = fmaxf(v.y, 0.f);
                            v.z = fmaxf(v.z, 0.f); v.w = fmaxf(v.w, 0.f); }
            if (RES) { float4 rv = *(const float4*)(res + o);
                       v.x += rv.x; v.y += rv.y; v.z += rv.z; v.w += rv.w; }
            *(float4*)(Y + o) = v;
        }
    }
}

// ==== prep_w: transpose+split all per-layer GEMM weights to bf16 [C][K] ====
__global__ __launch_bounds__(256) void prep_w(const float* __restrict__ Wq,
                                              const float* __restrict__ Wk,
                                              const float* __restrict__ Wv,
                                              const float* __restrict__ Wo,
                                              const float* __restrict__ fW1,
                                              const float* __restrict__ fW2,
                                              ushort* __restrict__ oh,
                                              ushort* __restrict__ ol) {
    int l = blockIdx.y, t = blockIdx.x;
    const float* src; int K, C, tiles_c; size_t obase;
    if (t < 64) {
        int mi = t >> 4; t &= 15;
        src = (mi == 0 ? Wq : mi == 1 ? Wk : mi == 2 ? Wv : Wo) + (size_t)l * 16384;
        K = 128; C = 128; tiles_c = 4; obase = (size_t)l * WLAY + (size_t)mi * 16384;
    } else if (t < 128) {
        t -= 64; src = fW1 + (size_t)l * 65536;
        K = 128; C = 512; tiles_c = 16; obase = (size_t)l * WLAY + 65536;
    } else {
        t -= 128; src = fW2 + (size_t)l * 65536;
        K = 512; C = 128; tiles_c = 4; obase = (size_t)l * WLAY + 131072;
    }
    int tc = t % tiles_c, tk = t / tiles_c;
    __shared__ float tile[32][33];
    int tx = threadIdx.x & 31, ty = threadIdx.x >> 5;
#pragma unroll
    for (int i = 0; i < 4; i++) {
        int k = tk * 32 + ty + i * 8;
        tile[ty + i * 8][tx] = src[(size_t)k * C + tc * 32 + tx];
    }
    __syncthreads();
#pragma unroll
    for (int i = 0; i < 4; i++) {
        int c = tc * 32 + ty + i * 8;
        float v = tile[tx][ty + i * 8];
        ushort h = f2bh(v);
        ushort lo = f2bh(v - bh2f(h));
        size_t o = obase + (size_t)c * K + tk * 32 + tx;
        oh[o] = h; ol[o] = lo;
    }
}

// ============== naive GEMM for small/ragged shapes =========================
template <int ACT, bool RES>
__global__ void small_gemm(const float* __restrict__ X, const float* __restrict__ W,
                           const float* __restrict__ bias, const float* __restrict__ res,
                           float* __restrict__ Y, int n, int Kd, int C) {
    int idx = blockIdx.x * 256 + threadIdx.x;
    if (idx >= n * C) return;
    int row = idx / C, c = idx - row * C;
    float a = bias ? bias[c] : 0.f;
    const float* xr = X + (size_t)row * Kd;
    for (int k = 0; k < Kd; k++) a = fmaf(xr[k], W[(size_t)k * C + c], a);
    if (ACT == 1) a = fmaxf(a, 0.f);
    if (RES) a += res[idx];
    Y[idx] = a;
}

// ==== combined weights cW[l][k][c256]: tiled f32 GEMM, 16 blocks ===========
__global__ __launch_bounds__(256) void combine_fast(const float* __restrict__ eW2,
                                                    const float* __restrict__ Wke,
                                                    const float* __restrict__ Wve,
                                                    float* __restrict__ cW) {
    __shared__ float Xs[128 * 36];
    __shared__ float Ws[32 * 128];
    int x = blockIdx.x;
    int li = x & 7, kv = x >> 3;
    int l = li < 4 ? li : li + 1;
    int g = (li & 3) + 1;
    const float* E2 = eW2 + (size_t)g * 16384;
    const float* Wp = (kv ? Wve : Wke) + (size_t)l * 16384;
    float* out = cW + (size_t)l * 32768 + kv * 128;
    int tid = threadIdx.x;
    int tc = tid & 15, tr = tid >> 4;
    int cA = tc * 4, rA = tr * 4;
    float acc[8][8] = {};
    for (int j0 = 0; j0 < 128; j0 += 32) {
#pragma unroll
        for (int i = 0; i < 4; i++) {
            int idx = tid + i * 256;
            int r = idx >> 3, jc = idx & 7;
            *(float4*)(Xs + r * 36 + jc * 4) =
                *(const float4*)(E2 + (size_t)r * 128 + j0 + jc * 4);
        }
#pragma unroll
        for (int i = 0; i < 4; i++) {
            int idx = tid + i * 256;
            int cc = idx & 31, jj = idx >> 5;
            *(float4*)(Ws + jj * 128 + cc * 4) =
                *(const float4*)(Wp + (size_t)(j0 + jj) * 128 + cc * 4);
        }
        __syncthreads();
#pragma unroll 8
        for (int jj = 0; jj < 32; jj++) {
            float4 w0 = *(const float4*)(Ws + jj * 128 + cA);
            float4 w1 = *(const float4*)(Ws + jj * 128 + cA + 64);
            float xr[8];
#pragma unroll
            for (int i2 = 0; i2 < 4; i2++) {
                xr[i2]     = Xs[(rA + i2) * 36 + jj];
                xr[4 + i2] = Xs[(rA + i2 + 64) * 36 + jj];
            }
#pragma unroll
            for (int i2 = 0; i2 < 8; i2++) {
                float xv = xr[i2];
                acc[i2][0] = fmaf(xv, w0.x, acc[i2][0]);
                acc[i2][1] = fmaf(xv, w0.y, acc[i2][1]);
                acc[i2][2] = fmaf(xv, w0.z, acc[i2][2]);
                acc[i2][3] = fmaf(xv, w0.w, acc[i2][3]);
                acc[i2][4] = fmaf(xv, w1.x, acc[i2][4]);
                acc[i2][5] = fmaf(xv, w1.y, acc[i2][5]);
                acc[i2][6] = fmaf(xv, w1.z, acc[i2][6]);
                acc[i2][7] = fmaf(xv, w1.w, acc[i2][7]);
            }
        }
        __syncthreads();
    }
#pragma unroll
    for (int i = 0; i < 8; i++) {
        int r = (i < 4) ? (rA + i) : (rA + i + 60);
#pragma unroll
        for (int chh = 0; chh < 2; chh++) {
            int c = cA + chh * 64;
            *(float4*)(out + (size_t)r * 256 + c) =
                make_float4(acc[i][chh * 4 + 0], acc[i][chh * 4 + 1],
                            acc[i][chh * 4 + 2], acc[i][chh * 4 + 3]);
        }
    }
}
__global__ void combine_bias(const float* __restrict__ eb2,
                             const float* __restrict__ Wke,
                             const float* __restrict__ Wve,
                             float* __restrict__ cb) {
    int x = blockIdx.x;
    int li = x & 7, kv = x >> 3;
    int l = li < 4 ? li : li + 1;
    int g = (li & 3) + 1;
    const float* Wp = (kv ? Wve : Wke) + (size_t)l * 16384;
    const float* eb = eb2 + g * 128;
    int cc = threadIdx.x;
    float a = 0.f;
    for (int j = 0; j < 128; j++) a = fmaf(eb[j], Wp[(size_t)j * 128 + cc], a);
    cb[l * 256 + kv * 128 + cc] = a;
}

// ============================ CSR construction =============================
__global__ void zero_i32(int* __restrict__ p, int n) {
    int i = blockIdx.x * 256 + threadIdx.x;
    if (i < n) p[i] = 0;
}
__global__ void hist_kernel(const int* __restrict__ dst, int E, int* __restrict__ deg) {
    int e = blockIdx.x * 256 + threadIdx.x;
    if (e < E) atomicAdd(&deg[dst[e]], 1);
}
__global__ __launch_bounds__(256) void exscan5(const int* __restrict__ deg0,
                                               int* __restrict__ off0,
                                               int* __restrict__ cursor0, int n) {
    int g = blockIdx.x;
    const int* deg = deg0 + (size_t)g * n;
    int* off = off0 + (size_t)g * (n + 1);
    int* cursor = cursor0 + (size_t)g * n;
    __shared__ int wsum[4];
    __shared__ int carry;
    int tid = threadIdx.x, lane = tid & 63, w = tid >> 6;
    if (tid == 0) carry = 0;
    __syncthreads();
    for (int base = 0; base < n; base += 256) {
        int v = (base + tid < n) ? deg[base + tid] : 0;
        int incl = v;
        for (int d = 1; d < 64; d <<= 1) {
            int t = __shfl_up(incl, d, 64);
            if (lane >= d) incl += t;
        }
        if (lane == 63) wsum[w] = incl;
        __syncthreads();
        int woff = 0;
        for (int i = 0; i < w; i++) woff += wsum[i];
        int total = wsum[0] + wsum[1] + wsum[2] + wsum[3];
        int excl = carry + woff + incl - v;
        if (base + tid < n) { off[base + tid] = excl; cursor[base + tid] = excl; }
        __syncthreads();
        if (tid == 0) carry += total;
        __syncthreads();
    }
    if (threadIdx.x == 0) off[n] = carry;
}
__global__ void scatter_kernel(const int* __restrict__ dst, int E,
                               int* __restrict__ cursor, int* __restrict__ eids) {
    int e = blockIdx.x * 256 + threadIdx.x;
    if (e < E) { int p = atomicAdd(&cursor[dst[e]], 1); eids[p] = e; }
}
__global__ void sort_edges(const int* __restrict__ eid, const int* __restrict__ srcArr,
                           const float* __restrict__ attr, int aw, int E,
                           int* __restrict__ esrc, float4* __restrict__ eattr) {
    int pos = blockIdx.x * 256 + threadIdx.x;
    if (pos >= E) return;
    int e = eid[pos];
    esrc[pos] = srcArr[e];
    if (attr) {
        float4 v;
        v.x = attr[(size_t)e * aw + 0];
        v.y = attr[(size_t)e * aw + 1];
        v.z = (aw > 2) ? attr[(size_t)e * aw + 2] : 0.f;
        v.w = (aw > 3) ? attr[(size_t)e * aw + 3] : 0.f;
        eattr[pos] = v;
    }
}

// ====== prep_g: g[d][cp][h] = bf16( 0.25*sum_t Ck[cp][16h+t] q[d][16h+t] ) =
// register-held Ck slice (64 contiguous floats/thread), q batched in LDS.
// grid = M/8 blocks, one shot.
__global__ __launch_bounds__(256) void prep_g(const float* __restrict__ q,
                                              const float* __restrict__ cWl,
                                              const float* __restrict__ cbl,
                                              ushort* __restrict__ g,
                                              float* __restrict__ sb) {
    __shared__ float qs[8 * 132];
    int tid = threadIdx.x;
    int cp = tid & 127, hb = (tid >> 7) * 4;     // hb in {0,4}, wave-uniform
    float ck[64];
    {
        const float* csrc = cWl + (size_t)cp * 256 + hb * 16;
#pragma unroll
        for (int t4 = 0; t4 < 16; t4++) {
            float4 v = *(const float4*)(csrc + t4 * 4);
            ck[t4 * 4 + 0] = v.x; ck[t4 * 4 + 1] = v.y;
            ck[t4 * 4 + 2] = v.z; ck[t4 * 4 + 3] = v.w;
        }
    }
    int d0 = blockIdx.x * 8;
    {
        int dl = tid >> 5, col = (tid & 31) * 4;
        *(float4*)(qs + dl * 132 + col) = *(const float4*)(q + (size_t)(d0 + dl) * 128 + col);
    }
    __syncthreads();
#pragma unroll
    for (int dl = 0; dl < 8; dl++) {
        const float* qr = qs + dl * 132 + hb * 16;   // broadcast reads (wave-uniform addr)
        float a0 = 0.f, a1 = 0.f, a2 = 0.f, a3 = 0.f;
#pragma unroll
        for (int t = 0; t < 16; t++) {
            a0 = fmaf(ck[t],      qr[t],      a0);
            a1 = fmaf(ck[16 + t], qr[16 + t], a1);
            a2 = fmaf(ck[32 + t], qr[32 + t], a2);
            a3 = fmaf(ck[48 + t], qr[48 + t], a3);
        }
        ushort4 o = make_ushort4(f2bh(a0 * 0.25f), f2bh(a1 * 0.25f),
                                 f2bh(a2 * 0.25f), f2bh(a3 * 0.25f));
        *(ushort4*)(g + (size_t)(d0 + dl) * 1024 + cp * 8 + hb) = o;
    }
    if (tid < 64) {
        int dl = tid >> 3, h = tid & 7;
        const float* qr = qs + dl * 132 + h * 16;
        const float* cbr = cbl + h * 16;
        float a = 0.f;
#pragma unroll
        for (int t = 0; t < 16; t++) a = fmaf(cbr[t], qr[t], a);
        sb[(d0 + dl) * 8 + h] = a * 0.25f;
    }
}

// ===== factorized fused attention (edge-emb layers): one wave per dst ======
__global__ __launch_bounds__(256) void attn_fact(const int* __restrict__ off,
                                                 const int* __restrict__ esrc,
                                                 const float4* __restrict__ eattr,
                                                 const ushort* __restrict__ g,
                                                 const float* __restrict__ sb,
                                                 const float* __restrict__ eW1,
                                                 const float* __restrict__ eb1,
                                                 const float* __restrict__ kx,
                                                 const float* __restrict__ vx,
                                                 const float* __restrict__ q,
                                                 ushort* __restrict__ hsum,
                                                 float* __restrict__ vxacc,
                                                 float* __restrict__ den) {
    __shared__ float lds[4 * 144];
    int w = threadIdx.x >> 6, l = threadIdx.x & 63;
    int i = l & 15, hlo = l >> 4;
    float* hw = lds + w * 144;
    int d = blockIdx.x * 4 + w;
    int beg = off[d], end = off[d + 1];
    float q0 = q[(size_t)d * 128 + l] * 0.25f;
    float q1 = q[(size_t)d * 128 + 64 + l] * 0.25f;
    float gA[8], gB[8];
#pragma unroll
    for (int j = 0; j < 8; j++) {
        gA[j] = bh2f(g[(size_t)d * 1024 + (j * 16 + i) * 8 + hlo]);
        gB[j] = bh2f(g[(size_t)d * 1024 + (j * 16 + i) * 8 + hlo + 4]);
    }
    float sbA = sb[d * 8 + hlo], sbB = sb[d * 8 + 4 + hlo];
    float w1a[4], w1b[4];
#pragma unroll
    for (int j = 0; j < 4; j++) { w1a[j] = eW1[j * 128 + l]; w1b[j] = eW1[j * 128 + 64 + l]; }
    float ebA = eb1[l], ebB = eb1[64 + l];
    float mA = -INFINITY, mB = -INFINITY, dnA = 0.f, dnB = 0.f;
    float accL[8] = {}, accH[8] = {};
    float va0 = 0.f, va1 = 0.f;
    float4 aC = make_float4(0.f, 0.f, 0.f, 0.f);
    float k0C = 0.f, k1C = 0.f, v0C = 0.f, v1C = 0.f;
    if (beg < end) {
        int s0 = esrc[beg]; aC = eattr[beg];
        const float* kxr = kx + (size_t)s0 * 128;
        const float* vxr = vx + (size_t)s0 * 128;
        k0C = kxr[l]; k1C = kxr[64 + l];
        v0C = vxr[l]; v1C = vxr[64 + l];
    }
    for (int pos = beg; pos < end; pos++) {
        float4 at = aC;
        float k0 = k0C, k1 = k1C, v0 = v0C, v1 = v1C;
        if (pos + 1 < end) {
            int sN = esrc[pos + 1]; aC = eattr[pos + 1];
            const float* kxr = kx + (size_t)sN * 128;
            const float* vxr = vx + (size_t)sN * 128;
            k0C = kxr[l]; k1C = kxr[64 + l];
            v0C = vxr[l]; v1C = vxr[64 + l];
        }
        float h0 = fmaxf(ebA + at.x * w1a[0] + at.y * w1a[1] + at.z * w1a[2] + at.w * w1a[3], 0.f);
        float h1 = fmaxf(ebB + at.x * w1b[0] + at.y * w1b[1] + at.z * w1b[2] + at.w * w1b[3], 0.f);
        hw[l] = h0; hw[64 + l] = h1;
        __builtin_amdgcn_wave_barrier();
        float pA = q0 * k0, pB = q1 * k1;
#pragma unroll
        for (int j = 0; j < 8; j++) {
            float hv = hw[j * 16 + i];
            pA = fmaf(hv, gA[j], pA);
            pB = fmaf(hv, gB[j], pB);
        }
#pragma unroll
        for (int msk = 1; msk < 16; msk <<= 1) {
            pA += __shfl_xor(pA, msk, 64);
            pB += __shfl_xor(pB, msk, 64);
        }
        pA += sbA; pB += sbB;
        float nmA = fmaxf(mA, pA), nmB = fmaxf(mB, pB);
        float cA = __expf(mA - nmA), cB = __expf(mB - nmB);
        float wA = __expf(pA - nmA), wB = __expf(pB - nmB);
        mA = nmA; mB = nmB;
        dnA = dnA * cA + wA; dnB = dnB * cB + wB;
        va0 = va0 * cA + wA * v0; va1 = va1 * cB + wB * v1;
        if (i == 0) {
            hw[128 + hlo] = wA; hw[132 + hlo] = wB;
            hw[136 + hlo] = cA; hw[140 + hlo] = cB;
        }
        __builtin_amdgcn_wave_barrier();
        float4 wv0 = *(float4*)(hw + 128), wv1 = *(float4*)(hw + 132);
        float4 cv0 = *(float4*)(hw + 136), cv1 = *(float4*)(hw + 140);
        accL[0] = fmaf(accL[0], cv0.x, wv0.x * h0); accH[0] = fmaf(accH[0], cv0.x, wv0.x * h1);
        accL[1] = fmaf(accL[1], cv0.y, wv0.y * h0); accH[1] = fmaf(accH[1], cv0.y, wv0.y * h1);
        accL[2] = fmaf(accL[2], cv0.z, wv0.z * h0); accH[2] = fmaf(accH[2], cv0.z, wv0.z * h1);
        accL[3] = fmaf(accL[3], cv0.w, wv0.w * h0); accH[3] = fmaf(accH[3], cv0.w, wv0.w * h1);
        accL[4] = fmaf(accL[4], cv1.x, wv1.x * h0); accH[4] = fmaf(accH[4], cv1.x, wv1.x * h1);
        accL[5] = fmaf(accL[5], cv1.y, wv1.y * h0); accH[5] = fmaf(accH[5], cv1.y, wv1.y * h1);
        accL[6] = fmaf(accL[6], cv1.z, wv1.z * h0); accH[6] = fmaf(accH[6], cv1.z, wv1.z * h1);
        accL[7] = fmaf(accL[7], cv1.w, wv1.w * h0); accH[7] = fmaf(accH[7], cv1.w, wv1.w * h1);
    }
#pragma unroll
    for (int h = 0; h < 8; h++) {
        hsum[(size_t)d * 1024 + h * 128 + l]      = f2bh(accL[h]);
        hsum[(size_t)d * 1024 + h * 128 + 64 + l] = f2bh(accH[h]);
    }
    vxacc[(size_t)d * 128 + l] = va0;
    vxacc[(size_t)d * 128 + 64 + l] = va1;
    if (i == 0) { den[d * 8 + hlo] = dnA; den[d * 8 + 4 + hlo] = dnB; }
}

// ========= plain fused attention (no edge emb): one wave per dst ===========
__global__ __launch_bounds__(256) void attn_plain(const int* __restrict__ off,
                                                  const int* __restrict__ esrc,
                                                  const float* __restrict__ kx,
                                                  const float* __restrict__ vx,
                                                  const float* __restrict__ q,
                                                  float* __restrict__ agg) {
    int w = threadIdx.x >> 6, lane = threadIdx.x & 63;
    int d = blockIdx.x * 4 + w;
    int beg = off[d], end = off[d + 1];
    float q0 = q[(size_t)d * 128 + lane] * 0.25f;
    float q1 = q[(size_t)d * 128 + 64 + lane] * 0.25f;
    float m0 = -INFINITY, m1 = -INFINITY;
    float den0 = 0.f, den1 = 0.f, acc0 = 0.f, acc1 = 0.f;
    float k0C = 0.f, k1C = 0.f, v0C = 0.f, v1C = 0.f;
    if (beg < end) {
        int s0 = esrc[beg];
        const float* kxr = kx + (size_t)s0 * 128;
        const float* vxr = vx + (size_t)s0 * 128;
        k0C = kxr[lane]; k1C = kxr[64 + lane];
        v0C = vxr[lane]; v1C = vxr[64 + lane];
    }
    for (int pos = beg; pos < end; pos++) {
        float k0 = k0C, k1 = k1C, v0 = v0C, v1 = v1C;
        if (pos + 1 < end) {
            int sN = esrc[pos + 1];
            const float* kxr = kx + (size_t)sN * 128;
            const float* vxr = vx + (size_t)sN * 128;
            k0C = kxr[lane]; k1C = kxr[64 + lane];
            v0C = vxr[lane]; v1C = vxr[64 + lane];
        }
        float p0 = q0 * k0, p1 = q1 * k1;
#pragma unroll
        for (int msk = 1; msk < 16; msk <<= 1) {
            p0 += __shfl_xor(p0, msk, 64);
            p1 += __shfl_xor(p1, msk, 64);
        }
        float nm0 = fmaxf(m0, p0), nm1 = fmaxf(m1, p1);
        float c0 = __expf(m0 - nm0), c1 = __expf(m1 - nm1);
        float e0 = __expf(p0 - nm0), e1 = __expf(p1 - nm1);
        acc0 = acc0 * c0 + e0 * v0; den0 = den0 * c0 + e0;
        acc1 = acc1 * c1 + e1 * v1; den1 = den1 * c1 + e1;
        m0 = nm0; m1 = nm1;
    }
    agg[(size_t)d * 128 + lane]      = acc0 / (den0 + 1e-9f);
    agg[(size_t)d * 128 + 64 + lane] = acc1 / (den1 + 1e-9f);
}

// ====== epilogue: agg = (vxacc + hsum @ blockdiag(Cv)) * inv + cvb * cf ====
static constexpr int HST_ = 1092;
__global__ __launch_bounds__(256) void agg_fin(const ushort* __restrict__ hsum,
                                               const float* __restrict__ vxacc,
                                               const float* __restrict__ den,
                                               const float* __restrict__ cWl,
                                               const float* __restrict__ cbl,
                                               float* __restrict__ agg) {
    __shared__ float Cvs[128 * 128];
    __shared__ float hstage[8 * HST_];
    __shared__ float dens[64];
    int tid = threadIdx.x;
    {
        int cp = tid >> 1, cb0 = (tid & 1) * 64;
#pragma unroll
        for (int kq = 0; kq < 16; kq++)
            *(float4*)(Cvs + cp * 128 + cb0 + kq * 4) =
                *(const float4*)(cWl + (size_t)cp * 256 + 128 + cb0 + kq * 4);
    }
    int j = tid & 31, dsel = tid >> 5;
    int c4 = j * 4, h = j >> 2;
    float4 cvb = *(const float4*)(cbl + 128 + c4);
    for (int d0 = blockIdx.x * 8; d0 < M_; d0 += gridDim.x * 8) {
        __syncthreads();
        int r = tid * 4;
#pragma unroll
        for (int k = 0; k < 8; k++) {
            ushort4 u = *(const ushort4*)(hsum + (size_t)(d0 + k) * 1024 + r);
            *(float4*)(hstage + k * HST_ + (r >> 7) * 136 + (r & 127)) =
                make_float4(bh2f(u.x), bh2f(u.y), bh2f(u.z), bh2f(u.w));
        }
        if (tid < 64) dens[tid] = den[d0 * 8 + tid];
        __syncthreads();
        int d = d0 + dsel;
        float dn = dens[dsel * 8 + h];
        float inv = 1.f / (dn + 1e-9f);
        float cf = dn * inv;
        float a0 = 0.f, a1 = 0.f, a2 = 0.f, a3 = 0.f;
        const float* hrow = hstage + dsel * HST_ + h * 136;
#pragma unroll 4
        for (int cpp = 0; cpp < 128; cpp++) {
            float hs = hrow[cpp];
            float4 cv = *(float4*)(Cvs + cpp * 128 + c4);
            a0 = fmaf(hs, cv.x, a0); a1 = fmaf(hs, cv.y, a1);
            a2 = fmaf(hs, cv.z, a2); a3 = fmaf(hs, cv.w, a3);
        }
        float4 vv = *(const float4*)(vxacc + (size_t)d * 128 + c4);
        float4 o;
        o.x = (vv.x + a0) * inv + cvb.x * cf;
        o.y = (vv.y + a1) * inv + cvb.y * cf;
        o.z = (vv.z + a2) * inv + cvb.z * cf;
        o.w = (vv.w + a3) * inv + cvb.w * cf;
        *(float4*)(agg + (size_t)d * 128 + c4) = o;
    }
}

// ======================= small glue kernels ================================
__global__ void mode_init(float* __restrict__ m, const float* __restrict__ mt) {
    int idx = blockIdx.x * 256 + threadIdx.x;
    if (idx >= M_ * H_) return;
    int node = idx >> 7, c = idx & 127;
    m[idx] = mt[(node % K_) * H_ + c];
}
__global__ void extract_last(const float* __restrict__ m, float* __restrict__ out) {
    int idx = blockIdx.x * 256 + threadIdx.x;
    if (idx >= AK_ * H_) return;
    int row = idx >> 7, c = idx & 127;
    int a = row / K_, k = row - a * K_;
    int node = (a * T_ + (T_ - 1)) * K_ + k;
    out[idx] = m[(size_t)node * H_ + c];
}
__global__ void add_anchor(float* __restrict__ m, const float* __restrict__ anchor) {
    int idx = blockIdx.x * 256 + threadIdx.x;
    if (idx >= M_ * H_) return;
    int node = idx >> 7, c = idx & 127;
    int a = node / (T_ * K_), k = node % K_;
    m[idx] += anchor[(size_t)(a * K_ + k) * H_ + c];
}

// ============================ host launch ==================================
extern "C" void kernel_launch(void* const* d_in, const int* in_sizes, int n_in,
                              void* d_out, int out_size, void* d_ws, size_t ws_size,
                              hipStream_t stream) {
    const float* a_input     = (const float*)d_in[0];
    const float* l_embs      = (const float*)d_in[1];
    const float* mode_tokens = (const float*)d_in[2];
    const float* emb_W1 = (const float*)d_in[3];
    const float* emb_b1 = (const float*)d_in[4];
    const float* emb_W2 = (const float*)d_in[5];
    const float* emb_b2 = (const float*)d_in[6];
    const float* ga_Wq  = (const float*)d_in[7];
    const float* ga_Wk  = (const float*)d_in[8];
    const float* ga_Wv  = (const float*)d_in[9];
    const float* ga_Wo  = (const float*)d_in[10];
    const float* ga_Wke = (const float*)d_in[11];
    const float* ga_Wve = (const float*)d_in[12];
    const float* ga_g1  = (const float*)d_in[13];
    const float* ga_b1  = (const float*)d_in[14];
    const float* ga_g2  = (const float*)d_in[15];
    const float* ga_b2  = (const float*)d_in[16];
    const float* ga_fW1 = (const float*)d_in[17];
    const float* ga_fb1 = (const float*)d_in[18];
    const float* ga_fW2 = (const float*)d_in[19];
    const float* ga_fb2 = (const float*)d_in[20];
    const float* tp_W1 = (const float*)d_in[21];
    const float* tp_b1 = (const float*)d_in[22];
    const float* tp_W2 = (const float*)d_in[23];
    const float* tp_b2 = (const float*)d_in[24];
    const float* pa_W1 = (const float*)d_in[25];
    const float* pa_b1 = (const float*)d_in[26];
    const float* pa_W2 = (const float*)d_in[27];
    const float* pa_b2 = (const float*)d_in[28];
    const float* tr_W1 = (const float*)d_in[29];
    const float* tr_b1 = (const float*)d_in[30];
    const float* tr_W2 = (const float*)d_in[31];
    const float* tr_b2 = (const float*)d_in[32];
    const float* attrs[4] = { (const float*)d_in[33], (const float*)d_in[34],
                              (const float*)d_in[35], (const float*)d_in[36] };
    const int* eis[5] = { (const int*)d_in[37], (const int*)d_in[38], (const int*)d_in[39],
                          (const int*)d_in[40], (const int*)d_in[41] };
    int Es[5];
    int Emax = 0;
    for (int i = 0; i < 5; i++) { Es[i] = in_sizes[37 + i] / 2; if (Es[i] > Emax) Emax = Es[i]; }

    size_t off = 0;
    auto alloc = [&](size_t nbytes) -> char* {
        char* p = (char*)d_ws + off;
        off += ((nbytes + 255) / 256) * 256;
        return p;
    };
    float* cW     = (float*)alloc((size_t)NL_ * 128 * 256 * 4);
    float* cb     = (float*)alloc((size_t)NL_ * 256 * 4);
    ushort* wbh   = (ushort*)alloc((size_t)NL_ * WLAY * 2);
    ushort* wbl   = (ushort*)alloc((size_t)NL_ * WLAY * 2);
    float* a_embs = (float*)alloc((size_t)AT_ * H_ * 4);
    float* m      = (float*)alloc((size_t)M_ * H_ * 4);
    float* xd_ln  = (float*)alloc((size_t)M_ * H_ * 4);
    float* xs_ln  = (float*)alloc((size_t)AT_ * H_ * 4);
    float* q      = (float*)alloc((size_t)M_ * H_ * 4);
    float* kx     = (float*)alloc((size_t)M_ * H_ * 4);
    float* vx     = (float*)alloc((size_t)M_ * H_ * 4);
    float* agg    = (float*)alloc((size_t)M_ * H_ * 4);
    float* big    = (float*)alloc((size_t)M_ * FF_ * 4);     // FFN hidden
    ushort* gbuf  = (ushort*)alloc((size_t)M_ * 1024 * 2);   // bf16 g [d][cp][h]
    ushort* hsumb = (ushort*)alloc((size_t)M_ * 1024 * 2);   // bf16 hsum [d][h][cp]
    float* vxacc  = (float*)alloc((size_t)M_ * H_ * 4);
    float* den    = (float*)alloc((size_t)M_ * 8 * 4);
    float* sb     = (float*)alloc((size_t)M_ * 8 * 4);
    int* csr_off  = (int*)alloc((size_t)5 * (M_ + 1) * 4);
    int* csr_eid  = (int*)alloc((size_t)5 * Emax * 4);
    int* esrc     = (int*)alloc((size_t)5 * Emax * 4);
    float4* eattr = (float4*)alloc((size_t)4 * Emax * 16);
    int* deg5     = (int*)alloc((size_t)5 * M_ * 4);
    int* cursor5  = (int*)alloc((size_t)5 * M_ * 4);
    float* mlast  = (float*)alloc((size_t)AK_ * H_ * 4);
    float* hbuf   = (float*)alloc((size_t)AK_ * H_ * 4);
    float* anchor = (float*)alloc((size_t)AK_ * H_ * 4);
    (void)ws_size; (void)n_in;

    float* outp = (float*)d_out;

    // ---- CSR + sorted src/attr for 5 graphs ----
    zero_i32<<<(5 * M_ + 255) / 256, 256, 0, stream>>>(deg5, 5 * M_);
    for (int gI = 0; gI < 5; gI++)
        hist_kernel<<<(Es[gI] + 255) / 256, 256, 0, stream>>>(eis[gI] + Es[gI], Es[gI], deg5 + (size_t)gI * M_);
    exscan5<<<5, 256, 0, stream>>>(deg5, csr_off, cursor5, M_);
    for (int gI = 0; gI < 5; gI++)
        scatter_kernel<<<(Es[gI] + 255) / 256, 256, 0, stream>>>(eis[gI] + Es[gI], Es[gI],
            cursor5 + (size_t)gI * M_, csr_eid + (size_t)gI * Emax);
    for (int gI = 0; gI < 5; gI++) {
        int aw = (gI == 0 || gI == 2) ? 4 : (gI == 4 ? 0 : 3);
        sort_edges<<<(Es[gI] + 255) / 256, 256, 0, stream>>>(
            csr_eid + (size_t)gI * Emax, eis[gI], (gI < 4) ? attrs[gI] : nullptr, aw, Es[gI],
            esrc + (size_t)gI * Emax, eattr + (size_t)gI * Emax);
    }

    // ---- weight prep ----
    prep_w<<<dim3(192, 10), 256, 0, stream>>>(ga_Wq, ga_Wk, ga_Wv, ga_Wo, ga_fW1, ga_fW2, wbh, wbl);
    combine_fast<<<16, 256, 0, stream>>>(emb_W2, ga_Wke, ga_Wve, cW);
    combine_bias<<<16, 128, 0, stream>>>(emb_b2, ga_Wke, ga_Wve, cb);

    // ---- embeddings / init ----
    small_gemm<1, false><<<(AT_ * H_ + 255) / 256, 256, 0, stream>>>(a_input, emb_W1, emb_b1, nullptr, big, AT_, 5, H_);
    small_gemm<0, false><<<(AT_ * H_ + 255) / 256, 256, 0, stream>>>(big, emb_W2, emb_b2, nullptr, a_embs, AT_, H_, H_);
    mode_init<<<(M_ * H_ + 255) / 256, 256, 0, stream>>>(m, mode_tokens);

    struct Cfg { const float* srcX; int n_src; int gi; bool hasE; };
    Cfg cfgs[10] = {
        { a_embs, AT_, 0, true }, { l_embs, L_, 1, true },
        { nullptr, M_, 2, true }, { nullptr, M_, 3, true },
        { nullptr, M_, 4, false },
        { a_embs, AT_, 0, true }, { l_embs, L_, 1, true },
        { nullptr, M_, 2, true }, { nullptr, M_, 3, true },
        { nullptr, M_, 4, false },
    };

    for (int l = 0; l < 10; l++) {
        const Cfg& cf = cfgs[l];
        const int* offg = csr_off + cf.gi * (M_ + 1);
        const int* esrcg = esrc + (size_t)cf.gi * Emax;
        const float4* eattrg = eattr + (size_t)cf.gi * Emax;
        const float* g1 = ga_g1 + l * H_; const float* b1 = ga_b1 + l * H_;
        size_t wb = (size_t)l * WLAY;

        ln_kernel<<<M_ / 4, 256, 0, stream>>>(m, g1, b1, xd_ln, M_);
        mgemm<0, false><<<dim3(M_ / 128, 1), 256, 0, stream>>>(
            xd_ln, wbh + wb, wbl + wb, nullptr, nullptr, q, M_, 128, 128);
        const float* srcLN = xd_ln;
        if (cf.srcX) {
            ln_kernel<<<cf.n_src / 4, 256, 0, stream>>>(cf.srcX, g1, b1, xs_ln, cf.n_src);
            srcLN = xs_ln;
        }
        mgemm<0, false><<<dim3(cf.n_src / 128, 1), 256, 0, stream>>>(
            srcLN, wbh + wb + 16384, wbl + wb + 16384, nullptr, nullptr, kx, cf.n_src, 128, 128);
        mgemm<0, false><<<dim3(cf.n_src / 128, 1), 256, 0, stream>>>(
            srcLN, wbh + wb + 32768, wbl + wb + 32768, nullptr, nullptr, vx, cf.n_src, 128, 128);

        if (cf.hasE) {
            int gg = (l < 5) ? l + 1 : l - 4;
            const float* eW1g = emb_W1 + (size_t)gg * 5 * H_;
            const float* eb1g = emb_b1 + (size_t)gg * H_;
            prep_g<<<M_ / 8, 256, 0, stream>>>(q, cW + (size_t)l * 128 * 256, cb + l * 256, gbuf, sb);
            attn_fact<<<M_ / 4, 256, 0, stream>>>(offg, esrcg, eattrg, gbuf, sb, eW1g, eb1g,
                                                  kx, vx, q, hsumb, vxacc, den);
            agg_fin<<<256, 256, 0, stream>>>(hsumb, vxacc, den,
                                             cW + (size_t)l * 128 * 256, cb + l * 256, agg);
        } else {
            attn_plain<<<M_ / 4, 256, 0, stream>>>(offg, esrcg, kx, vx, q, agg);
        }

        mgemm<0, true><<<dim3(M_ / 128, 1), 256, 0, stream>>>(
            agg, wbh + wb + 49152, wbl + wb + 49152, nullptr, m, m, M_, 128, 128);
        ln_kernel<<<M_ / 4, 256, 0, stream>>>(m, ga_g2 + l * H_, ga_b2 + l * H_, xd_ln, M_);
        mgemm<1, false><<<dim3(M_ / 128, 4), 256, 0, stream>>>(
            xd_ln, wbh + wb + 65536, wbl + wb + 65536, ga_fb1 + l * FF_, nullptr, big, M_, 128, 512);
        mgemm<0, true><<<dim3(M_ / 128, 1), 256, 0, stream>>>(
            big, wbh + wb + 131072, wbl + wb + 131072, ga_fb2 + l * H_, m, m, M_, 512, 128);

        if (l == 4) {
            extract_last<<<(AK_ * H_ + 255) / 256, 256, 0, stream>>>(m, mlast);
            small_gemm<1, false><<<(AK_ * H_ + 255) / 256, 256, 0, stream>>>(mlast, tp_W1, tp_b1, nullptr, hbuf, AK_, H_, H_);
            small_gemm<0, false><<<(AK_ * P2F + 255) / 256, 256, 0, stream>>>(hbuf, tp_W2, tp_b2, nullptr, outp, AK_, H_, P2F);
            small_gemm<1, false><<<(AK_ * H_ + 255) / 256, 256, 0, stream>>>(outp, pa_W1, pa_b1, nullptr, hbuf, AK_, P2F, H_);
            small_gemm<0, false><<<(AK_ * H_ + 255) / 256, 256, 0, stream>>>(hbuf, pa_W2, pa_b2, nullptr, anchor, AK_, H_, H_);
            add_anchor<<<(M_ * H_ + 255) / 256, 256, 0, stream>>>(m, anchor);
        }
    }

    extract_last<<<(AK_ * H_ + 255) / 256, 256, 0, stream>>>(m, mlast);
    small_gemm<1, false><<<(AK_ * H_ + 255) / 256, 256, 0, stream>>>(mlast, tr_W1, tr_b1, nullptr, hbuf, AK_, H_, H_);
    small_gemm<0, true><<<(AK_ * P2F + 255) / 256, 256, 0, stream>>>(hbuf, tr_W2, tr_b2, outp, outp + AK_ * P2F, AK_, H_, P2F);
}